// Round 5
// baseline (246.880 us; speedup 1.0000x reference)
//
#include <hip/hip_runtime.h>

typedef __attribute__((ext_vector_type(4))) float f32x4;
typedef __attribute__((ext_vector_type(8))) short bf16x8;
typedef __attribute__((ext_vector_type(2))) unsigned int u32x2;
typedef __attribute__((ext_vector_type(4))) unsigned int u32x4;

#define EPSV 1e-5f

// workspace layout (bytes)
#define OFF_BUFA 0u
#define OFF_BUFB 33554432u
#define OFF_T    67108864u
#define OFF_WQ1  (OFF_T + 0u)       // f32 [128][12]  (9 taps used)
#define OFF_R3F  (OFF_T + 6144u)    // f32 [9][128]   integer-valued
#define OFF_CST3 (OFF_T + 10752u)   // f32x4 [128]
#define OFF_CST1 (OFF_T + 12800u)   // f32x4 [128]
#define OFF_R2BF (OFF_T + 14848u)   // bf16 [128][128]
#define OFF_CST2 (OFF_T + 47616u)   // f32x4 [128]
#define OFF_R4BF (OFF_T + 49664u)   // bf16 [128][128]
#define OFF_CST4 (OFF_T + 82432u)   // f32x4 [128]
#define OFF_R5BF (OFF_T + 84480u)   // bf16 [32][128] (rows 19..31 zero)
#define OFF_CST5 (OFF_T + 92672u)   // float2 [32]

struct PArgs {
  const float *dw1, *pw1, *dw2, *pw2, *clsw, *clsb;
  const float *g1, *b1, *m1, *v1;
  const float *g2, *b2, *m2, *v2;
  const float *g3, *b3, *m3, *v3;
  const float *g4, *b4, *m4, *v4;
  const float *s1, *s2, *s3, *s4;
};

__device__ __forceinline__ unsigned short f2bf(float f) {
  return (unsigned short)(__builtin_bit_cast(unsigned int, f) >> 16);
}
__device__ __forceinline__ float clip7(float r) { return fminf(fmaxf(r, -7.f), 7.f); }

// y = a*A; t = (y-m)*sc + b; k = clamp(rint(t/s),0,15).  c = {A, sc, m, b}
__device__ __forceinline__ unsigned int qstep(float a, f32x4 c, float s) {
  float t = (a * c.x - c.z) * c.y + c.w;
  float u = t / s;
  float k = fminf(fmaxf(rintf(u), 0.f), 15.f);
  return (unsigned int)k;
}

// 4 u8 -> 2 dwords of packed bf16
__device__ __forceinline__ void cvt2(unsigned int d, unsigned int &lo, unsigned int &hi) {
  float f0 = (float)(d & 0xffu);
  float f1 = (float)((d >> 8) & 0xffu);
  float f2 = (float)((d >> 16) & 0xffu);
  float f3 = (float)(d >> 24);
  lo = (__builtin_bit_cast(unsigned int, f0) >> 16) | (__builtin_bit_cast(unsigned int, f1) & 0xffff0000u);
  hi = (__builtin_bit_cast(unsigned int, f2) >> 16) | (__builtin_bit_cast(unsigned int, f3) & 0xffff0000u);
}

__device__ __forceinline__ float wmax16(float v) {
  #pragma unroll
  for (int s = 1; s < 16; s <<= 1) v = fmaxf(v, __shfl_xor(v, s));
  return v;
}
__device__ __forceinline__ float wmax64(float v) {
  #pragma unroll
  for (int s = 1; s < 64; s <<= 1) v = fmaxf(v, __shfl_xor(v, s));
  return v;
}

// ---------------- prep: quantize weights, fold BN constants ----------------
__global__ __launch_bounds__(64) void prep_kernel(PArgs P, char* __restrict__ ws) {
  int bi = blockIdx.x, l = threadIdx.x;
  float* wq1 = (float*)(ws + OFF_WQ1);
  float* r3f = (float*)(ws + OFF_R3F);
  f32x4* cst1 = (f32x4*)(ws + OFF_CST1);
  f32x4* cst2 = (f32x4*)(ws + OFF_CST2);
  f32x4* cst3 = (f32x4*)(ws + OFF_CST3);
  f32x4* cst4 = (f32x4*)(ws + OFF_CST4);
  unsigned short* r2 = (unsigned short*)(ws + OFF_R2BF);
  unsigned short* r4 = (unsigned short*)(ws + OFF_R4BF);
  unsigned short* r5 = (unsigned short*)(ws + OFF_R5BF);
  float2* cst5 = (float2*)(ws + OFF_CST5);

  if (bi < 128) {
    int c = bi;
    float w = (l < 9) ? P.dw1[c * 9 + l] : 0.f;
    float mx = wmax16(fabsf(w));
    float sq = fmaxf(mx / 7.0f, 1e-8f);
    if (l < 9) wq1[c * 12 + l] = clip7(rintf(w / sq)) * sq;
    if (l == 0) {
      float sc = P.g1[c] / sqrtf(P.v1[c] + EPSV);
      cst1[c] = f32x4{1.f, sc, P.m1[c], P.b1[c]};
    }
  } else if (bi < 256) {
    int o = bi - 128;
    float w0 = P.pw1[o * 128 + l], w1 = P.pw1[o * 128 + 64 + l];
    float mx = wmax64(fmaxf(fabsf(w0), fabsf(w1)));
    float sq = fmaxf(mx / 7.0f, 1e-8f);
    r2[o * 128 + l]      = f2bf(clip7(rintf(w0 / sq)));
    r2[o * 128 + 64 + l] = f2bf(clip7(rintf(w1 / sq)));
    if (l == 0) {
      float sc = P.g2[o] / sqrtf(P.v2[o] + EPSV);
      cst2[o] = f32x4{P.s1[0] * sq, sc, P.m2[o], P.b2[o]};
    }
  } else if (bi < 384) {
    int c = bi - 256;
    float w = (l < 9) ? P.dw2[c * 9 + l] : 0.f;
    float mx = wmax16(fabsf(w));
    float sq = fmaxf(mx / 7.0f, 1e-8f);
    if (l < 9) r3f[l * 128 + c] = clip7(rintf(w / sq));
    if (l == 0) {
      float sc = P.g3[c] / sqrtf(P.v3[c] + EPSV);
      cst3[c] = f32x4{P.s2[0] * sq, sc, P.m3[c], P.b3[c]};
    }
  } else if (bi < 512) {
    int o = bi - 384;
    float w0 = P.pw2[o * 128 + l], w1 = P.pw2[o * 128 + 64 + l];
    float mx = wmax64(fmaxf(fabsf(w0), fabsf(w1)));
    float sq = fmaxf(mx / 7.0f, 1e-8f);
    r4[o * 128 + l]      = f2bf(clip7(rintf(w0 / sq)));
    r4[o * 128 + 64 + l] = f2bf(clip7(rintf(w1 / sq)));
    if (l == 0) {
      float sc = P.g4[o] / sqrtf(P.v4[o] + EPSV);
      cst4[o] = f32x4{P.s3[0] * sq, sc, P.m4[o], P.b4[o]};
    }
  } else {
    int o = bi - 512;
    if (o < 19) {
      float w0 = P.clsw[o * 128 + l], w1 = P.clsw[o * 128 + 64 + l];
      float mx = wmax64(fmaxf(fabsf(w0), fabsf(w1)));
      float sq = fmaxf(mx / 7.0f, 1e-8f);
      r5[o * 128 + l]      = f2bf(clip7(rintf(w0 / sq)));
      r5[o * 128 + 64 + l] = f2bf(clip7(rintf(w1 / sq)));
      if (l == 0) {
        float A5 = P.s4[0] * sq;
        float bq = rintf(P.clsb[o] / A5) * A5;
        cst5[o] = make_float2(A5, bq);
      }
    } else {
      r5[o * 128 + l] = 0; r5[o * 128 + 64 + l] = 0;
      if (l == 0) cst5[o] = make_float2(0.f, 0.f);
    }
  }
}

// ---------------- dw-conv1 v5: 4-row blocks to kill halo re-fetch ----------------
// block = (b, h-quad, c-half): 4 out rows x 256 w x 64 ch; reads 6 rows (amp 1.5x vs 3x).
// 512 thr: wq=tid&63 (w-quad), cg=tid>>6 (8 ch each). Rows fully unrolled (static idx).
// fmaf/qstep sequence identical to r2/r4 per output row -> bit-identical output.
// LDS tile [1024 pos][64B], write swizzle c ^ ((wq&15)<<2); coalesced permuted store.
__global__ __launch_bounds__(512) void dw1_kernel(const float* __restrict__ x,
                                                  char* __restrict__ ws,
                                                  const float* __restrict__ s1p) {
  __shared__ __align__(16) unsigned char tile[65536];
  int bid = blockIdx.x;
  int b = bid & 7;                     // XCD x owns image b=x
  int rest = bid >> 3;                 // [0,64): (hq, c-half), c-halves adjacent
  int cs = rest & 1, hq = rest >> 1;
  int h0 = hq << 2;
  int tid = threadIdx.x;
  int wq = tid & 63, cg = tid >> 6;
  int w0 = wq << 2;
  int sw = (wq & 15) << 2;
  const float* wq1 = (const float*)(ws + OFF_WQ1);
  const f32x4* cst1 = (const f32x4*)(ws + OFF_CST1);
  float s_act = *s1p;

  unsigned int accw[4][4] = {{0,0,0,0},{0,0,0,0},{0,0,0,0},{0,0,0,0}};
  #pragma unroll 2
  for (int cc = 0; cc < 8; cc++) {
    int crel = (cg << 3) + cc;
    int c = (cs << 6) + crel;
    const float* wp = wq1 + c * 12;
    float k0 = wp[0], k1 = wp[1], k2 = wp[2], k3 = wp[3], k4 = wp[4],
          k5 = wp[5], k6 = wp[6], k7 = wp[7], k8 = wp[8];
    const float* xp = x + (((size_t)((b << 7) | c)) << 15) + (h0 << 8) + w0;
    f32x4 rw[6];
    float lf[6], rt[6];
    #pragma unroll
    for (int i = 0; i < 6; i++) {
      int g = h0 - 1 + i;
      f32x4 v = {0.f, 0.f, 0.f, 0.f};
      if (g >= 0 && g <= 127) v = *(const f32x4*)(xp + ((i - 1) << 8));
      rw[i] = v;
      float lv = __shfl_up(v.w, 1), rv = __shfl_down(v.x, 1);
      if (wq == 0)  lv = 0.f;
      if (wq == 63) rv = 0.f;
      lf[i] = lv; rt[i] = rv;
    }
    f32x4 cs1v = cst1[c];
    int sh = (cc & 3) << 3;
    #pragma unroll
    for (int r = 0; r < 4; r++) {
      f32x4 vm = rw[r], v0 = rw[r + 1], vp = rw[r + 2];
      float lm = lf[r], l0 = lf[r + 1], lp = lf[r + 2];
      float rm = rt[r], r0 = rt[r + 1], rp = rt[r + 2];
      float y0 = 0.f, y1 = 0.f, y2 = 0.f, y3 = 0.f;
      // row -1 (k0,k1,k2), row 0 (k3,k4,k5), row +1 (k6,k7,k8) — r1/r2/r4 order
      y0 = fmaf(lm,   k0, y0); y0 = fmaf(vm.x, k1, y0); y0 = fmaf(vm.y, k2, y0);
      y1 = fmaf(vm.x, k0, y1); y1 = fmaf(vm.y, k1, y1); y1 = fmaf(vm.z, k2, y1);
      y2 = fmaf(vm.y, k0, y2); y2 = fmaf(vm.z, k1, y2); y2 = fmaf(vm.w, k2, y2);
      y3 = fmaf(vm.z, k0, y3); y3 = fmaf(vm.w, k1, y3); y3 = fmaf(rm,   k2, y3);

      y0 = fmaf(l0,   k3, y0); y0 = fmaf(v0.x, k4, y0); y0 = fmaf(v0.y, k5, y0);
      y1 = fmaf(v0.x, k3, y1); y1 = fmaf(v0.y, k4, y1); y1 = fmaf(v0.z, k5, y1);
      y2 = fmaf(v0.y, k3, y2); y2 = fmaf(v0.z, k4, y2); y2 = fmaf(v0.w, k5, y2);
      y3 = fmaf(v0.z, k3, y3); y3 = fmaf(v0.w, k4, y3); y3 = fmaf(r0,   k5, y3);

      y0 = fmaf(lp,   k6, y0); y0 = fmaf(vp.x, k7, y0); y0 = fmaf(vp.y, k8, y0);
      y1 = fmaf(vp.x, k6, y1); y1 = fmaf(vp.y, k7, y1); y1 = fmaf(vp.z, k8, y1);
      y2 = fmaf(vp.y, k6, y2); y2 = fmaf(vp.z, k7, y2); y2 = fmaf(vp.w, k8, y2);
      y3 = fmaf(vp.z, k6, y3); y3 = fmaf(vp.w, k7, y3); y3 = fmaf(rp,   k8, y3);

      accw[r][0] |= qstep(y0, cs1v, s_act) << sh;
      accw[r][1] |= qstep(y1, cs1v, s_act) << sh;
      accw[r][2] |= qstep(y2, cs1v, s_act) << sh;
      accw[r][3] |= qstep(y3, cs1v, s_act) << sh;
    }
    if ((cc & 3) == 3) {
      int c0 = (cg << 3) + (cc & 4);          // relative 4-ch base within the 64-ch half
      #pragma unroll
      for (int r = 0; r < 4; r++) {
        #pragma unroll
        for (int j = 0; j < 4; j++) {
          *(unsigned int*)(tile + (((r << 8) + w0 + j) << 6) + (c0 ^ sw)) = accw[r][j];
          accw[r][j] = 0;
        }
      }
    }
  }
  __syncthreads();
  // cooperative store: logical 16B chunk (p, s): physical chunk s^px2, words ^s23
  unsigned char* gout = (unsigned char*)(ws + OFF_BUFA) +
                        (((size_t)(((b << 7) | h0) << 8)) << 7) + (cs << 6);
  #pragma unroll
  for (int it = 0; it < 8; it++) {
    int idx = (it << 9) + tid;                  // [0, 4096)
    int p = idx >> 2, s = idx & 3;
    int px2 = (p >> 4) & 3, s23 = (p >> 2) & 3;
    u32x4 ch = *(const u32x4*)(tile + (p << 6) + ((s ^ px2) << 4));
    unsigned int t0 = ch.x, t1 = ch.y, t2 = ch.z, t3 = ch.w, tt;
    if (s23 & 1) { tt = t0; t0 = t1; t1 = tt; tt = t2; t2 = t3; t3 = tt; }
    if (s23 & 2) { tt = t0; t0 = t2; t2 = tt; tt = t1; t1 = t3; t3 = tt; }
    *(u32x4*)(gout + (size_t)p * 128 + (s << 4)) = u32x4{t0, t1, t2, t3};
  }
}

// ---------------- pointwise conv (bf16 MFMA, exact int) + BN + qrelu ----------------
__global__ __launch_bounds__(256) void pw_kernel(const unsigned char* __restrict__ in,
                                                 unsigned char* __restrict__ out,
                                                 const unsigned short* __restrict__ rbf,
                                                 const f32x4* __restrict__ cst,
                                                 const float* __restrict__ sp) {
  __shared__ unsigned char lds[8192];
  int tid = threadIdx.x;
  int p0 = blockIdx.x << 5;
  {
    int p = tid >> 3, q = tid & 7;
    int kc = q >> 1, lg = (q & 1) << 1, pt = p >> 4;
    u32x4 g = *(const u32x4*)(in + (size_t)(p0 + p) * 128 + q * 16);
    unsigned int a0, a1, a2, a3, a4, a5, a6, a7;
    cvt2(g.x, a0, a1); cvt2(g.y, a2, a3); cvt2(g.z, a4, a5); cvt2(g.w, a6, a7);
    int l1 = (p & 15) | (lg << 4);
    int ad = (((((pt << 2) + kc) << 6) | l1) << 4);
    *(u32x4*)(lds + ad)       = u32x4{a0, a1, a2, a3};
    *(u32x4*)(lds + ad + 256) = u32x4{a4, a5, a6, a7};
  }
  __syncthreads();
  int l = tid & 63, wv = tid >> 6;
  int ob = wv << 5;
  bf16x8 af[2][4];
  #pragma unroll
  for (int ot = 0; ot < 2; ot++)
    #pragma unroll
    for (int kc = 0; kc < 4; kc++) {
      int o = ob + (ot << 4) + (l & 15);
      int k = (kc << 5) + ((l >> 4) << 3);
      af[ot][kc] = *(const bf16x8*)(rbf + o * 128 + k);
    }
  f32x4 acc[2][2] = {{{0,0,0,0},{0,0,0,0}},{{0,0,0,0},{0,0,0,0}}};
  #pragma unroll
  for (int kc = 0; kc < 4; kc++) {
    bf16x8 b0 = *(const bf16x8*)(lds + (((kc << 6) + l) << 4));
    bf16x8 b1 = *(const bf16x8*)(lds + ((((4 + kc) << 6) + l) << 4));
    #pragma unroll
    for (int ot = 0; ot < 2; ot++) {
      acc[ot][0] = __builtin_amdgcn_mfma_f32_16x16x32_bf16(af[ot][kc], b0, acc[ot][0], 0, 0, 0);
      acc[ot][1] = __builtin_amdgcn_mfma_f32_16x16x32_bf16(af[ot][kc], b1, acc[ot][1], 0, 0, 0);
    }
  }
  float s_act = *sp;
  #pragma unroll
  for (int ot = 0; ot < 2; ot++) {
    int o0 = ob + (ot << 4) + ((l >> 4) << 2);
    f32x4 c0 = cst[o0], c1 = cst[o0 + 1], c2 = cst[o0 + 2], c3 = cst[o0 + 3];
    #pragma unroll
    for (int pt = 0; pt < 2; pt++) {
      int p = p0 + (pt << 4) + (l & 15);
      f32x4 a = acc[ot][pt];
      unsigned int pk = qstep(a.x, c0, s_act) | (qstep(a.y, c1, s_act) << 8) |
                        (qstep(a.z, c2, s_act) << 16) | (qstep(a.w, c3, s_act) << 24);
      *(unsigned int*)(out + (size_t)p * 128 + o0) = pk;
    }
  }
}

// ---------------- dw-conv2 (exact int in fp32) + BN3 + qrelu ----------------
__global__ __launch_bounds__(256) void dw2_kernel(const unsigned char* __restrict__ in,
                                                  unsigned char* __restrict__ out,
                                                  const char* __restrict__ ws,
                                                  const float* __restrict__ sp) {
  __shared__ float tabs[1664];
  const float* src = (const float*)(ws + OFF_R3F);
  for (int i = threadIdx.x; i < 1664; i += 256) tabs[i] = src[i];
  __syncthreads();
  int tid = threadIdx.x;
  int cq = tid & 31, pl = tid >> 5;
  int c4 = cq << 2;
  float wk[9][4];
  #pragma unroll
  for (int t = 0; t < 9; t++) {
    wk[t][0] = tabs[t * 128 + c4];     wk[t][1] = tabs[t * 128 + c4 + 1];
    wk[t][2] = tabs[t * 128 + c4 + 2]; wk[t][3] = tabs[t * 128 + c4 + 3];
  }
  const f32x4* cst3 = (const f32x4*)(tabs + 1152);
  f32x4 cs0 = cst3[c4], cs1 = cst3[c4 + 1], cs2 = cst3[c4 + 2], cs3 = cst3[c4 + 3];
  float s_act = *sp;
  int p0 = blockIdx.x << 5;
  #pragma unroll
  for (int j = 0; j < 4; j++) {
    int p = p0 + pl + (j << 3);
    int w = p & 255, hh = (p >> 8) & 127;
    float a0 = 0.f, a1 = 0.f, a2 = 0.f, a3 = 0.f;
    #pragma unroll
    for (int dh = -1; dh <= 1; dh++) {
      if (hh + dh < 0 || hh + dh > 127) continue;
      #pragma unroll
      for (int dw = -1; dw <= 1; dw++) {
        if (w + dw < 0 || w + dw > 255) continue;
        unsigned int v = *(const unsigned int*)(in + (size_t)(p + dh * 256 + dw) * 128 + c4);
        int t = (dh + 1) * 3 + (dw + 1);
        a0 = fmaf((float)(v & 0xffu),         wk[t][0], a0);
        a1 = fmaf((float)((v >> 8) & 0xffu),  wk[t][1], a1);
        a2 = fmaf((float)((v >> 16) & 0xffu), wk[t][2], a2);
        a3 = fmaf((float)(v >> 24),           wk[t][3], a3);
      }
    }
    unsigned int pk = qstep(a0, cs0, s_act) | (qstep(a1, cs1, s_act) << 8) |
                      (qstep(a2, cs2, s_act) << 16) | (qstep(a3, cs3, s_act) << 24);
    *(unsigned int*)(out + (size_t)p * 128 + c4) = pk;
  }
}

// ---------------- classifier ----------------
__global__ __launch_bounds__(256) void cls_kernel(const unsigned char* __restrict__ in,
                                                  float* __restrict__ out,
                                                  const unsigned short* __restrict__ r5,
                                                  const float2* __restrict__ cst5) {
  __shared__ unsigned char lds[16384];
  int tid = threadIdx.x;
  int p0 = blockIdx.x << 6;
  #pragma unroll
  for (int it = 0; it < 2; it++) {
    int idx = tid + (it << 8);
    int p = idx >> 3, q = idx & 7;
    int kc = q >> 1, lg = (q & 1) << 1, pt = p >> 4;
    u32x4 g = *(const u32x4*)(in + (size_t)(p0 + p) * 128 + q * 16);
    unsigned int a0, a1, a2, a3, a4, a5, a6, a7;
    cvt2(g.x, a0, a1); cvt2(g.y, a2, a3); cvt2(g.z, a4, a5); cvt2(g.w, a6, a7);
    int l1 = (p & 15) | (lg << 4);
    int ad = (((((pt << 2) + kc) << 6) | l1) << 4);
    *(u32x4*)(lds + ad)       = u32x4{a0, a1, a2, a3};
    *(u32x4*)(lds + ad + 256) = u32x4{a4, a5, a6, a7};
  }
  __syncthreads();
  int l = tid & 63, pt = tid >> 6;
  bf16x8 af[2][4];
  #pragma unroll
  for (int ot = 0; ot < 2; ot++)
    #pragma unroll
    for (int kc = 0; kc < 4; kc++) {
      int o = (ot << 4) + (l & 15);
      int k = (kc << 5) + ((l >> 4) << 3);
      af[ot][kc] = *(const bf16x8*)(r5 + o * 128 + k);
    }
  f32x4 acc[2] = {{0,0,0,0},{0,0,0,0}};
  #pragma unroll
  for (int kc = 0; kc < 4; kc++) {
    bf16x8 b = *(const bf16x8*)(lds + (((((pt << 2) + kc) << 6) + l) << 4));
    acc[0] = __builtin_amdgcn_mfma_f32_16x16x32_bf16(af[0][kc], b, acc[0], 0, 0, 0);
    acc[1] = __builtin_amdgcn_mfma_f32_16x16x32_bf16(af[1][kc], b, acc[1], 0, 0, 0);
  }
  int p = p0 + (pt << 4) + (l & 15);
  int bb = p >> 15, hw = p & 32767;
  float* ob = out + (((size_t)bb * 19) << 15) + hw;
  #pragma unroll
  for (int ot = 0; ot < 2; ot++) {
    int obase = (ot << 4) + ((l >> 4) << 2);
    f32x4 a = acc[ot];
    #pragma unroll
    for (int i = 0; i < 4; i++) {
      int o = obase + i;
      if (o < 19) {
        float2 c5 = cst5[o];
        ob[(size_t)o << 15] = fmaf(a[i], c5.x, c5.y);
      }
    }
  }
}

// ---------------- launch ----------------
extern "C" void kernel_launch(void* const* d_in, const int* in_sizes, int n_in,
                              void* d_out, int out_size, void* d_ws, size_t ws_size,
                              hipStream_t stream) {
  (void)in_sizes; (void)n_in; (void)out_size; (void)ws_size;
  char* ws = (char*)d_ws;
  PArgs P;
  P.dw1  = (const float*)d_in[1];
  P.pw1  = (const float*)d_in[2];
  P.dw2  = (const float*)d_in[3];
  P.pw2  = (const float*)d_in[4];
  P.clsw = (const float*)d_in[5];
  P.clsb = (const float*)d_in[6];
  P.g1 = (const float*)d_in[7];  P.b1 = (const float*)d_in[8];
  P.m1 = (const float*)d_in[9];  P.v1 = (const float*)d_in[10];
  P.g2 = (const float*)d_in[11]; P.b2 = (const float*)d_in[12];
  P.m2 = (const float*)d_in[13]; P.v2 = (const float*)d_in[14];
  P.g3 = (const float*)d_in[15]; P.b3 = (const float*)d_in[16];
  P.m3 = (const float*)d_in[17]; P.v3 = (const float*)d_in[18];
  P.g4 = (const float*)d_in[19]; P.b4 = (const float*)d_in[20];
  P.m4 = (const float*)d_in[21]; P.v4 = (const float*)d_in[22];
  P.s1 = (const float*)d_in[23]; P.s2 = (const float*)d_in[24];
  P.s3 = (const float*)d_in[25]; P.s4 = (const float*)d_in[26];

  const float* x = (const float*)d_in[0];
  unsigned char* bufA = (unsigned char*)(ws + OFF_BUFA);
  unsigned char* bufB = (unsigned char*)(ws + OFF_BUFB);

  prep_kernel<<<544, 64, 0, stream>>>(P, ws);
  dw1_kernel<<<512, 512, 0, stream>>>(x, ws, P.s1);                        // x -> k1 (A)
  pw_kernel<<<8192, 256, 0, stream>>>(bufA, bufB,
      (const unsigned short*)(ws + OFF_R2BF), (const f32x4*)(ws + OFF_CST2), P.s2);  // k1 -> k2 (B)
  dw2_kernel<<<8192, 256, 0, stream>>>(bufB, bufA, ws, P.s3);              // k2 -> k3 (A)
  pw_kernel<<<8192, 256, 0, stream>>>(bufA, bufB,
      (const unsigned short*)(ws + OFF_R4BF), (const f32x4*)(ws + OFF_CST4), P.s4);  // k3 -> k4 (B)
  cls_kernel<<<4096, 256, 0, stream>>>(bufB, (float*)d_out,
      (const unsigned short*)(ws + OFF_R5BF), (const float2*)(ws + OFF_CST5));       // k4 -> out
}

// Round 6
// 198.466 us; speedup vs baseline: 1.2439x; 1.2439x over previous
//
#include <hip/hip_runtime.h>

typedef __attribute__((ext_vector_type(4))) float f32x4;
typedef __attribute__((ext_vector_type(8))) short bf16x8;
typedef __attribute__((ext_vector_type(2))) unsigned int u32x2;
typedef __attribute__((ext_vector_type(4))) unsigned int u32x4;

#define EPSV 1e-5f

// workspace layout (bytes)
#define OFF_BUFA 0u
#define OFF_BUFB 33554432u
#define OFF_T    67108864u
#define OFF_WQ1  (OFF_T + 0u)       // f32 [128][12]  (9 taps used)
#define OFF_R3F  (OFF_T + 6144u)    // f32 [9][128]   integer-valued
#define OFF_CST3 (OFF_T + 10752u)   // f32x4 [128]
#define OFF_CST1 (OFF_T + 12800u)   // f32x4 [128]
#define OFF_R2BF (OFF_T + 14848u)   // bf16 [128][128]
#define OFF_CST2 (OFF_T + 47616u)   // f32x4 [128]
#define OFF_R4BF (OFF_T + 49664u)   // bf16 [128][128]
#define OFF_CST4 (OFF_T + 82432u)   // f32x4 [128]
#define OFF_R5BF (OFF_T + 84480u)   // bf16 [32][128] (rows 19..31 zero)
#define OFF_CST5 (OFF_T + 92672u)   // float2 [32]

struct PArgs {
  const float *dw1, *pw1, *dw2, *pw2, *clsw, *clsb;
  const float *g1, *b1, *m1, *v1;
  const float *g2, *b2, *m2, *v2;
  const float *g3, *b3, *m3, *v3;
  const float *g4, *b4, *m4, *v4;
  const float *s1, *s2, *s3, *s4;
};

__device__ __forceinline__ unsigned short f2bf(float f) {
  return (unsigned short)(__builtin_bit_cast(unsigned int, f) >> 16);
}
__device__ __forceinline__ float clip7(float r) { return fminf(fmaxf(r, -7.f), 7.f); }

// y = a*A; t = (y-m)*sc + b; k = clamp(rint(t/s),0,15).  c = {A, sc, m, b}
__device__ __forceinline__ unsigned int qstep(float a, f32x4 c, float s) {
  float t = (a * c.x - c.z) * c.y + c.w;
  float u = t / s;
  float k = fminf(fmaxf(rintf(u), 0.f), 15.f);
  return (unsigned int)k;
}

// 4 u8 -> 2 dwords of packed bf16
__device__ __forceinline__ void cvt2(unsigned int d, unsigned int &lo, unsigned int &hi) {
  float f0 = (float)(d & 0xffu);
  float f1 = (float)((d >> 8) & 0xffu);
  float f2 = (float)((d >> 16) & 0xffu);
  float f3 = (float)(d >> 24);
  lo = (__builtin_bit_cast(unsigned int, f0) >> 16) | (__builtin_bit_cast(unsigned int, f1) & 0xffff0000u);
  hi = (__builtin_bit_cast(unsigned int, f2) >> 16) | (__builtin_bit_cast(unsigned int, f3) & 0xffff0000u);
}

__device__ __forceinline__ float wmax16(float v) {
  #pragma unroll
  for (int s = 1; s < 16; s <<= 1) v = fmaxf(v, __shfl_xor(v, s));
  return v;
}
__device__ __forceinline__ float wmax64(float v) {
  #pragma unroll
  for (int s = 1; s < 64; s <<= 1) v = fmaxf(v, __shfl_xor(v, s));
  return v;
}

// ---------------- prep: quantize weights, fold BN constants ----------------
__global__ __launch_bounds__(64) void prep_kernel(PArgs P, char* __restrict__ ws) {
  int bi = blockIdx.x, l = threadIdx.x;
  float* wq1 = (float*)(ws + OFF_WQ1);
  float* r3f = (float*)(ws + OFF_R3F);
  f32x4* cst1 = (f32x4*)(ws + OFF_CST1);
  f32x4* cst2 = (f32x4*)(ws + OFF_CST2);
  f32x4* cst3 = (f32x4*)(ws + OFF_CST3);
  f32x4* cst4 = (f32x4*)(ws + OFF_CST4);
  unsigned short* r2 = (unsigned short*)(ws + OFF_R2BF);
  unsigned short* r4 = (unsigned short*)(ws + OFF_R4BF);
  unsigned short* r5 = (unsigned short*)(ws + OFF_R5BF);
  float2* cst5 = (float2*)(ws + OFF_CST5);

  if (bi < 128) {
    int c = bi;
    float w = (l < 9) ? P.dw1[c * 9 + l] : 0.f;
    float mx = wmax16(fabsf(w));
    float sq = fmaxf(mx / 7.0f, 1e-8f);
    if (l < 9) wq1[c * 12 + l] = clip7(rintf(w / sq)) * sq;
    if (l == 0) {
      float sc = P.g1[c] / sqrtf(P.v1[c] + EPSV);
      cst1[c] = f32x4{1.f, sc, P.m1[c], P.b1[c]};
    }
  } else if (bi < 256) {
    int o = bi - 128;
    float w0 = P.pw1[o * 128 + l], w1 = P.pw1[o * 128 + 64 + l];
    float mx = wmax64(fmaxf(fabsf(w0), fabsf(w1)));
    float sq = fmaxf(mx / 7.0f, 1e-8f);
    r2[o * 128 + l]      = f2bf(clip7(rintf(w0 / sq)));
    r2[o * 128 + 64 + l] = f2bf(clip7(rintf(w1 / sq)));
    if (l == 0) {
      float sc = P.g2[o] / sqrtf(P.v2[o] + EPSV);
      cst2[o] = f32x4{P.s1[0] * sq, sc, P.m2[o], P.b2[o]};
    }
  } else if (bi < 384) {
    int c = bi - 256;
    float w = (l < 9) ? P.dw2[c * 9 + l] : 0.f;
    float mx = wmax16(fabsf(w));
    float sq = fmaxf(mx / 7.0f, 1e-8f);
    if (l < 9) r3f[l * 128 + c] = clip7(rintf(w / sq));
    if (l == 0) {
      float sc = P.g3[c] / sqrtf(P.v3[c] + EPSV);
      cst3[c] = f32x4{P.s2[0] * sq, sc, P.m3[c], P.b3[c]};
    }
  } else if (bi < 512) {
    int o = bi - 384;
    float w0 = P.pw2[o * 128 + l], w1 = P.pw2[o * 128 + 64 + l];
    float mx = wmax64(fmaxf(fabsf(w0), fabsf(w1)));
    float sq = fmaxf(mx / 7.0f, 1e-8f);
    r4[o * 128 + l]      = f2bf(clip7(rintf(w0 / sq)));
    r4[o * 128 + 64 + l] = f2bf(clip7(rintf(w1 / sq)));
    if (l == 0) {
      float sc = P.g4[o] / sqrtf(P.v4[o] + EPSV);
      cst4[o] = f32x4{P.s3[0] * sq, sc, P.m4[o], P.b4[o]};
    }
  } else {
    int o = bi - 512;
    if (o < 19) {
      float w0 = P.clsw[o * 128 + l], w1 = P.clsw[o * 128 + 64 + l];
      float mx = wmax64(fmaxf(fabsf(w0), fabsf(w1)));
      float sq = fmaxf(mx / 7.0f, 1e-8f);
      r5[o * 128 + l]      = f2bf(clip7(rintf(w0 / sq)));
      r5[o * 128 + 64 + l] = f2bf(clip7(rintf(w1 / sq)));
      if (l == 0) {
        float A5 = P.s4[0] * sq;
        float bq = rintf(P.clsb[o] / A5) * A5;
        cst5[o] = make_float2(A5, bq);
      }
    } else {
      r5[o * 128 + l] = 0; r5[o * 128 + 64 + l] = 0;
      if (l == 0) cst5[o] = make_float2(0.f, 0.f);
    }
  }
}

// ---------------- dw-conv1 (v4, frozen): (b,h)-row blocks, 8 waves ----------------
__global__ __launch_bounds__(512) void dw1_kernel(const float* __restrict__ x,
                                                  char* __restrict__ ws,
                                                  const float* __restrict__ s1p) {
  __shared__ __align__(16) unsigned char tile[32768];
  int bid = blockIdx.x;
  int orig = ((bid & 7) << 7) + (bid >> 3);   // XCD x owns image b=x, h sequential
  int b = orig >> 7, h = orig & 127;
  int tid = threadIdx.x;
  int wq = tid & 63, cg = tid >> 6;
  const float* wq1 = (const float*)(ws + OFF_WQ1);
  const f32x4* cst1 = (const f32x4*)(ws + OFF_CST1);
  float s_act = *s1p;
  int w0 = wq << 2;
  int sw = (wq & 31) << 2;
  int cbase = cg << 4;

  unsigned int acc0 = 0, acc1 = 0, acc2 = 0, acc3 = 0;
  #pragma unroll 4
  for (int cc = 0; cc < 16; cc++) {
    int c = cbase + cc;
    const float* wp = wq1 + c * 12;
    float k0 = wp[0], k1 = wp[1], k2 = wp[2], k3 = wp[3], k4 = wp[4],
          k5 = wp[5], k6 = wp[6], k7 = wp[7], k8 = wp[8];
    const float* xp = x + (((size_t)((b << 7) | c)) << 15) + (h << 8) + w0;
    f32x4 vm = {0.f, 0.f, 0.f, 0.f}, vp = {0.f, 0.f, 0.f, 0.f};
    f32x4 v0 = *(const f32x4*)(xp);
    if (h > 0)   vm = *(const f32x4*)(xp - 256);
    if (h < 127) vp = *(const f32x4*)(xp + 256);
    float lm = __shfl_up(vm.w, 1), l0 = __shfl_up(v0.w, 1), lp = __shfl_up(vp.w, 1);
    float rm = __shfl_down(vm.x, 1), r0 = __shfl_down(v0.x, 1), rp = __shfl_down(vp.x, 1);
    if (wq == 0)  { lm = 0.f; l0 = 0.f; lp = 0.f; }
    if (wq == 63) { rm = 0.f; r0 = 0.f; rp = 0.f; }

    float y0 = 0.f, y1 = 0.f, y2 = 0.f, y3 = 0.f;
    // row -1 (k0,k1,k2) then row 0 (k3,k4,k5) then row +1 (k6,k7,k8) — r1 order
    y0 = fmaf(lm,   k0, y0); y0 = fmaf(vm.x, k1, y0); y0 = fmaf(vm.y, k2, y0);
    y1 = fmaf(vm.x, k0, y1); y1 = fmaf(vm.y, k1, y1); y1 = fmaf(vm.z, k2, y1);
    y2 = fmaf(vm.y, k0, y2); y2 = fmaf(vm.z, k1, y2); y2 = fmaf(vm.w, k2, y2);
    y3 = fmaf(vm.z, k0, y3); y3 = fmaf(vm.w, k1, y3); y3 = fmaf(rm,   k2, y3);

    y0 = fmaf(l0,   k3, y0); y0 = fmaf(v0.x, k4, y0); y0 = fmaf(v0.y, k5, y0);
    y1 = fmaf(v0.x, k3, y1); y1 = fmaf(v0.y, k4, y1); y1 = fmaf(v0.z, k5, y1);
    y2 = fmaf(v0.y, k3, y2); y2 = fmaf(v0.z, k4, y2); y2 = fmaf(v0.w, k5, y2);
    y3 = fmaf(v0.z, k3, y3); y3 = fmaf(v0.w, k4, y3); y3 = fmaf(r0,   k5, y3);

    y0 = fmaf(lp,   k6, y0); y0 = fmaf(vp.x, k7, y0); y0 = fmaf(vp.y, k8, y0);
    y1 = fmaf(vp.x, k6, y1); y1 = fmaf(vp.y, k7, y1); y1 = fmaf(vp.z, k8, y1);
    y2 = fmaf(vp.y, k6, y2); y2 = fmaf(vp.z, k7, y2); y2 = fmaf(vp.w, k8, y2);
    y3 = fmaf(vp.z, k6, y3); y3 = fmaf(vp.w, k7, y3); y3 = fmaf(rp,   k8, y3);

    f32x4 cs = cst1[c];
    int sh = (cc & 3) << 3;
    acc0 |= qstep(y0, cs, s_act) << sh;
    acc1 |= qstep(y1, cs, s_act) << sh;
    acc2 |= qstep(y2, cs, s_act) << sh;
    acc3 |= qstep(y3, cs, s_act) << sh;
    if ((cc & 3) == 3) {
      int c0 = c - 3;
      *(unsigned int*)(tile + ((w0 + 0) << 7) + (c0 ^ sw)) = acc0;
      *(unsigned int*)(tile + ((w0 + 1) << 7) + (c0 ^ sw)) = acc1;
      *(unsigned int*)(tile + ((w0 + 2) << 7) + (c0 ^ sw)) = acc2;
      *(unsigned int*)(tile + ((w0 + 3) << 7) + (c0 ^ sw)) = acc3;
      acc0 = acc1 = acc2 = acc3 = 0;
    }
  }
  __syncthreads();
  // cooperative store: logical 16B chunk g=(p,s); physical chunk s^px, words ^s23
  unsigned char* gout = (unsigned char*)(ws + OFF_BUFA) + ((size_t)orig << 15);
  #pragma unroll
  for (int it = 0; it < 4; it++) {
    int idx = (it << 9) + tid;
    int p = idx >> 3, s = idx & 7;
    int px = (p >> 4) & 7, s23 = (p >> 2) & 3;
    u32x4 ch = *(const u32x4*)(tile + (p << 7) + ((s ^ px) << 4));
    unsigned int t0 = ch.x, t1 = ch.y, t2 = ch.z, t3 = ch.w, tt;
    if (s23 & 1) { tt = t0; t0 = t1; t1 = tt; tt = t2; t2 = t3; t3 = tt; }
    if (s23 & 2) { tt = t0; t0 = t2; t2 = tt; tt = t1; t1 = t3; t3 = tt; }
    *(u32x4*)(gout + (idx << 4)) = u32x4{t0, t1, t2, t3};
  }
}

// ---------------- pointwise conv v2: 128 positions/block (bf16 MFMA, exact int) ----------------
// grid 2048. Staging layout = same fragment scheme, pt extended to [0,8). 64 MFMA/wave.
__global__ __launch_bounds__(256) void pw_kernel(const unsigned char* __restrict__ in,
                                                 unsigned char* __restrict__ out,
                                                 const unsigned short* __restrict__ rbf,
                                                 const f32x4* __restrict__ cst,
                                                 const float* __restrict__ sp) {
  __shared__ unsigned char lds[32768];
  int tid = threadIdx.x;
  int p0 = blockIdx.x << 7;
  #pragma unroll
  for (int it = 0; it < 4; it++) {
    int idx = tid + (it << 8);
    int p = idx >> 3, q = idx & 7;
    int kc = q >> 1, lg = (q & 1) << 1, pt = p >> 4;
    u32x4 g = *(const u32x4*)(in + (size_t)(p0 + p) * 128 + q * 16);
    unsigned int a0, a1, a2, a3, a4, a5, a6, a7;
    cvt2(g.x, a0, a1); cvt2(g.y, a2, a3); cvt2(g.z, a4, a5); cvt2(g.w, a6, a7);
    int l1 = (p & 15) | (lg << 4);
    int ad = (((((pt << 2) + kc) << 6) | l1) << 4);
    *(u32x4*)(lds + ad)       = u32x4{a0, a1, a2, a3};
    *(u32x4*)(lds + ad + 256) = u32x4{a4, a5, a6, a7};
  }
  __syncthreads();
  int l = tid & 63, wv = tid >> 6;
  int ob = wv << 5;                          // wave owns 32 output channels
  bf16x8 af[2][4];
  #pragma unroll
  for (int ot = 0; ot < 2; ot++)
    #pragma unroll
    for (int kc = 0; kc < 4; kc++) {
      int o = ob + (ot << 4) + (l & 15);
      int k = (kc << 5) + ((l >> 4) << 3);
      af[ot][kc] = *(const bf16x8*)(rbf + o * 128 + k);
    }
  f32x4 acc[2][8];
  #pragma unroll
  for (int ot = 0; ot < 2; ot++)
    #pragma unroll
    for (int pt = 0; pt < 8; pt++) acc[ot][pt] = f32x4{0.f, 0.f, 0.f, 0.f};
  #pragma unroll
  for (int kc = 0; kc < 4; kc++) {
    bf16x8 bb[8];
    #pragma unroll
    for (int pt = 0; pt < 8; pt++)
      bb[pt] = *(const bf16x8*)(lds + ((((((pt << 2) + kc) << 6)) + l) << 4));
    #pragma unroll
    for (int ot = 0; ot < 2; ot++)
      #pragma unroll
      for (int pt = 0; pt < 8; pt++)
        acc[ot][pt] = __builtin_amdgcn_mfma_f32_16x16x32_bf16(af[ot][kc], bb[pt], acc[ot][pt], 0, 0, 0);
  }
  float s_act = *sp;
  #pragma unroll
  for (int ot = 0; ot < 2; ot++) {
    int o0 = ob + (ot << 4) + ((l >> 4) << 2);
    f32x4 c0 = cst[o0], c1 = cst[o0 + 1], c2 = cst[o0 + 2], c3 = cst[o0 + 3];
    #pragma unroll
    for (int pt = 0; pt < 8; pt++) {
      int p = p0 + (pt << 4) + (l & 15);
      f32x4 a = acc[ot][pt];
      unsigned int pk = qstep(a.x, c0, s_act) | (qstep(a.y, c1, s_act) << 8) |
                        (qstep(a.z, c2, s_act) << 16) | (qstep(a.w, c3, s_act) << 24);
      *(unsigned int*)(out + (size_t)p * 128 + o0) = pk;
    }
  }
}

// ---------------- dw-conv2 (exact int in fp32) + BN3 + qrelu ----------------
__global__ __launch_bounds__(256) void dw2_kernel(const unsigned char* __restrict__ in,
                                                  unsigned char* __restrict__ out,
                                                  const char* __restrict__ ws,
                                                  const float* __restrict__ sp) {
  __shared__ float tabs[1664];
  const float* src = (const float*)(ws + OFF_R3F);
  for (int i = threadIdx.x; i < 1664; i += 256) tabs[i] = src[i];
  __syncthreads();
  int tid = threadIdx.x;
  int cq = tid & 31, pl = tid >> 5;
  int c4 = cq << 2;
  float wk[9][4];
  #pragma unroll
  for (int t = 0; t < 9; t++) {
    wk[t][0] = tabs[t * 128 + c4];     wk[t][1] = tabs[t * 128 + c4 + 1];
    wk[t][2] = tabs[t * 128 + c4 + 2]; wk[t][3] = tabs[t * 128 + c4 + 3];
  }
  const f32x4* cst3 = (const f32x4*)(tabs + 1152);
  f32x4 cs0 = cst3[c4], cs1 = cst3[c4 + 1], cs2 = cst3[c4 + 2], cs3 = cst3[c4 + 3];
  float s_act = *sp;
  int p0 = blockIdx.x << 5;
  #pragma unroll
  for (int j = 0; j < 4; j++) {
    int p = p0 + pl + (j << 3);
    int w = p & 255, hh = (p >> 8) & 127;
    float a0 = 0.f, a1 = 0.f, a2 = 0.f, a3 = 0.f;
    #pragma unroll
    for (int dh = -1; dh <= 1; dh++) {
      if (hh + dh < 0 || hh + dh > 127) continue;
      #pragma unroll
      for (int dw = -1; dw <= 1; dw++) {
        if (w + dw < 0 || w + dw > 255) continue;
        unsigned int v = *(const unsigned int*)(in + (size_t)(p + dh * 256 + dw) * 128 + c4);
        int t = (dh + 1) * 3 + (dw + 1);
        a0 = fmaf((float)(v & 0xffu),         wk[t][0], a0);
        a1 = fmaf((float)((v >> 8) & 0xffu),  wk[t][1], a1);
        a2 = fmaf((float)((v >> 16) & 0xffu), wk[t][2], a2);
        a3 = fmaf((float)(v >> 24),           wk[t][3], a3);
      }
    }
    unsigned int pk = qstep(a0, cs0, s_act) | (qstep(a1, cs1, s_act) << 8) |
                      (qstep(a2, cs2, s_act) << 16) | (qstep(a3, cs3, s_act) << 24);
    *(unsigned int*)(out + (size_t)p * 128 + c4) = pk;
  }
}

// ---------------- classifier v2: 128 positions/block ----------------
__global__ __launch_bounds__(256) void cls_kernel(const unsigned char* __restrict__ in,
                                                  float* __restrict__ out,
                                                  const unsigned short* __restrict__ r5,
                                                  const float2* __restrict__ cst5) {
  __shared__ unsigned char lds[32768];
  int tid = threadIdx.x;
  int p0 = blockIdx.x << 7;
  #pragma unroll
  for (int it = 0; it < 4; it++) {
    int idx = tid + (it << 8);
    int p = idx >> 3, q = idx & 7;
    int kc = q >> 1, lg = (q & 1) << 1, pt = p >> 4;
    u32x4 g = *(const u32x4*)(in + (size_t)(p0 + p) * 128 + q * 16);
    unsigned int a0, a1, a2, a3, a4, a5, a6, a7;
    cvt2(g.x, a0, a1); cvt2(g.y, a2, a3); cvt2(g.z, a4, a5); cvt2(g.w, a6, a7);
    int l1 = (p & 15) | (lg << 4);
    int ad = (((((pt << 2) + kc) << 6) | l1) << 4);
    *(u32x4*)(lds + ad)       = u32x4{a0, a1, a2, a3};
    *(u32x4*)(lds + ad + 256) = u32x4{a4, a5, a6, a7};
  }
  __syncthreads();
  int l = tid & 63, wv = tid >> 6;
  int pt0 = wv << 1;                          // wave owns 2 position tiles
  bf16x8 af[2][4];
  #pragma unroll
  for (int ot = 0; ot < 2; ot++)
    #pragma unroll
    for (int kc = 0; kc < 4; kc++) {
      int o = (ot << 4) + (l & 15);
      int k = (kc << 5) + ((l >> 4) << 3);
      af[ot][kc] = *(const bf16x8*)(r5 + o * 128 + k);
    }
  f32x4 acc[2][2] = {{{0,0,0,0},{0,0,0,0}},{{0,0,0,0},{0,0,0,0}}};
  #pragma unroll
  for (int kc = 0; kc < 4; kc++) {
    bf16x8 b0 = *(const bf16x8*)(lds + ((((((pt0    ) << 2) + kc) << 6) + l) << 4));
    bf16x8 b1 = *(const bf16x8*)(lds + ((((((pt0 + 1) << 2) + kc) << 6) + l) << 4));
    #pragma unroll
    for (int ot = 0; ot < 2; ot++) {
      acc[ot][0] = __builtin_amdgcn_mfma_f32_16x16x32_bf16(af[ot][kc], b0, acc[ot][0], 0, 0, 0);
      acc[ot][1] = __builtin_amdgcn_mfma_f32_16x16x32_bf16(af[ot][kc], b1, acc[ot][1], 0, 0, 0);
    }
  }
  #pragma unroll
  for (int ptl = 0; ptl < 2; ptl++) {
    int p = p0 + ((pt0 + ptl) << 4) + (l & 15);
    int bb = p >> 15, hw = p & 32767;
    float* ob = out + (((size_t)bb * 19) << 15) + hw;
    #pragma unroll
    for (int ot = 0; ot < 2; ot++) {
      int obase = (ot << 4) + ((l >> 4) << 2);
      f32x4 a = acc[ot][ptl];
      #pragma unroll
      for (int i = 0; i < 4; i++) {
        int o = obase + i;
        if (o < 19) {
          float2 c5 = cst5[o];
          ob[(size_t)o << 15] = fmaf(a[i], c5.x, c5.y);
        }
      }
    }
  }
}

// ---------------- launch ----------------
extern "C" void kernel_launch(void* const* d_in, const int* in_sizes, int n_in,
                              void* d_out, int out_size, void* d_ws, size_t ws_size,
                              hipStream_t stream) {
  (void)in_sizes; (void)n_in; (void)out_size; (void)ws_size;
  char* ws = (char*)d_ws;
  PArgs P;
  P.dw1  = (const float*)d_in[1];
  P.pw1  = (const float*)d_in[2];
  P.dw2  = (const float*)d_in[3];
  P.pw2  = (const float*)d_in[4];
  P.clsw = (const float*)d_in[5];
  P.clsb = (const float*)d_in[6];
  P.g1 = (const float*)d_in[7];  P.b1 = (const float*)d_in[8];
  P.m1 = (const float*)d_in[9];  P.v1 = (const float*)d_in[10];
  P.g2 = (const float*)d_in[11]; P.b2 = (const float*)d_in[12];
  P.m2 = (const float*)d_in[13]; P.v2 = (const float*)d_in[14];
  P.g3 = (const float*)d_in[15]; P.b3 = (const float*)d_in[16];
  P.m3 = (const float*)d_in[17]; P.v3 = (const float*)d_in[18];
  P.g4 = (const float*)d_in[19]; P.b4 = (const float*)d_in[20];
  P.m4 = (const float*)d_in[21]; P.v4 = (const float*)d_in[22];
  P.s1 = (const float*)d_in[23]; P.s2 = (const float*)d_in[24];
  P.s3 = (const float*)d_in[25]; P.s4 = (const float*)d_in[26];

  const float* x = (const float*)d_in[0];
  unsigned char* bufA = (unsigned char*)(ws + OFF_BUFA);
  unsigned char* bufB = (unsigned char*)(ws + OFF_BUFB);

  prep_kernel<<<544, 64, 0, stream>>>(P, ws);
  dw1_kernel<<<1024, 512, 0, stream>>>(x, ws, P.s1);                       // x -> k1 (A)
  pw_kernel<<<2048, 256, 0, stream>>>(bufA, bufB,
      (const unsigned short*)(ws + OFF_R2BF), (const f32x4*)(ws + OFF_CST2), P.s2);  // k1 -> k2 (B)
  dw2_kernel<<<8192, 256, 0, stream>>>(bufB, bufA, ws, P.s3);              // k2 -> k3 (A)
  pw_kernel<<<2048, 256, 0, stream>>>(bufA, bufB,
      (const unsigned short*)(ws + OFF_R4BF), (const f32x4*)(ws + OFF_CST4), P.s4);  // k3 -> k4 (B)
  cls_kernel<<<2048, 256, 0, stream>>>(bufB, (float*)d_out,
      (const unsigned short*)(ws + OFF_R5BF), (const float2*)(ws + OFF_CST5));       // k4 -> out
}

// Round 7
// 166.772 us; speedup vs baseline: 1.4803x; 1.1900x over previous
//
#include <hip/hip_runtime.h>

typedef __attribute__((ext_vector_type(4))) float f32x4;
typedef __attribute__((ext_vector_type(8))) short bf16x8;
typedef __attribute__((ext_vector_type(2))) unsigned int u32x2;
typedef __attribute__((ext_vector_type(4))) unsigned int u32x4;

#define EPSV 1e-5f

// workspace layout (bytes)
#define OFF_BUFA 0u
#define OFF_BUFB 33554432u
#define OFF_T    67108864u
#define OFF_WQ1  (OFF_T + 0u)       // f32 [128][12]  (9 taps used)
#define OFF_R3F  (OFF_T + 6144u)    // f32 [9][128]   integer-valued
#define OFF_CST3 (OFF_T + 10752u)   // f32x4 [128]
#define OFF_CST1 (OFF_T + 12800u)   // f32x4 [128]
#define OFF_R2BF (OFF_T + 14848u)   // bf16 [128][128]
#define OFF_CST2 (OFF_T + 47616u)   // f32x4 [128]
#define OFF_R4BF (OFF_T + 49664u)   // bf16 [128][128]
#define OFF_CST4 (OFF_T + 82432u)   // f32x4 [128]
#define OFF_R5BF (OFF_T + 84480u)   // bf16 [32][128] (rows 19..31 zero)
#define OFF_CST5 (OFF_T + 92672u)   // float2 [32]

struct PArgs {
  const float *dw1, *pw1, *dw2, *pw2, *clsw, *clsb;
  const float *g1, *b1, *m1, *v1;
  const float *g2, *b2, *m2, *v2;
  const float *g3, *b3, *m3, *v3;
  const float *g4, *b4, *m4, *v4;
  const float *s1, *s2, *s3, *s4;
};

__device__ __forceinline__ unsigned short f2bf(float f) {
  return (unsigned short)(__builtin_bit_cast(unsigned int, f) >> 16);
}
__device__ __forceinline__ float clip7(float r) { return fminf(fmaxf(r, -7.f), 7.f); }

// y = a*A; t = (y-m)*sc + b; k = clamp(rint(t/s),0,15).  c = {A, sc, m, b}
__device__ __forceinline__ unsigned int qstep(float a, f32x4 c, float s) {
  float t = (a * c.x - c.z) * c.y + c.w;
  float u = t / s;
  float k = fminf(fmaxf(rintf(u), 0.f), 15.f);
  return (unsigned int)k;
}

// 4 u8 -> 2 dwords of packed bf16
__device__ __forceinline__ void cvt2(unsigned int d, unsigned int &lo, unsigned int &hi) {
  float f0 = (float)(d & 0xffu);
  float f1 = (float)((d >> 8) & 0xffu);
  float f2 = (float)((d >> 16) & 0xffu);
  float f3 = (float)(d >> 24);
  lo = (__builtin_bit_cast(unsigned int, f0) >> 16) | (__builtin_bit_cast(unsigned int, f1) & 0xffff0000u);
  hi = (__builtin_bit_cast(unsigned int, f2) >> 16) | (__builtin_bit_cast(unsigned int, f3) & 0xffff0000u);
}

__device__ __forceinline__ float wmax16(float v) {
  #pragma unroll
  for (int s = 1; s < 16; s <<= 1) v = fmaxf(v, __shfl_xor(v, s));
  return v;
}
__device__ __forceinline__ float wmax64(float v) {
  #pragma unroll
  for (int s = 1; s < 64; s <<= 1) v = fmaxf(v, __shfl_xor(v, s));
  return v;
}

// ---------------- prep: quantize weights, fold BN constants ----------------
__global__ __launch_bounds__(64) void prep_kernel(PArgs P, char* __restrict__ ws) {
  int bi = blockIdx.x, l = threadIdx.x;
  float* wq1 = (float*)(ws + OFF_WQ1);
  float* r3f = (float*)(ws + OFF_R3F);
  f32x4* cst1 = (f32x4*)(ws + OFF_CST1);
  f32x4* cst2 = (f32x4*)(ws + OFF_CST2);
  f32x4* cst3 = (f32x4*)(ws + OFF_CST3);
  f32x4* cst4 = (f32x4*)(ws + OFF_CST4);
  unsigned short* r2 = (unsigned short*)(ws + OFF_R2BF);
  unsigned short* r4 = (unsigned short*)(ws + OFF_R4BF);
  unsigned short* r5 = (unsigned short*)(ws + OFF_R5BF);
  float2* cst5 = (float2*)(ws + OFF_CST5);

  if (bi < 128) {
    int c = bi;
    float w = (l < 9) ? P.dw1[c * 9 + l] : 0.f;
    float mx = wmax16(fabsf(w));
    float sq = fmaxf(mx / 7.0f, 1e-8f);
    if (l < 9) wq1[c * 12 + l] = clip7(rintf(w / sq)) * sq;
    if (l == 0) {
      float sc = P.g1[c] / sqrtf(P.v1[c] + EPSV);
      cst1[c] = f32x4{1.f, sc, P.m1[c], P.b1[c]};
    }
  } else if (bi < 256) {
    int o = bi - 128;
    float w0 = P.pw1[o * 128 + l], w1 = P.pw1[o * 128 + 64 + l];
    float mx = wmax64(fmaxf(fabsf(w0), fabsf(w1)));
    float sq = fmaxf(mx / 7.0f, 1e-8f);
    r2[o * 128 + l]      = f2bf(clip7(rintf(w0 / sq)));
    r2[o * 128 + 64 + l] = f2bf(clip7(rintf(w1 / sq)));
    if (l == 0) {
      float sc = P.g2[o] / sqrtf(P.v2[o] + EPSV);
      cst2[o] = f32x4{P.s1[0] * sq, sc, P.m2[o], P.b2[o]};
    }
  } else if (bi < 384) {
    int c = bi - 256;
    float w = (l < 9) ? P.dw2[c * 9 + l] : 0.f;
    float mx = wmax16(fabsf(w));
    float sq = fmaxf(mx / 7.0f, 1e-8f);
    if (l < 9) r3f[l * 128 + c] = clip7(rintf(w / sq));
    if (l == 0) {
      float sc = P.g3[c] / sqrtf(P.v3[c] + EPSV);
      cst3[c] = f32x4{P.s2[0] * sq, sc, P.m3[c], P.b3[c]};
    }
  } else if (bi < 512) {
    int o = bi - 384;
    float w0 = P.pw2[o * 128 + l], w1 = P.pw2[o * 128 + 64 + l];
    float mx = wmax64(fmaxf(fabsf(w0), fabsf(w1)));
    float sq = fmaxf(mx / 7.0f, 1e-8f);
    r4[o * 128 + l]      = f2bf(clip7(rintf(w0 / sq)));
    r4[o * 128 + 64 + l] = f2bf(clip7(rintf(w1 / sq)));
    if (l == 0) {
      float sc = P.g4[o] / sqrtf(P.v4[o] + EPSV);
      cst4[o] = f32x4{P.s3[0] * sq, sc, P.m4[o], P.b4[o]};
    }
  } else {
    int o = bi - 512;
    if (o < 19) {
      float w0 = P.clsw[o * 128 + l], w1 = P.clsw[o * 128 + 64 + l];
      float mx = wmax64(fmaxf(fabsf(w0), fabsf(w1)));
      float sq = fmaxf(mx / 7.0f, 1e-8f);
      r5[o * 128 + l]      = f2bf(clip7(rintf(w0 / sq)));
      r5[o * 128 + 64 + l] = f2bf(clip7(rintf(w1 / sq)));
      if (l == 0) {
        float A5 = P.s4[0] * sq;
        float bq = rintf(P.clsb[o] / A5) * A5;
        cst5[o] = make_float2(A5, bq);
      }
    } else {
      r5[o * 128 + l] = 0; r5[o * 128 + 64 + l] = 0;
      if (l == 0) cst5[o] = make_float2(0.f, 0.f);
    }
  }
}

// ---------------- dw-conv1 v6: v4 structure, VGPR forced <=64 (8 waves/EU) ----------------
// block=(b,h), 512 threads; __launch_bounds__(512,8) -> VGPR<=64 -> 32 waves/CU resident.
// fmaf order identical to r1/r2/r4 -> bit-identical output.
__global__ __launch_bounds__(512, 8) void dw1_kernel(const float* __restrict__ x,
                                                     char* __restrict__ ws,
                                                     const float* __restrict__ s1p) {
  __shared__ __align__(16) unsigned char tile[32768];
  int bid = blockIdx.x;
  int orig = ((bid & 7) << 7) + (bid >> 3);   // XCD x owns image b=x, h sequential
  int b = orig >> 7, h = orig & 127;
  int tid = threadIdx.x;
  int wq = tid & 63, cg = tid >> 6;
  const float* wq1 = (const float*)(ws + OFF_WQ1);
  const f32x4* cst1 = (const f32x4*)(ws + OFF_CST1);
  float s_act = *s1p;
  int w0 = wq << 2;
  int sw = (wq & 31) << 2;
  int cbase = cg << 4;

  unsigned int acc0 = 0, acc1 = 0, acc2 = 0, acc3 = 0;
  #pragma unroll 2
  for (int cc = 0; cc < 16; cc++) {
    int c = cbase + cc;
    const float* wp = wq1 + c * 12;
    float k0 = wp[0], k1 = wp[1], k2 = wp[2], k3 = wp[3], k4 = wp[4],
          k5 = wp[5], k6 = wp[6], k7 = wp[7], k8 = wp[8];
    const float* xp = x + (((size_t)((b << 7) | c)) << 15) + (h << 8) + w0;
    f32x4 vm = {0.f, 0.f, 0.f, 0.f}, vp = {0.f, 0.f, 0.f, 0.f};
    f32x4 v0 = *(const f32x4*)(xp);
    if (h > 0)   vm = *(const f32x4*)(xp - 256);
    if (h < 127) vp = *(const f32x4*)(xp + 256);
    float lm = __shfl_up(vm.w, 1), l0 = __shfl_up(v0.w, 1), lp = __shfl_up(vp.w, 1);
    float rm = __shfl_down(vm.x, 1), r0 = __shfl_down(v0.x, 1), rp = __shfl_down(vp.x, 1);
    if (wq == 0)  { lm = 0.f; l0 = 0.f; lp = 0.f; }
    if (wq == 63) { rm = 0.f; r0 = 0.f; rp = 0.f; }

    float y0 = 0.f, y1 = 0.f, y2 = 0.f, y3 = 0.f;
    // row -1 (k0,k1,k2) then row 0 (k3,k4,k5) then row +1 (k6,k7,k8) — r1 order
    y0 = fmaf(lm,   k0, y0); y0 = fmaf(vm.x, k1, y0); y0 = fmaf(vm.y, k2, y0);
    y1 = fmaf(vm.x, k0, y1); y1 = fmaf(vm.y, k1, y1); y1 = fmaf(vm.z, k2, y1);
    y2 = fmaf(vm.y, k0, y2); y2 = fmaf(vm.z, k1, y2); y2 = fmaf(vm.w, k2, y2);
    y3 = fmaf(vm.z, k0, y3); y3 = fmaf(vm.w, k1, y3); y3 = fmaf(rm,   k2, y3);

    y0 = fmaf(l0,   k3, y0); y0 = fmaf(v0.x, k4, y0); y0 = fmaf(v0.y, k5, y0);
    y1 = fmaf(v0.x, k3, y1); y1 = fmaf(v0.y, k4, y1); y1 = fmaf(v0.z, k5, y1);
    y2 = fmaf(v0.y, k3, y2); y2 = fmaf(v0.z, k4, y2); y2 = fmaf(v0.w, k5, y2);
    y3 = fmaf(v0.z, k3, y3); y3 = fmaf(v0.w, k4, y3); y3 = fmaf(r0,   k5, y3);

    y0 = fmaf(lp,   k6, y0); y0 = fmaf(vp.x, k7, y0); y0 = fmaf(vp.y, k8, y0);
    y1 = fmaf(vp.x, k6, y1); y1 = fmaf(vp.y, k7, y1); y1 = fmaf(vp.z, k8, y1);
    y2 = fmaf(vp.y, k6, y2); y2 = fmaf(vp.z, k7, y2); y2 = fmaf(vp.w, k8, y2);
    y3 = fmaf(vp.z, k6, y3); y3 = fmaf(vp.w, k7, y3); y3 = fmaf(rp,   k8, y3);

    f32x4 cs = cst1[c];
    int sh = (cc & 3) << 3;
    acc0 |= qstep(y0, cs, s_act) << sh;
    acc1 |= qstep(y1, cs, s_act) << sh;
    acc2 |= qstep(y2, cs, s_act) << sh;
    acc3 |= qstep(y3, cs, s_act) << sh;
    if ((cc & 3) == 3) {
      int c0 = c - 3;
      *(unsigned int*)(tile + ((w0 + 0) << 7) + (c0 ^ sw)) = acc0;
      *(unsigned int*)(tile + ((w0 + 1) << 7) + (c0 ^ sw)) = acc1;
      *(unsigned int*)(tile + ((w0 + 2) << 7) + (c0 ^ sw)) = acc2;
      *(unsigned int*)(tile + ((w0 + 3) << 7) + (c0 ^ sw)) = acc3;
      acc0 = acc1 = acc2 = acc3 = 0;
    }
  }
  __syncthreads();
  // cooperative store: logical 16B chunk g=(p,s); physical chunk s^px, words ^s23
  unsigned char* gout = (unsigned char*)(ws + OFF_BUFA) + ((size_t)orig << 15);
  #pragma unroll
  for (int it = 0; it < 4; it++) {
    int idx = (it << 9) + tid;
    int p = idx >> 3, s = idx & 7;
    int px = (p >> 4) & 7, s23 = (p >> 2) & 3;
    u32x4 ch = *(const u32x4*)(tile + (p << 7) + ((s ^ px) << 4));
    unsigned int t0 = ch.x, t1 = ch.y, t2 = ch.z, t3 = ch.w, tt;
    if (s23 & 1) { tt = t0; t0 = t1; t1 = tt; tt = t2; t2 = t3; t3 = tt; }
    if (s23 & 2) { tt = t0; t0 = t2; t2 = tt; tt = t1; t1 = t3; t3 = tt; }
    *(u32x4*)(gout + (idx << 4)) = u32x4{t0, t1, t2, t3};
  }
}

// ---------------- pointwise conv v2: 128 positions/block (bf16 MFMA, exact int) ----------------
__global__ __launch_bounds__(256) void pw_kernel(const unsigned char* __restrict__ in,
                                                 unsigned char* __restrict__ out,
                                                 const unsigned short* __restrict__ rbf,
                                                 const f32x4* __restrict__ cst,
                                                 const float* __restrict__ sp) {
  __shared__ unsigned char lds[32768];
  int tid = threadIdx.x;
  int p0 = blockIdx.x << 7;
  #pragma unroll
  for (int it = 0; it < 4; it++) {
    int idx = tid + (it << 8);
    int p = idx >> 3, q = idx & 7;
    int kc = q >> 1, lg = (q & 1) << 1, pt = p >> 4;
    u32x4 g = *(const u32x4*)(in + (size_t)(p0 + p) * 128 + q * 16);
    unsigned int a0, a1, a2, a3, a4, a5, a6, a7;
    cvt2(g.x, a0, a1); cvt2(g.y, a2, a3); cvt2(g.z, a4, a5); cvt2(g.w, a6, a7);
    int l1 = (p & 15) | (lg << 4);
    int ad = (((((pt << 2) + kc) << 6) | l1) << 4);
    *(u32x4*)(lds + ad)       = u32x4{a0, a1, a2, a3};
    *(u32x4*)(lds + ad + 256) = u32x4{a4, a5, a6, a7};
  }
  __syncthreads();
  int l = tid & 63, wv = tid >> 6;
  int ob = wv << 5;                          // wave owns 32 output channels
  bf16x8 af[2][4];
  #pragma unroll
  for (int ot = 0; ot < 2; ot++)
    #pragma unroll
    for (int kc = 0; kc < 4; kc++) {
      int o = ob + (ot << 4) + (l & 15);
      int k = (kc << 5) + ((l >> 4) << 3);
      af[ot][kc] = *(const bf16x8*)(rbf + o * 128 + k);
    }
  f32x4 acc[2][8];
  #pragma unroll
  for (int ot = 0; ot < 2; ot++)
    #pragma unroll
    for (int pt = 0; pt < 8; pt++) acc[ot][pt] = f32x4{0.f, 0.f, 0.f, 0.f};
  #pragma unroll
  for (int kc = 0; kc < 4; kc++) {
    bf16x8 bb[8];
    #pragma unroll
    for (int pt = 0; pt < 8; pt++)
      bb[pt] = *(const bf16x8*)(lds + ((((((pt << 2) + kc) << 6)) + l) << 4));
    #pragma unroll
    for (int ot = 0; ot < 2; ot++)
      #pragma unroll
      for (int pt = 0; pt < 8; pt++)
        acc[ot][pt] = __builtin_amdgcn_mfma_f32_16x16x32_bf16(af[ot][kc], bb[pt], acc[ot][pt], 0, 0, 0);
  }
  float s_act = *sp;
  #pragma unroll
  for (int ot = 0; ot < 2; ot++) {
    int o0 = ob + (ot << 4) + ((l >> 4) << 2);
    f32x4 c0 = cst[o0], c1 = cst[o0 + 1], c2 = cst[o0 + 2], c3 = cst[o0 + 3];
    #pragma unroll
    for (int pt = 0; pt < 8; pt++) {
      int p = p0 + (pt << 4) + (l & 15);
      f32x4 a = acc[ot][pt];
      unsigned int pk = qstep(a.x, c0, s_act) | (qstep(a.y, c1, s_act) << 8) |
                        (qstep(a.z, c2, s_act) << 16) | (qstep(a.w, c3, s_act) << 24);
      *(unsigned int*)(out + (size_t)p * 128 + o0) = pk;
    }
  }
}

// ---------------- dw-conv2 v2: 4-consecutive-position sliding window ----------------
// thread = (cq in [0,32) -> 4 ch, pg in [0,8) -> 4 consecutive positions).
// 18 independent u32 loads (3 dh x 6 w window); OOB zero-fill (fmaf(0,w,a)==a exact).
// Per-output t=0..8 fmaf order identical to r1..r6 -> bit-identical output.
__global__ __launch_bounds__(256) void dw2_kernel(const unsigned char* __restrict__ in,
                                                  unsigned char* __restrict__ out,
                                                  const char* __restrict__ ws,
                                                  const float* __restrict__ sp) {
  __shared__ float tabs[1664];
  const float* src = (const float*)(ws + OFF_R3F);
  for (int i = threadIdx.x; i < 1664; i += 256) tabs[i] = src[i];
  __syncthreads();
  int tid = threadIdx.x;
  int cq = tid & 31, pg = tid >> 5;
  int c4 = cq << 2;
  float wk[9][4];
  #pragma unroll
  for (int t = 0; t < 9; t++) {
    wk[t][0] = tabs[t * 128 + c4];     wk[t][1] = tabs[t * 128 + c4 + 1];
    wk[t][2] = tabs[t * 128 + c4 + 2]; wk[t][3] = tabs[t * 128 + c4 + 3];
  }
  const f32x4* cst3 = (const f32x4*)(tabs + 1152);
  f32x4 cs0 = cst3[c4], cs1 = cst3[c4 + 1], cs2 = cst3[c4 + 2], cs3 = cst3[c4 + 3];
  float s_act = *sp;
  int pbase = (blockIdx.x << 5) + (pg << 2);     // 4 consecutive positions, same h row
  int wbase = pbase & 255, hh = (pbase >> 8) & 127;

  unsigned int xw[3][6];
  #pragma unroll
  for (int r = 0; r < 3; r++) {
    int dh = r - 1;
    bool rowok = (hh + dh >= 0) && (hh + dh <= 127);
    #pragma unroll
    for (int i = 0; i < 6; i++) {
      int wo = wbase + i - 1;
      unsigned int v = 0;
      if (rowok && wo >= 0 && wo <= 255)
        v = *(const unsigned int*)(in + (size_t)(pbase + dh * 256 + (i - 1)) * 128 + c4);
      xw[r][i] = v;
    }
  }
  #pragma unroll
  for (int j = 0; j < 4; j++) {
    float a0 = 0.f, a1 = 0.f, a2 = 0.f, a3 = 0.f;
    #pragma unroll
    for (int r = 0; r < 3; r++) {
      #pragma unroll
      for (int dwi = 0; dwi < 3; dwi++) {
        unsigned int v = xw[r][j + dwi];
        int t = r * 3 + dwi;
        a0 = fmaf((float)(v & 0xffu),         wk[t][0], a0);
        a1 = fmaf((float)((v >> 8) & 0xffu),  wk[t][1], a1);
        a2 = fmaf((float)((v >> 16) & 0xffu), wk[t][2], a2);
        a3 = fmaf((float)(v >> 24),           wk[t][3], a3);
      }
    }
    unsigned int pk = qstep(a0, cs0, s_act) | (qstep(a1, cs1, s_act) << 8) |
                      (qstep(a2, cs2, s_act) << 16) | (qstep(a3, cs3, s_act) << 24);
    *(unsigned int*)(out + (size_t)(pbase + j) * 128 + c4) = pk;
  }
}

// ---------------- classifier v2: 128 positions/block ----------------
__global__ __launch_bounds__(256) void cls_kernel(const unsigned char* __restrict__ in,
                                                  float* __restrict__ out,
                                                  const unsigned short* __restrict__ r5,
                                                  const float2* __restrict__ cst5) {
  __shared__ unsigned char lds[32768];
  int tid = threadIdx.x;
  int p0 = blockIdx.x << 7;
  #pragma unroll
  for (int it = 0; it < 4; it++) {
    int idx = tid + (it << 8);
    int p = idx >> 3, q = idx & 7;
    int kc = q >> 1, lg = (q & 1) << 1, pt = p >> 4;
    u32x4 g = *(const u32x4*)(in + (size_t)(p0 + p) * 128 + q * 16);
    unsigned int a0, a1, a2, a3, a4, a5, a6, a7;
    cvt2(g.x, a0, a1); cvt2(g.y, a2, a3); cvt2(g.z, a4, a5); cvt2(g.w, a6, a7);
    int l1 = (p & 15) | (lg << 4);
    int ad = (((((pt << 2) + kc) << 6) | l1) << 4);
    *(u32x4*)(lds + ad)       = u32x4{a0, a1, a2, a3};
    *(u32x4*)(lds + ad + 256) = u32x4{a4, a5, a6, a7};
  }
  __syncthreads();
  int l = tid & 63, wv = tid >> 6;
  int pt0 = wv << 1;                          // wave owns 2 position tiles
  bf16x8 af[2][4];
  #pragma unroll
  for (int ot = 0; ot < 2; ot++)
    #pragma unroll
    for (int kc = 0; kc < 4; kc++) {
      int o = (ot << 4) + (l & 15);
      int k = (kc << 5) + ((l >> 4) << 3);
      af[ot][kc] = *(const bf16x8*)(r5 + o * 128 + k);
    }
  f32x4 acc[2][2] = {{{0,0,0,0},{0,0,0,0}},{{0,0,0,0},{0,0,0,0}}};
  #pragma unroll
  for (int kc = 0; kc < 4; kc++) {
    bf16x8 b0 = *(const bf16x8*)(lds + ((((((pt0    ) << 2) + kc) << 6) + l) << 4));
    bf16x8 b1 = *(const bf16x8*)(lds + ((((((pt0 + 1) << 2) + kc) << 6) + l) << 4));
    #pragma unroll
    for (int ot = 0; ot < 2; ot++) {
      acc[ot][0] = __builtin_amdgcn_mfma_f32_16x16x32_bf16(af[ot][kc], b0, acc[ot][0], 0, 0, 0);
      acc[ot][1] = __builtin_amdgcn_mfma_f32_16x16x32_bf16(af[ot][kc], b1, acc[ot][1], 0, 0, 0);
    }
  }
  #pragma unroll
  for (int ptl = 0; ptl < 2; ptl++) {
    int p = p0 + ((pt0 + ptl) << 4) + (l & 15);
    int bb = p >> 15, hw = p & 32767;
    float* ob = out + (((size_t)bb * 19) << 15) + hw;
    #pragma unroll
    for (int ot = 0; ot < 2; ot++) {
      int obase = (ot << 4) + ((l >> 4) << 2);
      f32x4 a = acc[ot][ptl];
      #pragma unroll
      for (int i = 0; i < 4; i++) {
        int o = obase + i;
        if (o < 19) {
          float2 c5 = cst5[o];
          ob[(size_t)o << 15] = fmaf(a[i], c5.x, c5.y);
        }
      }
    }
  }
}

// ---------------- launch ----------------
extern "C" void kernel_launch(void* const* d_in, const int* in_sizes, int n_in,
                              void* d_out, int out_size, void* d_ws, size_t ws_size,
                              hipStream_t stream) {
  (void)in_sizes; (void)n_in; (void)out_size; (void)ws_size;
  char* ws = (char*)d_ws;
  PArgs P;
  P.dw1  = (const float*)d_in[1];
  P.pw1  = (const float*)d_in[2];
  P.dw2  = (const float*)d_in[3];
  P.pw2  = (const float*)d_in[4];
  P.clsw = (const float*)d_in[5];
  P.clsb = (const float*)d_in[6];
  P.g1 = (const float*)d_in[7];  P.b1 = (const float*)d_in[8];
  P.m1 = (const float*)d_in[9];  P.v1 = (const float*)d_in[10];
  P.g2 = (const float*)d_in[11]; P.b2 = (const float*)d_in[12];
  P.m2 = (const float*)d_in[13]; P.v2 = (const float*)d_in[14];
  P.g3 = (const float*)d_in[15]; P.b3 = (const float*)d_in[16];
  P.m3 = (const float*)d_in[17]; P.v3 = (const float*)d_in[18];
  P.g4 = (const float*)d_in[19]; P.b4 = (const float*)d_in[20];
  P.m4 = (const float*)d_in[21]; P.v4 = (const float*)d_in[22];
  P.s1 = (const float*)d_in[23]; P.s2 = (const float*)d_in[24];
  P.s3 = (const float*)d_in[25]; P.s4 = (const float*)d_in[26];

  const float* x = (const float*)d_in[0];
  unsigned char* bufA = (unsigned char*)(ws + OFF_BUFA);
  unsigned char* bufB = (unsigned char*)(ws + OFF_BUFB);

  prep_kernel<<<544, 64, 0, stream>>>(P, ws);
  dw1_kernel<<<1024, 512, 0, stream>>>(x, ws, P.s1);                       // x -> k1 (A)
  pw_kernel<<<2048, 256, 0, stream>>>(bufA, bufB,
      (const unsigned short*)(ws + OFF_R2BF), (const f32x4*)(ws + OFF_CST2), P.s2);  // k1 -> k2 (B)
  dw2_kernel<<<8192, 256, 0, stream>>>(bufB, bufA, ws, P.s3);              // k2 -> k3 (A)
  pw_kernel<<<2048, 256, 0, stream>>>(bufA, bufB,
      (const unsigned short*)(ws + OFF_R4BF), (const f32x4*)(ws + OFF_CST4), P.s4);  // k3 -> k4 (B)
  cls_kernel<<<2048, 256, 0, stream>>>(bufB, (float*)d_out,
      (const unsigned short*)(ws + OFF_R5BF), (const float2*)(ws + OFF_CST5));       // k4 -> out
}

// Round 8
// 150.884 us; speedup vs baseline: 1.6362x; 1.1053x over previous
//
#include <hip/hip_runtime.h>

typedef __attribute__((ext_vector_type(4))) float f32x4;
typedef __attribute__((ext_vector_type(8))) short bf16x8;
typedef __attribute__((ext_vector_type(2))) unsigned int u32x2;
typedef __attribute__((ext_vector_type(4))) unsigned int u32x4;

#define EPSV 1e-5f

// workspace layout (bytes)
#define OFF_BUFA 0u
#define OFF_BUFB 33554432u
#define OFF_T    67108864u
#define OFF_WQ1  (OFF_T + 0u)       // f32 [128][12]  (9 taps used)
#define OFF_R3F  (OFF_T + 6144u)    // f32 [9][128]   integer-valued
#define OFF_CST3 (OFF_T + 10752u)   // f32x4 [128]
#define OFF_CST1 (OFF_T + 12800u)   // f32x4 [128]
#define OFF_R2BF (OFF_T + 14848u)   // bf16 [128][128]
#define OFF_CST2 (OFF_T + 47616u)   // f32x4 [128]
#define OFF_R4BF (OFF_T + 49664u)   // bf16 [128][128]
#define OFF_CST4 (OFF_T + 82432u)   // f32x4 [128]
#define OFF_R5BF (OFF_T + 84480u)   // bf16 [32][128] (rows 19..31 zero)
#define OFF_CST5 (OFF_T + 92672u)   // float2 [32]

struct PArgs {
  const float *dw1, *pw1, *dw2, *pw2, *clsw, *clsb;
  const float *g1, *b1, *m1, *v1;
  const float *g2, *b2, *m2, *v2;
  const float *g3, *b3, *m3, *v3;
  const float *g4, *b4, *m4, *v4;
  const float *s1, *s2, *s3, *s4;
};

__device__ __forceinline__ unsigned short f2bf(float f) {
  return (unsigned short)(__builtin_bit_cast(unsigned int, f) >> 16);
}
__device__ __forceinline__ float clip7(float r) { return fminf(fmaxf(r, -7.f), 7.f); }

// y = a*A; t = (y-m)*sc + b; k = clamp(rint(t/s),0,15).  c = {A, sc, m, b}
__device__ __forceinline__ unsigned int qstep(float a, f32x4 c, float s) {
  float t = (a * c.x - c.z) * c.y + c.w;
  float u = t / s;
  float k = fminf(fmaxf(rintf(u), 0.f), 15.f);
  return (unsigned int)k;
}

// 4 u8 -> 2 dwords of packed bf16
__device__ __forceinline__ void cvt2(unsigned int d, unsigned int &lo, unsigned int &hi) {
  float f0 = (float)(d & 0xffu);
  float f1 = (float)((d >> 8) & 0xffu);
  float f2 = (float)((d >> 16) & 0xffu);
  float f3 = (float)(d >> 24);
  lo = (__builtin_bit_cast(unsigned int, f0) >> 16) | (__builtin_bit_cast(unsigned int, f1) & 0xffff0000u);
  hi = (__builtin_bit_cast(unsigned int, f2) >> 16) | (__builtin_bit_cast(unsigned int, f3) & 0xffff0000u);
}

__device__ __forceinline__ float wmax16(float v) {
  #pragma unroll
  for (int s = 1; s < 16; s <<= 1) v = fmaxf(v, __shfl_xor(v, s));
  return v;
}
__device__ __forceinline__ float wmax64(float v) {
  #pragma unroll
  for (int s = 1; s < 64; s <<= 1) v = fmaxf(v, __shfl_xor(v, s));
  return v;
}

// ---------------- prep: quantize weights, fold BN constants ----------------
__global__ __launch_bounds__(64) void prep_kernel(PArgs P, char* __restrict__ ws) {
  int bi = blockIdx.x, l = threadIdx.x;
  float* wq1 = (float*)(ws + OFF_WQ1);
  float* r3f = (float*)(ws + OFF_R3F);
  f32x4* cst1 = (f32x4*)(ws + OFF_CST1);
  f32x4* cst2 = (f32x4*)(ws + OFF_CST2);
  f32x4* cst3 = (f32x4*)(ws + OFF_CST3);
  f32x4* cst4 = (f32x4*)(ws + OFF_CST4);
  unsigned short* r2 = (unsigned short*)(ws + OFF_R2BF);
  unsigned short* r4 = (unsigned short*)(ws + OFF_R4BF);
  unsigned short* r5 = (unsigned short*)(ws + OFF_R5BF);
  float2* cst5 = (float2*)(ws + OFF_CST5);

  if (bi < 128) {
    int c = bi;
    float w = (l < 9) ? P.dw1[c * 9 + l] : 0.f;
    float mx = wmax16(fabsf(w));
    float sq = fmaxf(mx / 7.0f, 1e-8f);
    if (l < 9) wq1[c * 12 + l] = clip7(rintf(w / sq)) * sq;
    if (l == 0) {
      float sc = P.g1[c] / sqrtf(P.v1[c] + EPSV);
      cst1[c] = f32x4{1.f, sc, P.m1[c], P.b1[c]};
    }
  } else if (bi < 256) {
    int o = bi - 128;
    float w0 = P.pw1[o * 128 + l], w1 = P.pw1[o * 128 + 64 + l];
    float mx = wmax64(fmaxf(fabsf(w0), fabsf(w1)));
    float sq = fmaxf(mx / 7.0f, 1e-8f);
    r2[o * 128 + l]      = f2bf(clip7(rintf(w0 / sq)));
    r2[o * 128 + 64 + l] = f2bf(clip7(rintf(w1 / sq)));
    if (l == 0) {
      float sc = P.g2[o] / sqrtf(P.v2[o] + EPSV);
      cst2[o] = f32x4{P.s1[0] * sq, sc, P.m2[o], P.b2[o]};
    }
  } else if (bi < 384) {
    int c = bi - 256;
    float w = (l < 9) ? P.dw2[c * 9 + l] : 0.f;
    float mx = wmax16(fabsf(w));
    float sq = fmaxf(mx / 7.0f, 1e-8f);
    if (l < 9) r3f[l * 128 + c] = clip7(rintf(w / sq));
    if (l == 0) {
      float sc = P.g3[c] / sqrtf(P.v3[c] + EPSV);
      cst3[c] = f32x4{P.s2[0] * sq, sc, P.m3[c], P.b3[c]};
    }
  } else if (bi < 512) {
    int o = bi - 384;
    float w0 = P.pw2[o * 128 + l], w1 = P.pw2[o * 128 + 64 + l];
    float mx = wmax64(fmaxf(fabsf(w0), fabsf(w1)));
    float sq = fmaxf(mx / 7.0f, 1e-8f);
    r4[o * 128 + l]      = f2bf(clip7(rintf(w0 / sq)));
    r4[o * 128 + 64 + l] = f2bf(clip7(rintf(w1 / sq)));
    if (l == 0) {
      float sc = P.g4[o] / sqrtf(P.v4[o] + EPSV);
      cst4[o] = f32x4{P.s3[0] * sq, sc, P.m4[o], P.b4[o]};
    }
  } else {
    int o = bi - 512;
    if (o < 19) {
      float w0 = P.clsw[o * 128 + l], w1 = P.clsw[o * 128 + 64 + l];
      float mx = wmax64(fmaxf(fabsf(w0), fabsf(w1)));
      float sq = fmaxf(mx / 7.0f, 1e-8f);
      r5[o * 128 + l]      = f2bf(clip7(rintf(w0 / sq)));
      r5[o * 128 + 64 + l] = f2bf(clip7(rintf(w1 / sq)));
      if (l == 0) {
        float A5 = P.s4[0] * sq;
        float bq = rintf(P.clsb[o] / A5) * A5;
        cst5[o] = make_float2(A5, bq);
      }
    } else {
      r5[o * 128 + l] = 0; r5[o * 128 + 64 + l] = 0;
      if (l == 0) cst5[o] = make_float2(0.f, 0.f);
    }
  }
}

// ---------------- dw-conv1 (round-6 variant, frozen): (b,h)-row blocks, 8 waves ----------------
__global__ __launch_bounds__(512) void dw1_kernel(const float* __restrict__ x,
                                                  char* __restrict__ ws,
                                                  const float* __restrict__ s1p) {
  __shared__ __align__(16) unsigned char tile[32768];
  int bid = blockIdx.x;
  int orig = ((bid & 7) << 7) + (bid >> 3);   // XCD x owns image b=x, h sequential
  int b = orig >> 7, h = orig & 127;
  int tid = threadIdx.x;
  int wq = tid & 63, cg = tid >> 6;
  const float* wq1 = (const float*)(ws + OFF_WQ1);
  const f32x4* cst1 = (const f32x4*)(ws + OFF_CST1);
  float s_act = *s1p;
  int w0 = wq << 2;
  int sw = (wq & 31) << 2;
  int cbase = cg << 4;

  unsigned int acc0 = 0, acc1 = 0, acc2 = 0, acc3 = 0;
  #pragma unroll 4
  for (int cc = 0; cc < 16; cc++) {
    int c = cbase + cc;
    const float* wp = wq1 + c * 12;
    float k0 = wp[0], k1 = wp[1], k2 = wp[2], k3 = wp[3], k4 = wp[4],
          k5 = wp[5], k6 = wp[6], k7 = wp[7], k8 = wp[8];
    const float* xp = x + (((size_t)((b << 7) | c)) << 15) + (h << 8) + w0;
    f32x4 vm = {0.f, 0.f, 0.f, 0.f}, vp = {0.f, 0.f, 0.f, 0.f};
    f32x4 v0 = *(const f32x4*)(xp);
    if (h > 0)   vm = *(const f32x4*)(xp - 256);
    if (h < 127) vp = *(const f32x4*)(xp + 256);
    float lm = __shfl_up(vm.w, 1), l0 = __shfl_up(v0.w, 1), lp = __shfl_up(vp.w, 1);
    float rm = __shfl_down(vm.x, 1), r0 = __shfl_down(v0.x, 1), rp = __shfl_down(vp.x, 1);
    if (wq == 0)  { lm = 0.f; l0 = 0.f; lp = 0.f; }
    if (wq == 63) { rm = 0.f; r0 = 0.f; rp = 0.f; }

    float y0 = 0.f, y1 = 0.f, y2 = 0.f, y3 = 0.f;
    // row -1 (k0,k1,k2) then row 0 (k3,k4,k5) then row +1 (k6,k7,k8) — r1 order
    y0 = fmaf(lm,   k0, y0); y0 = fmaf(vm.x, k1, y0); y0 = fmaf(vm.y, k2, y0);
    y1 = fmaf(vm.x, k0, y1); y1 = fmaf(vm.y, k1, y1); y1 = fmaf(vm.z, k2, y1);
    y2 = fmaf(vm.y, k0, y2); y2 = fmaf(vm.z, k1, y2); y2 = fmaf(vm.w, k2, y2);
    y3 = fmaf(vm.z, k0, y3); y3 = fmaf(vm.w, k1, y3); y3 = fmaf(rm,   k2, y3);

    y0 = fmaf(l0,   k3, y0); y0 = fmaf(v0.x, k4, y0); y0 = fmaf(v0.y, k5, y0);
    y1 = fmaf(v0.x, k3, y1); y1 = fmaf(v0.y, k4, y1); y1 = fmaf(v0.z, k5, y1);
    y2 = fmaf(v0.y, k3, y2); y2 = fmaf(v0.z, k4, y2); y2 = fmaf(v0.w, k5, y2);
    y3 = fmaf(v0.z, k3, y3); y3 = fmaf(v0.w, k4, y3); y3 = fmaf(r0,   k5, y3);

    y0 = fmaf(lp,   k6, y0); y0 = fmaf(vp.x, k7, y0); y0 = fmaf(vp.y, k8, y0);
    y1 = fmaf(vp.x, k6, y1); y1 = fmaf(vp.y, k7, y1); y1 = fmaf(vp.z, k8, y1);
    y2 = fmaf(vp.y, k6, y2); y2 = fmaf(vp.z, k7, y2); y2 = fmaf(vp.w, k8, y2);
    y3 = fmaf(vp.z, k6, y3); y3 = fmaf(vp.w, k7, y3); y3 = fmaf(rp,   k8, y3);

    f32x4 cs = cst1[c];
    int sh = (cc & 3) << 3;
    acc0 |= qstep(y0, cs, s_act) << sh;
    acc1 |= qstep(y1, cs, s_act) << sh;
    acc2 |= qstep(y2, cs, s_act) << sh;
    acc3 |= qstep(y3, cs, s_act) << sh;
    if ((cc & 3) == 3) {
      int c0 = c - 3;
      *(unsigned int*)(tile + ((w0 + 0) << 7) + (c0 ^ sw)) = acc0;
      *(unsigned int*)(tile + ((w0 + 1) << 7) + (c0 ^ sw)) = acc1;
      *(unsigned int*)(tile + ((w0 + 2) << 7) + (c0 ^ sw)) = acc2;
      *(unsigned int*)(tile + ((w0 + 3) << 7) + (c0 ^ sw)) = acc3;
      acc0 = acc1 = acc2 = acc3 = 0;
    }
  }
  __syncthreads();
  // cooperative store: logical 16B chunk g=(p,s); physical chunk s^px, words ^s23
  unsigned char* gout = (unsigned char*)(ws + OFF_BUFA) + ((size_t)orig << 15);
  #pragma unroll
  for (int it = 0; it < 4; it++) {
    int idx = (it << 9) + tid;
    int p = idx >> 3, s = idx & 7;
    int px = (p >> 4) & 7, s23 = (p >> 2) & 3;
    u32x4 ch = *(const u32x4*)(tile + (p << 7) + ((s ^ px) << 4));
    unsigned int t0 = ch.x, t1 = ch.y, t2 = ch.z, t3 = ch.w, tt;
    if (s23 & 1) { tt = t0; t0 = t1; t1 = tt; tt = t2; t2 = t3; t3 = tt; }
    if (s23 & 2) { tt = t0; t0 = t2; t2 = tt; tt = t1; t1 = t3; t3 = tt; }
    *(u32x4*)(gout + (idx << 4)) = u32x4{t0, t1, t2, t3};
  }
}

// ---------------- pointwise conv (pw1): 128 positions/block (bf16 MFMA, exact int) ----------------
__global__ __launch_bounds__(256) void pw_kernel(const unsigned char* __restrict__ in,
                                                 unsigned char* __restrict__ out,
                                                 const unsigned short* __restrict__ rbf,
                                                 const f32x4* __restrict__ cst,
                                                 const float* __restrict__ sp) {
  __shared__ unsigned char lds[32768];
  int tid = threadIdx.x;
  int p0 = blockIdx.x << 7;
  #pragma unroll
  for (int it = 0; it < 4; it++) {
    int idx = tid + (it << 8);
    int p = idx >> 3, q = idx & 7;
    int kc = q >> 1, lg = (q & 1) << 1, pt = p >> 4;
    u32x4 g = *(const u32x4*)(in + (size_t)(p0 + p) * 128 + q * 16);
    unsigned int a0, a1, a2, a3, a4, a5, a6, a7;
    cvt2(g.x, a0, a1); cvt2(g.y, a2, a3); cvt2(g.z, a4, a5); cvt2(g.w, a6, a7);
    int l1 = (p & 15) | (lg << 4);
    int ad = (((((pt << 2) + kc) << 6) | l1) << 4);
    *(u32x4*)(lds + ad)       = u32x4{a0, a1, a2, a3};
    *(u32x4*)(lds + ad + 256) = u32x4{a4, a5, a6, a7};
  }
  __syncthreads();
  int l = tid & 63, wv = tid >> 6;
  int ob = wv << 5;                          // wave owns 32 output channels
  bf16x8 af[2][4];
  #pragma unroll
  for (int ot = 0; ot < 2; ot++)
    #pragma unroll
    for (int kc = 0; kc < 4; kc++) {
      int o = ob + (ot << 4) + (l & 15);
      int k = (kc << 5) + ((l >> 4) << 3);
      af[ot][kc] = *(const bf16x8*)(rbf + o * 128 + k);
    }
  f32x4 acc[2][8];
  #pragma unroll
  for (int ot = 0; ot < 2; ot++)
    #pragma unroll
    for (int pt = 0; pt < 8; pt++) acc[ot][pt] = f32x4{0.f, 0.f, 0.f, 0.f};
  #pragma unroll
  for (int kc = 0; kc < 4; kc++) {
    bf16x8 bb[8];
    #pragma unroll
    for (int pt = 0; pt < 8; pt++)
      bb[pt] = *(const bf16x8*)(lds + ((((((pt << 2) + kc) << 6)) + l) << 4));
    #pragma unroll
    for (int ot = 0; ot < 2; ot++)
      #pragma unroll
      for (int pt = 0; pt < 8; pt++)
        acc[ot][pt] = __builtin_amdgcn_mfma_f32_16x16x32_bf16(af[ot][kc], bb[pt], acc[ot][pt], 0, 0, 0);
  }
  float s_act = *sp;
  #pragma unroll
  for (int ot = 0; ot < 2; ot++) {
    int o0 = ob + (ot << 4) + ((l >> 4) << 2);
    f32x4 c0 = cst[o0], c1 = cst[o0 + 1], c2 = cst[o0 + 2], c3 = cst[o0 + 3];
    #pragma unroll
    for (int pt = 0; pt < 8; pt++) {
      int p = p0 + (pt << 4) + (l & 15);
      f32x4 a = acc[ot][pt];
      unsigned int pk = qstep(a.x, c0, s_act) | (qstep(a.y, c1, s_act) << 8) |
                        (qstep(a.z, c2, s_act) << 16) | (qstep(a.w, c3, s_act) << 24);
      *(unsigned int*)(out + (size_t)p * 128 + o0) = pk;
    }
  }
}

// ---------------- dw-conv2 v2: 4-consecutive-position sliding window ----------------
__global__ __launch_bounds__(256) void dw2_kernel(const unsigned char* __restrict__ in,
                                                  unsigned char* __restrict__ out,
                                                  const char* __restrict__ ws,
                                                  const float* __restrict__ sp) {
  __shared__ float tabs[1664];
  const float* src = (const float*)(ws + OFF_R3F);
  for (int i = threadIdx.x; i < 1664; i += 256) tabs[i] = src[i];
  __syncthreads();
  int tid = threadIdx.x;
  int cq = tid & 31, pg = tid >> 5;
  int c4 = cq << 2;
  float wk[9][4];
  #pragma unroll
  for (int t = 0; t < 9; t++) {
    wk[t][0] = tabs[t * 128 + c4];     wk[t][1] = tabs[t * 128 + c4 + 1];
    wk[t][2] = tabs[t * 128 + c4 + 2]; wk[t][3] = tabs[t * 128 + c4 + 3];
  }
  const f32x4* cst3 = (const f32x4*)(tabs + 1152);
  f32x4 cs0 = cst3[c4], cs1 = cst3[c4 + 1], cs2 = cst3[c4 + 2], cs3 = cst3[c4 + 3];
  float s_act = *sp;
  int pbase = (blockIdx.x << 5) + (pg << 2);     // 4 consecutive positions, same h row
  int wbase = pbase & 255, hh = (pbase >> 8) & 127;

  unsigned int xw[3][6];
  #pragma unroll
  for (int r = 0; r < 3; r++) {
    int dh = r - 1;
    bool rowok = (hh + dh >= 0) && (hh + dh <= 127);
    #pragma unroll
    for (int i = 0; i < 6; i++) {
      int wo = wbase + i - 1;
      unsigned int v = 0;
      if (rowok && wo >= 0 && wo <= 255)
        v = *(const unsigned int*)(in + (size_t)(pbase + dh * 256 + (i - 1)) * 128 + c4);
      xw[r][i] = v;
    }
  }
  #pragma unroll
  for (int j = 0; j < 4; j++) {
    float a0 = 0.f, a1 = 0.f, a2 = 0.f, a3 = 0.f;
    #pragma unroll
    for (int r = 0; r < 3; r++) {
      #pragma unroll
      for (int dwi = 0; dwi < 3; dwi++) {
        unsigned int v = xw[r][j + dwi];
        int t = r * 3 + dwi;
        a0 = fmaf((float)(v & 0xffu),         wk[t][0], a0);
        a1 = fmaf((float)((v >> 8) & 0xffu),  wk[t][1], a1);
        a2 = fmaf((float)((v >> 16) & 0xffu), wk[t][2], a2);
        a3 = fmaf((float)(v >> 24),           wk[t][3], a3);
      }
    }
    unsigned int pk = qstep(a0, cs0, s_act) | (qstep(a1, cs1, s_act) << 8) |
                      (qstep(a2, cs2, s_act) << 16) | (qstep(a3, cs3, s_act) << 24);
    *(unsigned int*)(out + (size_t)(pbase + j) * 128 + c4) = pk;
  }
}

// ---------------- fused pw2 + BN4 + qrelu + classifier ----------------
// k4 never touches global memory: pw2 epilogue writes quantized bf16 values
// directly into LDS in the cls B-fragment layout (wave wv owns k-chunk kc=wv).
__global__ __launch_bounds__(256) void pwcls_kernel(const unsigned char* __restrict__ in,
                                                    float* __restrict__ out,
                                                    const unsigned short* __restrict__ rbf,
                                                    const f32x4* __restrict__ cst,
                                                    const float* __restrict__ sp,
                                                    const unsigned short* __restrict__ r5,
                                                    const float2* __restrict__ cst5) {
  __shared__ unsigned char lds[32768];
  int tid = threadIdx.x;
  int p0 = blockIdx.x << 7;
  // --- stage k3 (identical fragment scheme to pw_kernel) ---
  #pragma unroll
  for (int it = 0; it < 4; it++) {
    int idx = tid + (it << 8);
    int p = idx >> 3, q = idx & 7;
    int kc = q >> 1, lg = (q & 1) << 1, pt = p >> 4;
    u32x4 g = *(const u32x4*)(in + (size_t)(p0 + p) * 128 + q * 16);
    unsigned int a0, a1, a2, a3, a4, a5, a6, a7;
    cvt2(g.x, a0, a1); cvt2(g.y, a2, a3); cvt2(g.z, a4, a5); cvt2(g.w, a6, a7);
    int l1 = (p & 15) | (lg << 4);
    int ad = (((((pt << 2) + kc) << 6) | l1) << 4);
    *(u32x4*)(lds + ad)       = u32x4{a0, a1, a2, a3};
    *(u32x4*)(lds + ad + 256) = u32x4{a4, a5, a6, a7};
  }
  __syncthreads();
  int l = tid & 63, wv = tid >> 6;
  int ob = wv << 5;
  // --- pw2 MFMA ---
  bf16x8 af[2][4];
  #pragma unroll
  for (int ot = 0; ot < 2; ot++)
    #pragma unroll
    for (int kc = 0; kc < 4; kc++) {
      int o = ob + (ot << 4) + (l & 15);
      int k = (kc << 5) + ((l >> 4) << 3);
      af[ot][kc] = *(const bf16x8*)(rbf + o * 128 + k);
    }
  f32x4 acc[2][8];
  #pragma unroll
  for (int ot = 0; ot < 2; ot++)
    #pragma unroll
    for (int pt = 0; pt < 8; pt++) acc[ot][pt] = f32x4{0.f, 0.f, 0.f, 0.f};
  #pragma unroll
  for (int kc = 0; kc < 4; kc++) {
    bf16x8 bb[8];
    #pragma unroll
    for (int pt = 0; pt < 8; pt++)
      bb[pt] = *(const bf16x8*)(lds + ((((((pt << 2) + kc) << 6)) + l) << 4));
    #pragma unroll
    for (int ot = 0; ot < 2; ot++)
      #pragma unroll
      for (int pt = 0; pt < 8; pt++)
        acc[ot][pt] = __builtin_amdgcn_mfma_f32_16x16x32_bf16(af[ot][kc], bb[pt], acc[ot][pt], 0, 0, 0);
  }
  float s_act = *sp;
  __syncthreads();   // all waves done reading k3 fragments; lds is reusable
  // --- epilogue: qstep -> bf16 pairs straight into cls B-fragment layout ---
  // lane l, ot, pt holds channels o0..o0+3 (o0 = 32wv+16ot+4(l>>4)) of position
  // p = 16pt+(l&15). Fragment slot: kc=wv, lane (l&15)|(hi<<4), hi=2ot+((l>>4)>>1),
  // byte-half ((l>>4)&1)*8.  bf16(small int) == cvt2 path exactly.
  {
    int hsel = (l >> 4) & 1;
    #pragma unroll
    for (int ot = 0; ot < 2; ot++) {
      int o0 = ob + (ot << 4) + ((l >> 4) << 2);
      f32x4 c0 = cst[o0], c1 = cst[o0 + 1], c2 = cst[o0 + 2], c3 = cst[o0 + 3];
      int hi = (ot << 1) + ((l >> 4) >> 1);
      int lfrag = (l & 15) | (hi << 4);
      #pragma unroll
      for (int pt = 0; pt < 8; pt++) {
        f32x4 a = acc[ot][pt];
        unsigned int k0 = qstep(a.x, c0, s_act), k1 = qstep(a.y, c1, s_act);
        unsigned int k2 = qstep(a.z, c2, s_act), k3 = qstep(a.w, c3, s_act);
        unsigned int w0 = (__builtin_bit_cast(unsigned int, (float)k0) >> 16) |
                          (__builtin_bit_cast(unsigned int, (float)k1) & 0xffff0000u);
        unsigned int w1 = (__builtin_bit_cast(unsigned int, (float)k2) >> 16) |
                          (__builtin_bit_cast(unsigned int, (float)k3) & 0xffff0000u);
        int ad = (((((pt << 2) + wv) << 6) | lfrag) << 4) + (hsel << 3);
        *(u32x2*)(lds + ad) = u32x2{w0, w1};
      }
    }
  }
  __syncthreads();
  // --- classifier MFMA: wave wv owns position tiles pt0, pt0+1 ---
  int pt0 = wv << 1;
  bf16x8 af5[2][4];
  #pragma unroll
  for (int ot = 0; ot < 2; ot++)
    #pragma unroll
    for (int kc = 0; kc < 4; kc++) {
      int o = (ot << 4) + (l & 15);
      int k = (kc << 5) + ((l >> 4) << 3);
      af5[ot][kc] = *(const bf16x8*)(r5 + o * 128 + k);
    }
  f32x4 a5[2][2] = {{{0,0,0,0},{0,0,0,0}},{{0,0,0,0},{0,0,0,0}}};
  #pragma unroll
  for (int kc = 0; kc < 4; kc++) {
    bf16x8 b0 = *(const bf16x8*)(lds + ((((((pt0    ) << 2) + kc) << 6) + l) << 4));
    bf16x8 b1 = *(const bf16x8*)(lds + ((((((pt0 + 1) << 2) + kc) << 6) + l) << 4));
    #pragma unroll
    for (int ot = 0; ot < 2; ot++) {
      a5[ot][0] = __builtin_amdgcn_mfma_f32_16x16x32_bf16(af5[ot][kc], b0, a5[ot][0], 0, 0, 0);
      a5[ot][1] = __builtin_amdgcn_mfma_f32_16x16x32_bf16(af5[ot][kc], b1, a5[ot][1], 0, 0, 0);
    }
  }
  #pragma unroll
  for (int ptl = 0; ptl < 2; ptl++) {
    int p = p0 + ((pt0 + ptl) << 4) + (l & 15);
    int bb = p >> 15, hw = p & 32767;
    float* ob2 = out + (((size_t)bb * 19) << 15) + hw;
    #pragma unroll
    for (int ot = 0; ot < 2; ot++) {
      int obase = (ot << 4) + ((l >> 4) << 2);
      f32x4 a = a5[ot][ptl];
      #pragma unroll
      for (int i = 0; i < 4; i++) {
        int o = obase + i;
        if (o < 19) {
          float2 c5 = cst5[o];
          ob2[(size_t)o << 15] = fmaf(a[i], c5.x, c5.y);
        }
      }
    }
  }
}

// ---------------- launch ----------------
extern "C" void kernel_launch(void* const* d_in, const int* in_sizes, int n_in,
                              void* d_out, int out_size, void* d_ws, size_t ws_size,
                              hipStream_t stream) {
  (void)in_sizes; (void)n_in; (void)out_size; (void)ws_size;
  char* ws = (char*)d_ws;
  PArgs P;
  P.dw1  = (const float*)d_in[1];
  P.pw1  = (const float*)d_in[2];
  P.dw2  = (const float*)d_in[3];
  P.pw2  = (const float*)d_in[4];
  P.clsw = (const float*)d_in[5];
  P.clsb = (const float*)d_in[6];
  P.g1 = (const float*)d_in[7];  P.b1 = (const float*)d_in[8];
  P.m1 = (const float*)d_in[9];  P.v1 = (const float*)d_in[10];
  P.g2 = (const float*)d_in[11]; P.b2 = (const float*)d_in[12];
  P.m2 = (const float*)d_in[13]; P.v2 = (const float*)d_in[14];
  P.g3 = (const float*)d_in[15]; P.b3 = (const float*)d_in[16];
  P.m3 = (const float*)d_in[17]; P.v3 = (const float*)d_in[18];
  P.g4 = (const float*)d_in[19]; P.b4 = (const float*)d_in[20];
  P.m4 = (const float*)d_in[21]; P.v4 = (const float*)d_in[22];
  P.s1 = (const float*)d_in[23]; P.s2 = (const float*)d_in[24];
  P.s3 = (const float*)d_in[25]; P.s4 = (const float*)d_in[26];

  const float* x = (const float*)d_in[0];
  unsigned char* bufA = (unsigned char*)(ws + OFF_BUFA);
  unsigned char* bufB = (unsigned char*)(ws + OFF_BUFB);

  prep_kernel<<<544, 64, 0, stream>>>(P, ws);
  dw1_kernel<<<1024, 512, 0, stream>>>(x, ws, P.s1);                       // x -> k1 (A)
  pw_kernel<<<2048, 256, 0, stream>>>(bufA, bufB,
      (const unsigned short*)(ws + OFF_R2BF), (const f32x4*)(ws + OFF_CST2), P.s2);  // k1 -> k2 (B)
  dw2_kernel<<<8192, 256, 0, stream>>>(bufB, bufA, ws, P.s3);              // k2 -> k3 (A)
  pwcls_kernel<<<2048, 256, 0, stream>>>(bufA, (float*)d_out,
      (const unsigned short*)(ws + OFF_R4BF), (const f32x4*)(ws + OFF_CST4), P.s4,
      (const unsigned short*)(ws + OFF_R5BF), (const float2*)(ws + OFF_CST5));       // k3 -> out
}

// Round 9
// 147.944 us; speedup vs baseline: 1.6687x; 1.0199x over previous
//
#include <hip/hip_runtime.h>

typedef __attribute__((ext_vector_type(4))) float f32x4;
typedef __attribute__((ext_vector_type(8))) short bf16x8;
typedef __attribute__((ext_vector_type(2))) unsigned int u32x2;
typedef __attribute__((ext_vector_type(4))) unsigned int u32x4;

#define EPSV 1e-5f

// workspace layout (bytes)
#define OFF_BUFA 0u
#define OFF_BUFB 33554432u
#define OFF_T    67108864u
#define OFF_WQ1  (OFF_T + 0u)       // f32 [128][12]  (9 taps used)
#define OFF_R3F  (OFF_T + 6144u)    // f32 [9][128]   integer-valued
#define OFF_CST3 (OFF_T + 10752u)   // f32x4 [128]
#define OFF_CST1 (OFF_T + 12800u)   // f32x4 [128]
#define OFF_R2BF (OFF_T + 14848u)   // bf16 [128][128]
#define OFF_CST2 (OFF_T + 47616u)   // f32x4 [128]
#define OFF_R4BF (OFF_T + 49664u)   // bf16 [128][128]
#define OFF_CST4 (OFF_T + 82432u)   // f32x4 [128]
#define OFF_R5BF (OFF_T + 84480u)   // bf16 [32][128] (rows 19..31 zero)
#define OFF_CST5 (OFF_T + 92672u)   // float2 [32]

struct PArgs {
  const float *dw1, *pw1, *dw2, *pw2, *clsw, *clsb;
  const float *g1, *b1, *m1, *v1;
  const float *g2, *b2, *m2, *v2;
  const float *g3, *b3, *m3, *v3;
  const float *g4, *b4, *m4, *v4;
  const float *s1, *s2, *s3, *s4;
};

__device__ __forceinline__ unsigned short f2bf(float f) {
  return (unsigned short)(__builtin_bit_cast(unsigned int, f) >> 16);
}
__device__ __forceinline__ float clip7(float r) { return fminf(fmaxf(r, -7.f), 7.f); }

// y = a*A; t = (y-m)*sc + b; k = clamp(rint(t/s),0,15).  c = {A, sc, m, b}
__device__ __forceinline__ unsigned int qstep(float a, f32x4 c, float s) {
  float t = (a * c.x - c.z) * c.y + c.w;
  float u = t / s;
  float k = fminf(fmaxf(rintf(u), 0.f), 15.f);
  return (unsigned int)k;
}

// 4 u8 -> 2 dwords of packed bf16
__device__ __forceinline__ void cvt2(unsigned int d, unsigned int &lo, unsigned int &hi) {
  float f0 = (float)(d & 0xffu);
  float f1 = (float)((d >> 8) & 0xffu);
  float f2 = (float)((d >> 16) & 0xffu);
  float f3 = (float)(d >> 24);
  lo = (__builtin_bit_cast(unsigned int, f0) >> 16) | (__builtin_bit_cast(unsigned int, f1) & 0xffff0000u);
  hi = (__builtin_bit_cast(unsigned int, f2) >> 16) | (__builtin_bit_cast(unsigned int, f3) & 0xffff0000u);
}

__device__ __forceinline__ float wmax16(float v) {
  #pragma unroll
  for (int s = 1; s < 16; s <<= 1) v = fmaxf(v, __shfl_xor(v, s));
  return v;
}
__device__ __forceinline__ float wmax64(float v) {
  #pragma unroll
  for (int s = 1; s < 64; s <<= 1) v = fmaxf(v, __shfl_xor(v, s));
  return v;
}

// ---------------- prep: quantize weights, fold BN constants ----------------
__global__ __launch_bounds__(64) void prep_kernel(PArgs P, char* __restrict__ ws) {
  int bi = blockIdx.x, l = threadIdx.x;
  float* wq1 = (float*)(ws + OFF_WQ1);
  float* r3f = (float*)(ws + OFF_R3F);
  f32x4* cst1 = (f32x4*)(ws + OFF_CST1);
  f32x4* cst2 = (f32x4*)(ws + OFF_CST2);
  f32x4* cst3 = (f32x4*)(ws + OFF_CST3);
  f32x4* cst4 = (f32x4*)(ws + OFF_CST4);
  unsigned short* r2 = (unsigned short*)(ws + OFF_R2BF);
  unsigned short* r4 = (unsigned short*)(ws + OFF_R4BF);
  unsigned short* r5 = (unsigned short*)(ws + OFF_R5BF);
  float2* cst5 = (float2*)(ws + OFF_CST5);

  if (bi < 128) {
    int c = bi;
    float w = (l < 9) ? P.dw1[c * 9 + l] : 0.f;
    float mx = wmax16(fabsf(w));
    float sq = fmaxf(mx / 7.0f, 1e-8f);
    if (l < 9) wq1[c * 12 + l] = clip7(rintf(w / sq)) * sq;
    if (l == 0) {
      float sc = P.g1[c] / sqrtf(P.v1[c] + EPSV);
      cst1[c] = f32x4{1.f, sc, P.m1[c], P.b1[c]};
    }
  } else if (bi < 256) {
    int o = bi - 128;
    float w0 = P.pw1[o * 128 + l], w1 = P.pw1[o * 128 + 64 + l];
    float mx = wmax64(fmaxf(fabsf(w0), fabsf(w1)));
    float sq = fmaxf(mx / 7.0f, 1e-8f);
    r2[o * 128 + l]      = f2bf(clip7(rintf(w0 / sq)));
    r2[o * 128 + 64 + l] = f2bf(clip7(rintf(w1 / sq)));
    if (l == 0) {
      float sc = P.g2[o] / sqrtf(P.v2[o] + EPSV);
      cst2[o] = f32x4{P.s1[0] * sq, sc, P.m2[o], P.b2[o]};
    }
  } else if (bi < 384) {
    int c = bi - 256;
    float w = (l < 9) ? P.dw2[c * 9 + l] : 0.f;
    float mx = wmax16(fabsf(w));
    float sq = fmaxf(mx / 7.0f, 1e-8f);
    if (l < 9) r3f[l * 128 + c] = clip7(rintf(w / sq));
    if (l == 0) {
      float sc = P.g3[c] / sqrtf(P.v3[c] + EPSV);
      cst3[c] = f32x4{P.s2[0] * sq, sc, P.m3[c], P.b3[c]};
    }
  } else if (bi < 512) {
    int o = bi - 384;
    float w0 = P.pw2[o * 128 + l], w1 = P.pw2[o * 128 + 64 + l];
    float mx = wmax64(fmaxf(fabsf(w0), fabsf(w1)));
    float sq = fmaxf(mx / 7.0f, 1e-8f);
    r4[o * 128 + l]      = f2bf(clip7(rintf(w0 / sq)));
    r4[o * 128 + 64 + l] = f2bf(clip7(rintf(w1 / sq)));
    if (l == 0) {
      float sc = P.g4[o] / sqrtf(P.v4[o] + EPSV);
      cst4[o] = f32x4{P.s3[0] * sq, sc, P.m4[o], P.b4[o]};
    }
  } else {
    int o = bi - 512;
    if (o < 19) {
      float w0 = P.clsw[o * 128 + l], w1 = P.clsw[o * 128 + 64 + l];
      float mx = wmax64(fmaxf(fabsf(w0), fabsf(w1)));
      float sq = fmaxf(mx / 7.0f, 1e-8f);
      r5[o * 128 + l]      = f2bf(clip7(rintf(w0 / sq)));
      r5[o * 128 + 64 + l] = f2bf(clip7(rintf(w1 / sq)));
      if (l == 0) {
        float A5 = P.s4[0] * sq;
        float bq = rintf(P.clsb[o] / A5) * A5;
        cst5[o] = make_float2(A5, bq);
      }
    } else {
      r5[o * 128 + l] = 0; r5[o * 128 + 64 + l] = 0;
      if (l == 0) cst5[o] = make_float2(0.f, 0.f);
    }
  }
}

// ---------------- dw-conv1 phase A: per-plane streaming, rolling 3-row window ----------------
// block = (b, c): one full 128x256 plane, each input row read ONCE (amp 1.125x).
// 512 thr: wq = tid&63 (w-quad), wv = tid>>6 (16 h-rows each, rolling window).
// Weights/BN consts block-uniform (SGPR). Output u8 NCHW plane, coalesced u32 stores.
// fmaf/qstep order per output identical to r1..r8 -> bit-identical bytes.
__global__ __launch_bounds__(512) void dwA_kernel(const float* __restrict__ x,
                                                  char* __restrict__ ws,
                                                  const float* __restrict__ s1p) {
  int bid = blockIdx.x;
  int b = bid & 7, c = bid >> 3;              // XCD x owns image b=x
  int tid = threadIdx.x;
  int wq = tid & 63, wv = tid >> 6;
  int w0 = wq << 2;
  int h0 = wv << 4;
  const float* wp = (const float*)(ws + OFF_WQ1) + c * 12;
  float k0 = wp[0], k1 = wp[1], k2 = wp[2], k3 = wp[3], k4 = wp[4],
        k5 = wp[5], k6 = wp[6], k7 = wp[7], k8 = wp[8];
  f32x4 cs = ((const f32x4*)(ws + OFF_CST1))[c];
  float s_act = *s1p;
  const float* plane = x + (((size_t)((b << 7) | c)) << 15);
  unsigned char* oplane = (unsigned char*)(ws + OFF_BUFB) + (((size_t)((b << 7) | c)) << 15);

  f32x4 vm = {0.f, 0.f, 0.f, 0.f};
  if (h0 > 0) vm = *(const f32x4*)(plane + ((h0 - 1) << 8) + w0);
  f32x4 v0 = *(const f32x4*)(plane + (h0 << 8) + w0);
  f32x4 vp = *(const f32x4*)(plane + ((h0 + 1) << 8) + w0);   // h0+1 <= 113 always
  float lm = __shfl_up(vm.w, 1), l0 = __shfl_up(v0.w, 1), lp = __shfl_up(vp.w, 1);
  float rm = __shfl_down(vm.x, 1), r0 = __shfl_down(v0.x, 1), rp = __shfl_down(vp.x, 1);
  if (wq == 0)  { lm = 0.f; l0 = 0.f; lp = 0.f; }
  if (wq == 63) { rm = 0.f; r0 = 0.f; rp = 0.f; }

  #pragma unroll 4
  for (int i = 0; i < 16; i++) {
    int h = h0 + i;
    float y0 = 0.f, y1 = 0.f, y2 = 0.f, y3 = 0.f;
    // row -1 (k0,k1,k2) then row 0 (k3,k4,k5) then row +1 (k6,k7,k8) — r1 order
    y0 = fmaf(lm,   k0, y0); y0 = fmaf(vm.x, k1, y0); y0 = fmaf(vm.y, k2, y0);
    y1 = fmaf(vm.x, k0, y1); y1 = fmaf(vm.y, k1, y1); y1 = fmaf(vm.z, k2, y1);
    y2 = fmaf(vm.y, k0, y2); y2 = fmaf(vm.z, k1, y2); y2 = fmaf(vm.w, k2, y2);
    y3 = fmaf(vm.z, k0, y3); y3 = fmaf(vm.w, k1, y3); y3 = fmaf(rm,   k2, y3);

    y0 = fmaf(l0,   k3, y0); y0 = fmaf(v0.x, k4, y0); y0 = fmaf(v0.y, k5, y0);
    y1 = fmaf(v0.x, k3, y1); y1 = fmaf(v0.y, k4, y1); y1 = fmaf(v0.z, k5, y1);
    y2 = fmaf(v0.y, k3, y2); y2 = fmaf(v0.z, k4, y2); y2 = fmaf(v0.w, k5, y2);
    y3 = fmaf(v0.z, k3, y3); y3 = fmaf(v0.w, k4, y3); y3 = fmaf(r0,   k5, y3);

    y0 = fmaf(lp,   k6, y0); y0 = fmaf(vp.x, k7, y0); y0 = fmaf(vp.y, k8, y0);
    y1 = fmaf(vp.x, k6, y1); y1 = fmaf(vp.y, k7, y1); y1 = fmaf(vp.z, k8, y1);
    y2 = fmaf(vp.y, k6, y2); y2 = fmaf(vp.z, k7, y2); y2 = fmaf(vp.w, k8, y2);
    y3 = fmaf(vp.z, k6, y3); y3 = fmaf(vp.w, k7, y3); y3 = fmaf(rp,   k8, y3);

    unsigned int pk = qstep(y0, cs, s_act) | (qstep(y1, cs, s_act) << 8) |
                      (qstep(y2, cs, s_act) << 16) | (qstep(y3, cs, s_act) << 24);
    *(unsigned int*)(oplane + (h << 8) + w0) = pk;

    // shift window; load row h+2 for next iteration
    vm = v0; lm = l0; rm = r0;
    v0 = vp; l0 = lp; r0 = rp;
    f32x4 nv = {0.f, 0.f, 0.f, 0.f};
    if (i < 15 && h + 2 < 128) nv = *(const f32x4*)(plane + ((h + 2) << 8) + w0);
    vp = nv;
    float nl = __shfl_up(nv.w, 1), nr = __shfl_down(nv.x, 1);
    if (wq == 0)  nl = 0.f;
    if (wq == 63) nr = 0.f;
    lp = nl; rp = nr;
  }
}

// ---------------- dw-conv1 phase B: NCHW u8 -> NHWC u8 transpose ----------------
// block = (b, 256-position chunk). 256 thr: pq = tid&63 (4 pos), cg = tid>>6 (32 ch in 8x4).
// 4x4 byte register transpose; LDS tile + swizzle + permuted store = dw1-v4's exact scheme.
__global__ __launch_bounds__(256) void tr_kernel(char* __restrict__ ws) {
  __shared__ __align__(16) unsigned char tile[32768];
  int bid = blockIdx.x;
  int b = bid & 7, chunk = bid >> 3;          // same XCD pinning as dwA
  int tid = threadIdx.x;
  int pq = tid & 63, cg = tid >> 6;
  int pl0 = pq << 2;
  int sw = (pq & 31) << 2;
  const unsigned char* inb = (const unsigned char*)(ws + OFF_BUFB);
  size_t gp0 = ((size_t)b << 22) + ((size_t)chunk << 8);   // b*128*32768 ... position base within image

  #pragma unroll
  for (int ci = 0; ci < 8; ci++) {
    int c4 = (cg << 5) + (ci << 2);
    // load u32 (4 positions) from each of 4 planes
    unsigned int t0 = *(const unsigned int*)(inb + (((size_t)((b << 7) | (c4 + 0))) << 15) + (chunk << 8) + pl0);
    unsigned int t1 = *(const unsigned int*)(inb + (((size_t)((b << 7) | (c4 + 1))) << 15) + (chunk << 8) + pl0);
    unsigned int t2 = *(const unsigned int*)(inb + (((size_t)((b << 7) | (c4 + 2))) << 15) + (chunk << 8) + pl0);
    unsigned int t3 = *(const unsigned int*)(inb + (((size_t)((b << 7) | (c4 + 3))) << 15) + (chunk << 8) + pl0);
    // 4x4 byte transpose: out j (position pl0+j) = bytes {t0.bj, t1.bj, t2.bj, t3.bj}
    #pragma unroll
    for (int j = 0; j < 4; j++) {
      unsigned int oj = ((t0 >> (8 * j)) & 0xffu)
                      | (((t1 >> (8 * j)) & 0xffu) << 8)
                      | (((t2 >> (8 * j)) & 0xffu) << 16)
                      | (((t3 >> (8 * j)) & 0xffu) << 24);
      *(unsigned int*)(tile + ((pl0 + j) << 7) + (c4 ^ sw)) = oj;
    }
  }
  __syncthreads();
  // cooperative store: logical 16B chunk (p,s); physical chunk s^px, words ^s23 (dw1-v4 scheme)
  unsigned char* gout = (unsigned char*)(ws + OFF_BUFA) + (((size_t)((b << 7) | chunk)) << 15);
  (void)gp0;
  #pragma unroll
  for (int it = 0; it < 8; it++) {
    int idx = (it << 8) + tid;                 // [0, 2048)
    int p = idx >> 3, s = idx & 7;
    int px = (p >> 4) & 7, s23 = (p >> 2) & 3;
    u32x4 ch = *(const u32x4*)(tile + (p << 7) + ((s ^ px) << 4));
    unsigned int t0 = ch.x, t1 = ch.y, t2 = ch.z, t3 = ch.w, tt;
    if (s23 & 1) { tt = t0; t0 = t1; t1 = tt; tt = t2; t2 = t3; t3 = tt; }
    if (s23 & 2) { tt = t0; t0 = t2; t2 = tt; tt = t1; t1 = t3; t3 = tt; }
    *(u32x4*)(gout + (idx << 4)) = u32x4{t0, t1, t2, t3};
  }
}

// ---------------- pointwise conv (pw1): 128 positions/block (bf16 MFMA, exact int) ----------------
__global__ __launch_bounds__(256) void pw_kernel(const unsigned char* __restrict__ in,
                                                 unsigned char* __restrict__ out,
                                                 const unsigned short* __restrict__ rbf,
                                                 const f32x4* __restrict__ cst,
                                                 const float* __restrict__ sp) {
  __shared__ unsigned char lds[32768];
  int tid = threadIdx.x;
  int p0 = blockIdx.x << 7;
  #pragma unroll
  for (int it = 0; it < 4; it++) {
    int idx = tid + (it << 8);
    int p = idx >> 3, q = idx & 7;
    int kc = q >> 1, lg = (q & 1) << 1, pt = p >> 4;
    u32x4 g = *(const u32x4*)(in + (size_t)(p0 + p) * 128 + q * 16);
    unsigned int a0, a1, a2, a3, a4, a5, a6, a7;
    cvt2(g.x, a0, a1); cvt2(g.y, a2, a3); cvt2(g.z, a4, a5); cvt2(g.w, a6, a7);
    int l1 = (p & 15) | (lg << 4);
    int ad = (((((pt << 2) + kc) << 6) | l1) << 4);
    *(u32x4*)(lds + ad)       = u32x4{a0, a1, a2, a3};
    *(u32x4*)(lds + ad + 256) = u32x4{a4, a5, a6, a7};
  }
  __syncthreads();
  int l = tid & 63, wv = tid >> 6;
  int ob = wv << 5;                          // wave owns 32 output channels
  bf16x8 af[2][4];
  #pragma unroll
  for (int ot = 0; ot < 2; ot++)
    #pragma unroll
    for (int kc = 0; kc < 4; kc++) {
      int o = ob + (ot << 4) + (l & 15);
      int k = (kc << 5) + ((l >> 4) << 3);
      af[ot][kc] = *(const bf16x8*)(rbf + o * 128 + k);
    }
  f32x4 acc[2][8];
  #pragma unroll
  for (int ot = 0; ot < 2; ot++)
    #pragma unroll
    for (int pt = 0; pt < 8; pt++) acc[ot][pt] = f32x4{0.f, 0.f, 0.f, 0.f};
  #pragma unroll
  for (int kc = 0; kc < 4; kc++) {
    bf16x8 bb[8];
    #pragma unroll
    for (int pt = 0; pt < 8; pt++)
      bb[pt] = *(const bf16x8*)(lds + ((((((pt << 2) + kc) << 6)) + l) << 4));
    #pragma unroll
    for (int ot = 0; ot < 2; ot++)
      #pragma unroll
      for (int pt = 0; pt < 8; pt++)
        acc[ot][pt] = __builtin_amdgcn_mfma_f32_16x16x32_bf16(af[ot][kc], bb[pt], acc[ot][pt], 0, 0, 0);
  }
  float s_act = *sp;
  #pragma unroll
  for (int ot = 0; ot < 2; ot++) {
    int o0 = ob + (ot << 4) + ((l >> 4) << 2);
    f32x4 c0 = cst[o0], c1 = cst[o0 + 1], c2 = cst[o0 + 2], c3 = cst[o0 + 3];
    #pragma unroll
    for (int pt = 0; pt < 8; pt++) {
      int p = p0 + (pt << 4) + (l & 15);
      f32x4 a = acc[ot][pt];
      unsigned int pk = qstep(a.x, c0, s_act) | (qstep(a.y, c1, s_act) << 8) |
                        (qstep(a.z, c2, s_act) << 16) | (qstep(a.w, c3, s_act) << 24);
      *(unsigned int*)(out + (size_t)p * 128 + o0) = pk;
    }
  }
}

// ---------------- dw-conv2 v2: 4-consecutive-position sliding window ----------------
__global__ __launch_bounds__(256) void dw2_kernel(const unsigned char* __restrict__ in,
                                                  unsigned char* __restrict__ out,
                                                  const char* __restrict__ ws,
                                                  const float* __restrict__ sp) {
  __shared__ float tabs[1664];
  const float* src = (const float*)(ws + OFF_R3F);
  for (int i = threadIdx.x; i < 1664; i += 256) tabs[i] = src[i];
  __syncthreads();
  int tid = threadIdx.x;
  int cq = tid & 31, pg = tid >> 5;
  int c4 = cq << 2;
  float wk[9][4];
  #pragma unroll
  for (int t = 0; t < 9; t++) {
    wk[t][0] = tabs[t * 128 + c4];     wk[t][1] = tabs[t * 128 + c4 + 1];
    wk[t][2] = tabs[t * 128 + c4 + 2]; wk[t][3] = tabs[t * 128 + c4 + 3];
  }
  const f32x4* cst3 = (const f32x4*)(tabs + 1152);
  f32x4 cs0 = cst3[c4], cs1 = cst3[c4 + 1], cs2 = cst3[c4 + 2], cs3 = cst3[c4 + 3];
  float s_act = *sp;
  int pbase = (blockIdx.x << 5) + (pg << 2);     // 4 consecutive positions, same h row
  int wbase = pbase & 255, hh = (pbase >> 8) & 127;

  unsigned int xw[3][6];
  #pragma unroll
  for (int r = 0; r < 3; r++) {
    int dh = r - 1;
    bool rowok = (hh + dh >= 0) && (hh + dh <= 127);
    #pragma unroll
    for (int i = 0; i < 6; i++) {
      int wo = wbase + i - 1;
      unsigned int v = 0;
      if (rowok && wo >= 0 && wo <= 255)
        v = *(const unsigned int*)(in + (size_t)(pbase + dh * 256 + (i - 1)) * 128 + c4);
      xw[r][i] = v;
    }
  }
  #pragma unroll
  for (int j = 0; j < 4; j++) {
    float a0 = 0.f, a1 = 0.f, a2 = 0.f, a3 = 0.f;
    #pragma unroll
    for (int r = 0; r < 3; r++) {
      #pragma unroll
      for (int dwi = 0; dwi < 3; dwi++) {
        unsigned int v = xw[r][j + dwi];
        int t = r * 3 + dwi;
        a0 = fmaf((float)(v & 0xffu),         wk[t][0], a0);
        a1 = fmaf((float)((v >> 8) & 0xffu),  wk[t][1], a1);
        a2 = fmaf((float)((v >> 16) & 0xffu), wk[t][2], a2);
        a3 = fmaf((float)(v >> 24),           wk[t][3], a3);
      }
    }
    unsigned int pk = qstep(a0, cs0, s_act) | (qstep(a1, cs1, s_act) << 8) |
                      (qstep(a2, cs2, s_act) << 16) | (qstep(a3, cs3, s_act) << 24);
    *(unsigned int*)(out + (size_t)(pbase + j) * 128 + c4) = pk;
  }
}

// ---------------- fused pw2 + BN4 + qrelu + classifier ----------------
__global__ __launch_bounds__(256) void pwcls_kernel(const unsigned char* __restrict__ in,
                                                    float* __restrict__ out,
                                                    const unsigned short* __restrict__ rbf,
                                                    const f32x4* __restrict__ cst,
                                                    const float* __restrict__ sp,
                                                    const unsigned short* __restrict__ r5,
                                                    const float2* __restrict__ cst5) {
  __shared__ unsigned char lds[32768];
  int tid = threadIdx.x;
  int p0 = blockIdx.x << 7;
  #pragma unroll
  for (int it = 0; it < 4; it++) {
    int idx = tid + (it << 8);
    int p = idx >> 3, q = idx & 7;
    int kc = q >> 1, lg = (q & 1) << 1, pt = p >> 4;
    u32x4 g = *(const u32x4*)(in + (size_t)(p0 + p) * 128 + q * 16);
    unsigned int a0, a1, a2, a3, a4, a5, a6, a7;
    cvt2(g.x, a0, a1); cvt2(g.y, a2, a3); cvt2(g.z, a4, a5); cvt2(g.w, a6, a7);
    int l1 = (p & 15) | (lg << 4);
    int ad = (((((pt << 2) + kc) << 6) | l1) << 4);
    *(u32x4*)(lds + ad)       = u32x4{a0, a1, a2, a3};
    *(u32x4*)(lds + ad + 256) = u32x4{a4, a5, a6, a7};
  }
  __syncthreads();
  int l = tid & 63, wv = tid >> 6;
  int ob = wv << 5;
  bf16x8 af[2][4];
  #pragma unroll
  for (int ot = 0; ot < 2; ot++)
    #pragma unroll
    for (int kc = 0; kc < 4; kc++) {
      int o = ob + (ot << 4) + (l & 15);
      int k = (kc << 5) + ((l >> 4) << 3);
      af[ot][kc] = *(const bf16x8*)(rbf + o * 128 + k);
    }
  f32x4 acc[2][8];
  #pragma unroll
  for (int ot = 0; ot < 2; ot++)
    #pragma unroll
    for (int pt = 0; pt < 8; pt++) acc[ot][pt] = f32x4{0.f, 0.f, 0.f, 0.f};
  #pragma unroll
  for (int kc = 0; kc < 4; kc++) {
    bf16x8 bb[8];
    #pragma unroll
    for (int pt = 0; pt < 8; pt++)
      bb[pt] = *(const bf16x8*)(lds + ((((((pt << 2) + kc) << 6)) + l) << 4));
    #pragma unroll
    for (int ot = 0; ot < 2; ot++)
      #pragma unroll
      for (int pt = 0; pt < 8; pt++)
        acc[ot][pt] = __builtin_amdgcn_mfma_f32_16x16x32_bf16(af[ot][kc], bb[pt], acc[ot][pt], 0, 0, 0);
  }
  float s_act = *sp;
  __syncthreads();   // all waves done reading k3 fragments; lds is reusable
  {
    int hsel = (l >> 4) & 1;
    #pragma unroll
    for (int ot = 0; ot < 2; ot++) {
      int o0 = ob + (ot << 4) + ((l >> 4) << 2);
      f32x4 c0 = cst[o0], c1 = cst[o0 + 1], c2 = cst[o0 + 2], c3 = cst[o0 + 3];
      int hi = (ot << 1) + ((l >> 4) >> 1);
      int lfrag = (l & 15) | (hi << 4);
      #pragma unroll
      for (int pt = 0; pt < 8; pt++) {
        f32x4 a = acc[ot][pt];
        unsigned int k0 = qstep(a.x, c0, s_act), k1 = qstep(a.y, c1, s_act);
        unsigned int k2 = qstep(a.z, c2, s_act), k3 = qstep(a.w, c3, s_act);
        unsigned int w0 = (__builtin_bit_cast(unsigned int, (float)k0) >> 16) |
                          (__builtin_bit_cast(unsigned int, (float)k1) & 0xffff0000u);
        unsigned int w1 = (__builtin_bit_cast(unsigned int, (float)k2) >> 16) |
                          (__builtin_bit_cast(unsigned int, (float)k3) & 0xffff0000u);
        int ad = (((((pt << 2) + wv) << 6) | lfrag) << 4) + (hsel << 3);
        *(u32x2*)(lds + ad) = u32x2{w0, w1};
      }
    }
  }
  __syncthreads();
  int pt0 = wv << 1;
  bf16x8 af5[2][4];
  #pragma unroll
  for (int ot = 0; ot < 2; ot++)
    #pragma unroll
    for (int kc = 0; kc < 4; kc++) {
      int o = (ot << 4) + (l & 15);
      int k = (kc << 5) + ((l >> 4) << 3);
      af5[ot][kc] = *(const bf16x8*)(r5 + o * 128 + k);
    }
  f32x4 a5[2][2] = {{{0,0,0,0},{0,0,0,0}},{{0,0,0,0},{0,0,0,0}}};
  #pragma unroll
  for (int kc = 0; kc < 4; kc++) {
    bf16x8 b0 = *(const bf16x8*)(lds + ((((((pt0    ) << 2) + kc) << 6) + l) << 4));
    bf16x8 b1 = *(const bf16x8*)(lds + ((((((pt0 + 1) << 2) + kc) << 6) + l) << 4));
    #pragma unroll
    for (int ot = 0; ot < 2; ot++) {
      a5[ot][0] = __builtin_amdgcn_mfma_f32_16x16x32_bf16(af5[ot][kc], b0, a5[ot][0], 0, 0, 0);
      a5[ot][1] = __builtin_amdgcn_mfma_f32_16x16x32_bf16(af5[ot][kc], b1, a5[ot][1], 0, 0, 0);
    }
  }
  #pragma unroll
  for (int ptl = 0; ptl < 2; ptl++) {
    int p = p0 + ((pt0 + ptl) << 4) + (l & 15);
    int bb = p >> 15, hw = p & 32767;
    float* ob2 = out + (((size_t)bb * 19) << 15) + hw;
    #pragma unroll
    for (int ot = 0; ot < 2; ot++) {
      int obase = (ot << 4) + ((l >> 4) << 2);
      f32x4 a = a5[ot][ptl];
      #pragma unroll
      for (int i = 0; i < 4; i++) {
        int o = obase + i;
        if (o < 19) {
          float2 c5 = cst5[o];
          ob2[(size_t)o << 15] = fmaf(a[i], c5.x, c5.y);
        }
      }
    }
  }
}

// ---------------- launch ----------------
extern "C" void kernel_launch(void* const* d_in, const int* in_sizes, int n_in,
                              void* d_out, int out_size, void* d_ws, size_t ws_size,
                              hipStream_t stream) {
  (void)in_sizes; (void)n_in; (void)out_size; (void)ws_size;
  char* ws = (char*)d_ws;
  PArgs P;
  P.dw1  = (const float*)d_in[1];
  P.pw1  = (const float*)d_in[2];
  P.dw2  = (const float*)d_in[3];
  P.pw2  = (const float*)d_in[4];
  P.clsw = (const float*)d_in[5];
  P.clsb = (const float*)d_in[6];
  P.g1 = (const float*)d_in[7];  P.b1 = (const float*)d_in[8];
  P.m1 = (const float*)d_in[9];  P.v1 = (const float*)d_in[10];
  P.g2 = (const float*)d_in[11]; P.b2 = (const float*)d_in[12];
  P.m2 = (const float*)d_in[13]; P.v2 = (const float*)d_in[14];
  P.g3 = (const float*)d_in[15]; P.b3 = (const float*)d_in[16];
  P.m3 = (const float*)d_in[17]; P.v3 = (const float*)d_in[18];
  P.g4 = (const float*)d_in[19]; P.b4 = (const float*)d_in[20];
  P.m4 = (const float*)d_in[21]; P.v4 = (const float*)d_in[22];
  P.s1 = (const float*)d_in[23]; P.s2 = (const float*)d_in[24];
  P.s3 = (const float*)d_in[25]; P.s4 = (const float*)d_in[26];

  const float* x = (const float*)d_in[0];
  unsigned char* bufA = (unsigned char*)(ws + OFF_BUFA);
  unsigned char* bufB = (unsigned char*)(ws + OFF_BUFB);

  prep_kernel<<<544, 64, 0, stream>>>(P, ws);
  dwA_kernel<<<1024, 512, 0, stream>>>(x, ws, P.s1);                       // x -> k1 NCHW u8 (B)
  tr_kernel<<<1024, 256, 0, stream>>>(ws);                                 // k1 NCHW (B) -> NHWC (A)
  pw_kernel<<<2048, 256, 0, stream>>>(bufA, bufB,
      (const unsigned short*)(ws + OFF_R2BF), (const f32x4*)(ws + OFF_CST2), P.s2);  // k1 -> k2 (B)
  dw2_kernel<<<8192, 256, 0, stream>>>(bufB, bufA, ws, P.s3);              // k2 -> k3 (A)
  pwcls_kernel<<<2048, 256, 0, stream>>>(bufA, (float*)d_out,
      (const unsigned short*)(ws + OFF_R4BF), (const f32x4*)(ws + OFF_CST4), P.s4,
      (const unsigned short*)(ws + OFF_R5BF), (const float2*)(ws + OFF_CST5));       // k3 -> out
}

// Round 10
// 136.368 us; speedup vs baseline: 1.8104x; 1.0849x over previous
//
#include <hip/hip_runtime.h>

typedef __attribute__((ext_vector_type(4))) float f32x4;
typedef __attribute__((ext_vector_type(8))) short bf16x8;
typedef __attribute__((ext_vector_type(2))) unsigned int u32x2;
typedef __attribute__((ext_vector_type(4))) unsigned int u32x4;

#define EPSV 1e-5f

// workspace layout (bytes)
#define OFF_BUFA 0u
#define OFF_BUFB 33554432u
#define OFF_T    67108864u
#define OFF_WQ1  (OFF_T + 0u)       // f32 [128][12]  (9 taps used)
#define OFF_R3F  (OFF_T + 6144u)    // f32 [9][128]   integer-valued
#define OFF_CST3 (OFF_T + 10752u)   // f32x4 [128]
#define OFF_CST1 (OFF_T + 12800u)   // f32x4 [128]
#define OFF_R2BF (OFF_T + 14848u)   // bf16 [128][128]
#define OFF_CST2 (OFF_T + 47616u)   // f32x4 [128]
#define OFF_R4BF (OFF_T + 49664u)   // bf16 [128][128]
#define OFF_CST4 (OFF_T + 82432u)   // f32x4 [128]
#define OFF_R5BF (OFF_T + 84480u)   // bf16 [32][128] (rows 19..31 zero)
#define OFF_CST5 (OFF_T + 92672u)   // float2 [32]

struct PArgs {
  const float *dw1, *pw1, *dw2, *pw2, *clsw, *clsb;
  const float *g1, *b1, *m1, *v1;
  const float *g2, *b2, *m2, *v2;
  const float *g3, *b3, *m3, *v3;
  const float *g4, *b4, *m4, *v4;
  const float *s1, *s2, *s3, *s4;
};

__device__ __forceinline__ unsigned short f2bf(float f) {
  return (unsigned short)(__builtin_bit_cast(unsigned int, f) >> 16);
}
__device__ __forceinline__ float clip7(float r) { return fminf(fmaxf(r, -7.f), 7.f); }

// y = a*A; t = (y-m)*sc + b; k = clamp(rint(t/s),0,15).  c = {A, sc, m, b}
__device__ __forceinline__ unsigned int qstep(float a, f32x4 c, float s) {
  float t = (a * c.x - c.z) * c.y + c.w;
  float u = t / s;
  float k = fminf(fmaxf(rintf(u), 0.f), 15.f);
  return (unsigned int)k;
}

// 4 u8 -> 2 dwords of packed bf16
__device__ __forceinline__ void cvt2(unsigned int d, unsigned int &lo, unsigned int &hi) {
  float f0 = (float)(d & 0xffu);
  float f1 = (float)((d >> 8) & 0xffu);
  float f2 = (float)((d >> 16) & 0xffu);
  float f3 = (float)(d >> 24);
  lo = (__builtin_bit_cast(unsigned int, f0) >> 16) | (__builtin_bit_cast(unsigned int, f1) & 0xffff0000u);
  hi = (__builtin_bit_cast(unsigned int, f2) >> 16) | (__builtin_bit_cast(unsigned int, f3) & 0xffff0000u);
}

__device__ __forceinline__ float wmax16(float v) {
  #pragma unroll
  for (int s = 1; s < 16; s <<= 1) v = fmaxf(v, __shfl_xor(v, s));
  return v;
}
__device__ __forceinline__ float wmax64(float v) {
  #pragma unroll
  for (int s = 1; s < 64; s <<= 1) v = fmaxf(v, __shfl_xor(v, s));
  return v;
}

// ---------------- prep: quantize weights, fold BN constants ----------------
__global__ __launch_bounds__(64) void prep_kernel(PArgs P, char* __restrict__ ws) {
  int bi = blockIdx.x, l = threadIdx.x;
  float* wq1 = (float*)(ws + OFF_WQ1);
  float* r3f = (float*)(ws + OFF_R3F);
  f32x4* cst1 = (f32x4*)(ws + OFF_CST1);
  f32x4* cst2 = (f32x4*)(ws + OFF_CST2);
  f32x4* cst3 = (f32x4*)(ws + OFF_CST3);
  f32x4* cst4 = (f32x4*)(ws + OFF_CST4);
  unsigned short* r2 = (unsigned short*)(ws + OFF_R2BF);
  unsigned short* r4 = (unsigned short*)(ws + OFF_R4BF);
  unsigned short* r5 = (unsigned short*)(ws + OFF_R5BF);
  float2* cst5 = (float2*)(ws + OFF_CST5);

  if (bi < 128) {
    int c = bi;
    float w = (l < 9) ? P.dw1[c * 9 + l] : 0.f;
    float mx = wmax16(fabsf(w));
    float sq = fmaxf(mx / 7.0f, 1e-8f);
    if (l < 9) wq1[c * 12 + l] = clip7(rintf(w / sq)) * sq;
    if (l == 0) {
      float sc = P.g1[c] / sqrtf(P.v1[c] + EPSV);
      cst1[c] = f32x4{1.f, sc, P.m1[c], P.b1[c]};
    }
  } else if (bi < 256) {
    int o = bi - 128;
    float w0 = P.pw1[o * 128 + l], w1 = P.pw1[o * 128 + 64 + l];
    float mx = wmax64(fmaxf(fabsf(w0), fabsf(w1)));
    float sq = fmaxf(mx / 7.0f, 1e-8f);
    r2[o * 128 + l]      = f2bf(clip7(rintf(w0 / sq)));
    r2[o * 128 + 64 + l] = f2bf(clip7(rintf(w1 / sq)));
    if (l == 0) {
      float sc = P.g2[o] / sqrtf(P.v2[o] + EPSV);
      cst2[o] = f32x4{P.s1[0] * sq, sc, P.m2[o], P.b2[o]};
    }
  } else if (bi < 384) {
    int c = bi - 256;
    float w = (l < 9) ? P.dw2[c * 9 + l] : 0.f;
    float mx = wmax16(fabsf(w));
    float sq = fmaxf(mx / 7.0f, 1e-8f);
    if (l < 9) r3f[l * 128 + c] = clip7(rintf(w / sq));
    if (l == 0) {
      float sc = P.g3[c] / sqrtf(P.v3[c] + EPSV);
      cst3[c] = f32x4{P.s2[0] * sq, sc, P.m3[c], P.b3[c]};
    }
  } else if (bi < 512) {
    int o = bi - 384;
    float w0 = P.pw2[o * 128 + l], w1 = P.pw2[o * 128 + 64 + l];
    float mx = wmax64(fmaxf(fabsf(w0), fabsf(w1)));
    float sq = fmaxf(mx / 7.0f, 1e-8f);
    r4[o * 128 + l]      = f2bf(clip7(rintf(w0 / sq)));
    r4[o * 128 + 64 + l] = f2bf(clip7(rintf(w1 / sq)));
    if (l == 0) {
      float sc = P.g4[o] / sqrtf(P.v4[o] + EPSV);
      cst4[o] = f32x4{P.s3[0] * sq, sc, P.m4[o], P.b4[o]};
    }
  } else {
    int o = bi - 512;
    if (o < 19) {
      float w0 = P.clsw[o * 128 + l], w1 = P.clsw[o * 128 + 64 + l];
      float mx = wmax64(fmaxf(fabsf(w0), fabsf(w1)));
      float sq = fmaxf(mx / 7.0f, 1e-8f);
      r5[o * 128 + l]      = f2bf(clip7(rintf(w0 / sq)));
      r5[o * 128 + 64 + l] = f2bf(clip7(rintf(w1 / sq)));
      if (l == 0) {
        float A5 = P.s4[0] * sq;
        float bq = rintf(P.clsb[o] / A5) * A5;
        cst5[o] = make_float2(A5, bq);
      }
    } else {
      r5[o * 128 + l] = 0; r5[o * 128 + 64 + l] = 0;
      if (l == 0) cst5[o] = make_float2(0.f, 0.f);
    }
  }
}

// ---------------- dw-conv1 phase A: per-plane streaming, rolling 3-row window ----------------
// block = (b, c): one full 128x256 plane, each input row read ONCE.
// Output u8 NCHW plane; fmaf/qstep order identical to r1..r9 -> bit-identical bytes.
__global__ __launch_bounds__(512) void dwA_kernel(const float* __restrict__ x,
                                                  char* __restrict__ ws,
                                                  const float* __restrict__ s1p) {
  int bid = blockIdx.x;
  int b = bid & 7, c = bid >> 3;              // XCD x owns image b=x
  int tid = threadIdx.x;
  int wq = tid & 63, wv = tid >> 6;
  int w0 = wq << 2;
  int h0 = wv << 4;
  const float* wp = (const float*)(ws + OFF_WQ1) + c * 12;
  float k0 = wp[0], k1 = wp[1], k2 = wp[2], k3 = wp[3], k4 = wp[4],
        k5 = wp[5], k6 = wp[6], k7 = wp[7], k8 = wp[8];
  f32x4 cs = ((const f32x4*)(ws + OFF_CST1))[c];
  float s_act = *s1p;
  const float* plane = x + (((size_t)((b << 7) | c)) << 15);
  unsigned char* oplane = (unsigned char*)(ws + OFF_BUFB) + (((size_t)((b << 7) | c)) << 15);

  f32x4 vm = {0.f, 0.f, 0.f, 0.f};
  if (h0 > 0) vm = *(const f32x4*)(plane + ((h0 - 1) << 8) + w0);
  f32x4 v0 = *(const f32x4*)(plane + (h0 << 8) + w0);
  f32x4 vp = *(const f32x4*)(plane + ((h0 + 1) << 8) + w0);
  float lm = __shfl_up(vm.w, 1), l0 = __shfl_up(v0.w, 1), lp = __shfl_up(vp.w, 1);
  float rm = __shfl_down(vm.x, 1), r0 = __shfl_down(v0.x, 1), rp = __shfl_down(vp.x, 1);
  if (wq == 0)  { lm = 0.f; l0 = 0.f; lp = 0.f; }
  if (wq == 63) { rm = 0.f; r0 = 0.f; rp = 0.f; }

  #pragma unroll 4
  for (int i = 0; i < 16; i++) {
    int h = h0 + i;
    float y0 = 0.f, y1 = 0.f, y2 = 0.f, y3 = 0.f;
    // row -1 (k0,k1,k2) then row 0 (k3,k4,k5) then row +1 (k6,k7,k8) — r1 order
    y0 = fmaf(lm,   k0, y0); y0 = fmaf(vm.x, k1, y0); y0 = fmaf(vm.y, k2, y0);
    y1 = fmaf(vm.x, k0, y1); y1 = fmaf(vm.y, k1, y1); y1 = fmaf(vm.z, k2, y1);
    y2 = fmaf(vm.y, k0, y2); y2 = fmaf(vm.z, k1, y2); y2 = fmaf(vm.w, k2, y2);
    y3 = fmaf(vm.z, k0, y3); y3 = fmaf(vm.w, k1, y3); y3 = fmaf(rm,   k2, y3);

    y0 = fmaf(l0,   k3, y0); y0 = fmaf(v0.x, k4, y0); y0 = fmaf(v0.y, k5, y0);
    y1 = fmaf(v0.x, k3, y1); y1 = fmaf(v0.y, k4, y1); y1 = fmaf(v0.z, k5, y1);
    y2 = fmaf(v0.y, k3, y2); y2 = fmaf(v0.z, k4, y2); y2 = fmaf(v0.w, k5, y2);
    y3 = fmaf(v0.z, k3, y3); y3 = fmaf(v0.w, k4, y3); y3 = fmaf(r0,   k5, y3);

    y0 = fmaf(lp,   k6, y0); y0 = fmaf(vp.x, k7, y0); y0 = fmaf(vp.y, k8, y0);
    y1 = fmaf(vp.x, k6, y1); y1 = fmaf(vp.y, k7, y1); y1 = fmaf(vp.z, k8, y1);
    y2 = fmaf(vp.y, k6, y2); y2 = fmaf(vp.z, k7, y2); y2 = fmaf(vp.w, k8, y2);
    y3 = fmaf(vp.z, k6, y3); y3 = fmaf(vp.w, k7, y3); y3 = fmaf(rp,   k8, y3);

    unsigned int pk = qstep(y0, cs, s_act) | (qstep(y1, cs, s_act) << 8) |
                      (qstep(y2, cs, s_act) << 16) | (qstep(y3, cs, s_act) << 24);
    *(unsigned int*)(oplane + (h << 8) + w0) = pk;

    // shift window; load row h+2 for next iteration
    vm = v0; lm = l0; rm = r0;
    v0 = vp; l0 = lp; r0 = rp;
    f32x4 nv = {0.f, 0.f, 0.f, 0.f};
    if (i < 15 && h + 2 < 128) nv = *(const f32x4*)(plane + ((h + 2) << 8) + w0);
    vp = nv;
    float nl = __shfl_up(nv.w, 1), nr = __shfl_down(nv.x, 1);
    if (wq == 0)  nl = 0.f;
    if (wq == 63) nr = 0.f;
    lp = nl; rp = nr;
  }
}

// ---------------- pw1 from NCHW: staging does the transpose in-register ----------------
// thread = (pb = tid&7 -> 16 consecutive positions, cq = tid>>3 -> 4 channels).
// 4 x u32x4 loads (16 pos from 4 planes), 4x16 byte transpose, cvt2, 8B LDS writes.
// Physical LDS slot = logical ^ ((pb&7)<<4) (position-slot low bits) -> conflict-free;
// MFMA read applies the same XOR. Byte values identical to NHWC path -> exact.
__global__ __launch_bounds__(256) void pwn_kernel(const unsigned char* __restrict__ in,
                                                  unsigned char* __restrict__ out,
                                                  const unsigned short* __restrict__ rbf,
                                                  const f32x4* __restrict__ cst,
                                                  const float* __restrict__ sp) {
  __shared__ unsigned char lds[32768];
  int tid = threadIdx.x;
  int p0 = blockIdx.x << 7;
  int b_img = p0 >> 15, loc0 = p0 & 32767;
  {
    int pb = tid & 7, cq = tid >> 3;
    int c4 = cq << 2;
    int kc = cq >> 3, lgr = (cq >> 1) & 3, half = cq & 1;
    const unsigned char* ib = in + (((size_t)(b_img << 7)) << 15) + loc0 + (pb << 4);
    u32x4 t0 = *(const u32x4*)(ib + ((size_t)(c4 + 0) << 15));
    u32x4 t1 = *(const u32x4*)(ib + ((size_t)(c4 + 1) << 15));
    u32x4 t2 = *(const u32x4*)(ib + ((size_t)(c4 + 2) << 15));
    u32x4 t3 = *(const u32x4*)(ib + ((size_t)(c4 + 3) << 15));
    int swz = (pb & 7) << 4;
    #pragma unroll
    for (int s = 0; s < 16; s++) {
      int wrd = s >> 2, sh8 = (s & 3) << 3;
      unsigned int chw = ((t0[wrd] >> sh8) & 0xffu)
                       | (((t1[wrd] >> sh8) & 0xffu) << 8)
                       | (((t2[wrd] >> sh8) & 0xffu) << 16)
                       | (((t3[wrd] >> sh8) & 0xffu) << 24);
      unsigned int lo, hi;
      cvt2(chw, lo, hi);
      int ad = ((((((pb << 2) + kc) << 6) | s | (lgr << 4)) << 4) + (half << 3)) ^ swz;
      *(u32x2*)(lds + ad) = u32x2{lo, hi};
    }
  }
  __syncthreads();
  int l = tid & 63, wv = tid >> 6;
  int ob = wv << 5;                          // wave owns 32 output channels
  bf16x8 af[2][4];
  #pragma unroll
  for (int ot = 0; ot < 2; ot++)
    #pragma unroll
    for (int kc = 0; kc < 4; kc++) {
      int o = ob + (ot << 4) + (l & 15);
      int k = (kc << 5) + ((l >> 4) << 3);
      af[ot][kc] = *(const bf16x8*)(rbf + o * 128 + k);
    }
  f32x4 acc[2][8];
  #pragma unroll
  for (int ot = 0; ot < 2; ot++)
    #pragma unroll
    for (int pt = 0; pt < 8; pt++) acc[ot][pt] = f32x4{0.f, 0.f, 0.f, 0.f};
  #pragma unroll
  for (int kc = 0; kc < 4; kc++) {
    bf16x8 bb[8];
    #pragma unroll
    for (int pt = 0; pt < 8; pt++)
      bb[pt] = *(const bf16x8*)(lds + (((((((pt << 2) + kc) << 6)) + l) << 4) ^ ((pt & 7) << 4)));
    #pragma unroll
    for (int ot = 0; ot < 2; ot++)
      #pragma unroll
      for (int pt = 0; pt < 8; pt++)
        acc[ot][pt] = __builtin_amdgcn_mfma_f32_16x16x32_bf16(af[ot][kc], bb[pt], acc[ot][pt], 0, 0, 0);
  }
  float s_act = *sp;
  #pragma unroll
  for (int ot = 0; ot < 2; ot++) {
    int o0 = ob + (ot << 4) + ((l >> 4) << 2);
    f32x4 c0 = cst[o0], c1 = cst[o0 + 1], c2 = cst[o0 + 2], c3 = cst[o0 + 3];
    #pragma unroll
    for (int pt = 0; pt < 8; pt++) {
      int p = p0 + (pt << 4) + (l & 15);
      f32x4 a = acc[ot][pt];
      unsigned int pk = qstep(a.x, c0, s_act) | (qstep(a.y, c1, s_act) << 8) |
                        (qstep(a.z, c2, s_act) << 16) | (qstep(a.w, c3, s_act) << 24);
      *(unsigned int*)(out + (size_t)p * 128 + o0) = pk;
    }
  }
}

// ---------------- dw-conv2 v2: 4-consecutive-position sliding window ----------------
__global__ __launch_bounds__(256) void dw2_kernel(const unsigned char* __restrict__ in,
                                                  unsigned char* __restrict__ out,
                                                  const char* __restrict__ ws,
                                                  const float* __restrict__ sp) {
  __shared__ float tabs[1664];
  const float* src = (const float*)(ws + OFF_R3F);
  for (int i = threadIdx.x; i < 1664; i += 256) tabs[i] = src[i];
  __syncthreads();
  int tid = threadIdx.x;
  int cq = tid & 31, pg = tid >> 5;
  int c4 = cq << 2;
  float wk[9][4];
  #pragma unroll
  for (int t = 0; t < 9; t++) {
    wk[t][0] = tabs[t * 128 + c4];     wk[t][1] = tabs[t * 128 + c4 + 1];
    wk[t][2] = tabs[t * 128 + c4 + 2]; wk[t][3] = tabs[t * 128 + c4 + 3];
  }
  const f32x4* cst3 = (const f32x4*)(tabs + 1152);
  f32x4 cs0 = cst3[c4], cs1 = cst3[c4 + 1], cs2 = cst3[c4 + 2], cs3 = cst3[c4 + 3];
  float s_act = *sp;
  int pbase = (blockIdx.x << 5) + (pg << 2);     // 4 consecutive positions, same h row
  int wbase = pbase & 255, hh = (pbase >> 8) & 127;

  unsigned int xw[3][6];
  #pragma unroll
  for (int r = 0; r < 3; r++) {
    int dh = r - 1;
    bool rowok = (hh + dh >= 0) && (hh + dh <= 127);
    #pragma unroll
    for (int i = 0; i < 6; i++) {
      int wo = wbase + i - 1;
      unsigned int v = 0;
      if (rowok && wo >= 0 && wo <= 255)
        v = *(const unsigned int*)(in + (size_t)(pbase + dh * 256 + (i - 1)) * 128 + c4);
      xw[r][i] = v;
    }
  }
  #pragma unroll
  for (int j = 0; j < 4; j++) {
    float a0 = 0.f, a1 = 0.f, a2 = 0.f, a3 = 0.f;
    #pragma unroll
    for (int r = 0; r < 3; r++) {
      #pragma unroll
      for (int dwi = 0; dwi < 3; dwi++) {
        unsigned int v = xw[r][j + dwi];
        int t = r * 3 + dwi;
        a0 = fmaf((float)(v & 0xffu),         wk[t][0], a0);
        a1 = fmaf((float)((v >> 8) & 0xffu),  wk[t][1], a1);
        a2 = fmaf((float)((v >> 16) & 0xffu), wk[t][2], a2);
        a3 = fmaf((float)(v >> 24),           wk[t][3], a3);
      }
    }
    unsigned int pk = qstep(a0, cs0, s_act) | (qstep(a1, cs1, s_act) << 8) |
                      (qstep(a2, cs2, s_act) << 16) | (qstep(a3, cs3, s_act) << 24);
    *(unsigned int*)(out + (size_t)(pbase + j) * 128 + c4) = pk;
  }
}

// ---------------- fused pw2 + BN4 + qrelu + classifier ----------------
__global__ __launch_bounds__(256) void pwcls_kernel(const unsigned char* __restrict__ in,
                                                    float* __restrict__ out,
                                                    const unsigned short* __restrict__ rbf,
                                                    const f32x4* __restrict__ cst,
                                                    const float* __restrict__ sp,
                                                    const unsigned short* __restrict__ r5,
                                                    const float2* __restrict__ cst5) {
  __shared__ unsigned char lds[32768];
  int tid = threadIdx.x;
  int p0 = blockIdx.x << 7;
  #pragma unroll
  for (int it = 0; it < 4; it++) {
    int idx = tid + (it << 8);
    int p = idx >> 3, q = idx & 7;
    int kc = q >> 1, lg = (q & 1) << 1, pt = p >> 4;
    u32x4 g = *(const u32x4*)(in + (size_t)(p0 + p) * 128 + q * 16);
    unsigned int a0, a1, a2, a3, a4, a5, a6, a7;
    cvt2(g.x, a0, a1); cvt2(g.y, a2, a3); cvt2(g.z, a4, a5); cvt2(g.w, a6, a7);
    int l1 = (p & 15) | (lg << 4);
    int ad = (((((pt << 2) + kc) << 6) | l1) << 4);
    *(u32x4*)(lds + ad)       = u32x4{a0, a1, a2, a3};
    *(u32x4*)(lds + ad + 256) = u32x4{a4, a5, a6, a7};
  }
  __syncthreads();
  int l = tid & 63, wv = tid >> 6;
  int ob = wv << 5;
  bf16x8 af[2][4];
  #pragma unroll
  for (int ot = 0; ot < 2; ot++)
    #pragma unroll
    for (int kc = 0; kc < 4; kc++) {
      int o = ob + (ot << 4) + (l & 15);
      int k = (kc << 5) + ((l >> 4) << 3);
      af[ot][kc] = *(const bf16x8*)(rbf + o * 128 + k);
    }
  f32x4 acc[2][8];
  #pragma unroll
  for (int ot = 0; ot < 2; ot++)
    #pragma unroll
    for (int pt = 0; pt < 8; pt++) acc[ot][pt] = f32x4{0.f, 0.f, 0.f, 0.f};
  #pragma unroll
  for (int kc = 0; kc < 4; kc++) {
    bf16x8 bb[8];
    #pragma unroll
    for (int pt = 0; pt < 8; pt++)
      bb[pt] = *(const bf16x8*)(lds + ((((((pt << 2) + kc) << 6)) + l) << 4));
    #pragma unroll
    for (int ot = 0; ot < 2; ot++)
      #pragma unroll
      for (int pt = 0; pt < 8; pt++)
        acc[ot][pt] = __builtin_amdgcn_mfma_f32_16x16x32_bf16(af[ot][kc], bb[pt], acc[ot][pt], 0, 0, 0);
  }
  float s_act = *sp;
  __syncthreads();   // all waves done reading k3 fragments; lds is reusable
  {
    int hsel = (l >> 4) & 1;
    #pragma unroll
    for (int ot = 0; ot < 2; ot++) {
      int o0 = ob + (ot << 4) + ((l >> 4) << 2);
      f32x4 c0 = cst[o0], c1 = cst[o0 + 1], c2 = cst[o0 + 2], c3 = cst[o0 + 3];
      int hi = (ot << 1) + ((l >> 4) >> 1);
      int lfrag = (l & 15) | (hi << 4);
      #pragma unroll
      for (int pt = 0; pt < 8; pt++) {
        f32x4 a = acc[ot][pt];
        unsigned int k0 = qstep(a.x, c0, s_act), k1 = qstep(a.y, c1, s_act);
        unsigned int k2 = qstep(a.z, c2, s_act), k3 = qstep(a.w, c3, s_act);
        unsigned int w0 = (__builtin_bit_cast(unsigned int, (float)k0) >> 16) |
                          (__builtin_bit_cast(unsigned int, (float)k1) & 0xffff0000u);
        unsigned int w1 = (__builtin_bit_cast(unsigned int, (float)k2) >> 16) |
                          (__builtin_bit_cast(unsigned int, (float)k3) & 0xffff0000u);
        int ad = (((((pt << 2) + wv) << 6) | lfrag) << 4) + (hsel << 3);
        *(u32x2*)(lds + ad) = u32x2{w0, w1};
      }
    }
  }
  __syncthreads();
  int pt0 = wv << 1;
  bf16x8 af5[2][4];
  #pragma unroll
  for (int ot = 0; ot < 2; ot++)
    #pragma unroll
    for (int kc = 0; kc < 4; kc++) {
      int o = (ot << 4) + (l & 15);
      int k = (kc << 5) + ((l >> 4) << 3);
      af5[ot][kc] = *(const bf16x8*)(r5 + o * 128 + k);
    }
  f32x4 a5[2][2] = {{{0,0,0,0},{0,0,0,0}},{{0,0,0,0},{0,0,0,0}}};
  #pragma unroll
  for (int kc = 0; kc < 4; kc++) {
    bf16x8 b0 = *(const bf16x8*)(lds + ((((((pt0    ) << 2) + kc) << 6) + l) << 4));
    bf16x8 b1 = *(const bf16x8*)(lds + ((((((pt0 + 1) << 2) + kc) << 6) + l) << 4));
    #pragma unroll
    for (int ot = 0; ot < 2; ot++) {
      a5[ot][0] = __builtin_amdgcn_mfma_f32_16x16x32_bf16(af5[ot][kc], b0, a5[ot][0], 0, 0, 0);
      a5[ot][1] = __builtin_amdgcn_mfma_f32_16x16x32_bf16(af5[ot][kc], b1, a5[ot][1], 0, 0, 0);
    }
  }
  #pragma unroll
  for (int ptl = 0; ptl < 2; ptl++) {
    int p = p0 + ((pt0 + ptl) << 4) + (l & 15);
    int bb = p >> 15, hw = p & 32767;
    float* ob2 = out + (((size_t)bb * 19) << 15) + hw;
    #pragma unroll
    for (int ot = 0; ot < 2; ot++) {
      int obase = (ot << 4) + ((l >> 4) << 2);
      f32x4 a = a5[ot][ptl];
      #pragma unroll
      for (int i = 0; i < 4; i++) {
        int o = obase + i;
        if (o < 19) {
          float2 c5 = cst5[o];
          ob2[(size_t)o << 15] = fmaf(a[i], c5.x, c5.y);
        }
      }
    }
  }
}

// ---------------- launch ----------------
extern "C" void kernel_launch(void* const* d_in, const int* in_sizes, int n_in,
                              void* d_out, int out_size, void* d_ws, size_t ws_size,
                              hipStream_t stream) {
  (void)in_sizes; (void)n_in; (void)out_size; (void)ws_size;
  char* ws = (char*)d_ws;
  PArgs P;
  P.dw1  = (const float*)d_in[1];
  P.pw1  = (const float*)d_in[2];
  P.dw2  = (const float*)d_in[3];
  P.pw2  = (const float*)d_in[4];
  P.clsw = (const float*)d_in[5];
  P.clsb = (const float*)d_in[6];
  P.g1 = (const float*)d_in[7];  P.b1 = (const float*)d_in[8];
  P.m1 = (const float*)d_in[9];  P.v1 = (const float*)d_in[10];
  P.g2 = (const float*)d_in[11]; P.b2 = (const float*)d_in[12];
  P.m2 = (const float*)d_in[13]; P.v2 = (const float*)d_in[14];
  P.g3 = (const float*)d_in[15]; P.b3 = (const float*)d_in[16];
  P.m3 = (const float*)d_in[17]; P.v3 = (const float*)d_in[18];
  P.g4 = (const float*)d_in[19]; P.b4 = (const float*)d_in[20];
  P.m4 = (const float*)d_in[21]; P.v4 = (const float*)d_in[22];
  P.s1 = (const float*)d_in[23]; P.s2 = (const float*)d_in[24];
  P.s3 = (const float*)d_in[25]; P.s4 = (const float*)d_in[26];

  const float* x = (const float*)d_in[0];
  unsigned char* bufA = (unsigned char*)(ws + OFF_BUFA);
  unsigned char* bufB = (unsigned char*)(ws + OFF_BUFB);

  prep_kernel<<<544, 64, 0, stream>>>(P, ws);
  dwA_kernel<<<1024, 512, 0, stream>>>(x, ws, P.s1);                       // x -> k1 NCHW u8 (B)
  pwn_kernel<<<2048, 256, 0, stream>>>(bufB, bufA,
      (const unsigned short*)(ws + OFF_R2BF), (const f32x4*)(ws + OFF_CST2), P.s2);  // k1 NCHW -> k2 NHWC (A)
  dw2_kernel<<<8192, 256, 0, stream>>>(bufA, bufB, ws, P.s3);              // k2 -> k3 (B)
  pwcls_kernel<<<2048, 256, 0, stream>>>(bufB, (float*)d_out,
      (const unsigned short*)(ws + OFF_R4BF), (const f32x4*)(ws + OFF_CST4), P.s4,
      (const unsigned short*)(ws + OFF_R5BF), (const float2*)(ws + OFF_CST5));       // k3 -> out
}

// Round 11
// 136.082 us; speedup vs baseline: 1.8142x; 1.0021x over previous
//
#include <hip/hip_runtime.h>

typedef __attribute__((ext_vector_type(4))) float f32x4;
typedef __attribute__((ext_vector_type(8))) short bf16x8;
typedef __attribute__((ext_vector_type(2))) unsigned int u32x2;
typedef __attribute__((ext_vector_type(4))) unsigned int u32x4;

#define EPSV 1e-5f

// workspace layout (bytes)
#define OFF_BUFA 0u
#define OFF_BUFB 33554432u
#define OFF_T    67108864u
#define OFF_WQ1  (OFF_T + 0u)       // f32 [128][12]  (9 taps used)
#define OFF_R3F  (OFF_T + 6144u)    // f32 [9][128]   integer-valued
#define OFF_CST3 (OFF_T + 10752u)   // f32x4 [128]
#define OFF_CST1 (OFF_T + 12800u)   // f32x4 [128]
#define OFF_R2BF (OFF_T + 14848u)   // bf16 [128][128]
#define OFF_CST2 (OFF_T + 47616u)   // f32x4 [128]
#define OFF_R4BF (OFF_T + 49664u)   // bf16 [128][128]
#define OFF_CST4 (OFF_T + 82432u)   // f32x4 [128]
#define OFF_R5BF (OFF_T + 84480u)   // bf16 [32][128] (rows 19..31 zero)
#define OFF_CST5 (OFF_T + 92672u)   // float2 [32]

struct PArgs {
  const float *dw1, *pw1, *dw2, *pw2, *clsw, *clsb;
  const float *g1, *b1, *m1, *v1;
  const float *g2, *b2, *m2, *v2;
  const float *g3, *b3, *m3, *v3;
  const float *g4, *b4, *m4, *v4;
  const float *s1, *s2, *s3, *s4;
};

__device__ __forceinline__ unsigned short f2bf(float f) {
  return (unsigned short)(__builtin_bit_cast(unsigned int, f) >> 16);
}
__device__ __forceinline__ float clip7(float r) { return fminf(fmaxf(r, -7.f), 7.f); }

// t = (a*A - m)*sc + b; k = clamp(rint(t/s),0,15) as float.  c = {A, sc, m, b}
__device__ __forceinline__ float qstepf(float a, f32x4 c, float s) {
  float t = (a * c.x - c.z) * c.y + c.w;
  float u = t / s;
  return fminf(fmaxf(rintf(u), 0.f), 15.f);
}
__device__ __forceinline__ unsigned int qstep(float a, f32x4 c, float s) {
  return (unsigned int)qstepf(a, c, s);
}

// 4 u8 -> 2 dwords of packed bf16
__device__ __forceinline__ void cvt2(unsigned int d, unsigned int &lo, unsigned int &hi) {
  float f0 = (float)(d & 0xffu);
  float f1 = (float)((d >> 8) & 0xffu);
  float f2 = (float)((d >> 16) & 0xffu);
  float f3 = (float)(d >> 24);
  lo = (__builtin_bit_cast(unsigned int, f0) >> 16) | (__builtin_bit_cast(unsigned int, f1) & 0xffff0000u);
  hi = (__builtin_bit_cast(unsigned int, f2) >> 16) | (__builtin_bit_cast(unsigned int, f3) & 0xffff0000u);
}

__device__ __forceinline__ float wmax16(float v) {
  #pragma unroll
  for (int s = 1; s < 16; s <<= 1) v = fmaxf(v, __shfl_xor(v, s));
  return v;
}
__device__ __forceinline__ float wmax64(float v) {
  #pragma unroll
  for (int s = 1; s < 64; s <<= 1) v = fmaxf(v, __shfl_xor(v, s));
  return v;
}

// ---------------- prep: quantize weights, fold BN constants ----------------
__global__ __launch_bounds__(64) void prep_kernel(PArgs P, char* __restrict__ ws) {
  int bi = blockIdx.x, l = threadIdx.x;
  float* wq1 = (float*)(ws + OFF_WQ1);
  float* r3f = (float*)(ws + OFF_R3F);
  f32x4* cst1 = (f32x4*)(ws + OFF_CST1);
  f32x4* cst2 = (f32x4*)(ws + OFF_CST2);
  f32x4* cst3 = (f32x4*)(ws + OFF_CST3);
  f32x4* cst4 = (f32x4*)(ws + OFF_CST4);
  unsigned short* r2 = (unsigned short*)(ws + OFF_R2BF);
  unsigned short* r4 = (unsigned short*)(ws + OFF_R4BF);
  unsigned short* r5 = (unsigned short*)(ws + OFF_R5BF);
  float2* cst5 = (float2*)(ws + OFF_CST5);

  if (bi < 128) {
    int c = bi;
    float w = (l < 9) ? P.dw1[c * 9 + l] : 0.f;
    float mx = wmax16(fabsf(w));
    float sq = fmaxf(mx / 7.0f, 1e-8f);
    if (l < 9) wq1[c * 12 + l] = clip7(rintf(w / sq)) * sq;
    if (l == 0) {
      float sc = P.g1[c] / sqrtf(P.v1[c] + EPSV);
      cst1[c] = f32x4{1.f, sc, P.m1[c], P.b1[c]};
    }
  } else if (bi < 256) {
    int o = bi - 128;
    float w0 = P.pw1[o * 128 + l], w1 = P.pw1[o * 128 + 64 + l];
    float mx = wmax64(fmaxf(fabsf(w0), fabsf(w1)));
    float sq = fmaxf(mx / 7.0f, 1e-8f);
    r2[o * 128 + l]      = f2bf(clip7(rintf(w0 / sq)));
    r2[o * 128 + 64 + l] = f2bf(clip7(rintf(w1 / sq)));
    if (l == 0) {
      float sc = P.g2[o] / sqrtf(P.v2[o] + EPSV);
      cst2[o] = f32x4{P.s1[0] * sq, sc, P.m2[o], P.b2[o]};
    }
  } else if (bi < 384) {
    int c = bi - 256;
    float w = (l < 9) ? P.dw2[c * 9 + l] : 0.f;
    float mx = wmax16(fabsf(w));
    float sq = fmaxf(mx / 7.0f, 1e-8f);
    if (l < 9) r3f[l * 128 + c] = clip7(rintf(w / sq));
    if (l == 0) {
      float sc = P.g3[c] / sqrtf(P.v3[c] + EPSV);
      cst3[c] = f32x4{P.s2[0] * sq, sc, P.m3[c], P.b3[c]};
    }
  } else if (bi < 512) {
    int o = bi - 384;
    float w0 = P.pw2[o * 128 + l], w1 = P.pw2[o * 128 + 64 + l];
    float mx = wmax64(fmaxf(fabsf(w0), fabsf(w1)));
    float sq = fmaxf(mx / 7.0f, 1e-8f);
    r4[o * 128 + l]      = f2bf(clip7(rintf(w0 / sq)));
    r4[o * 128 + 64 + l] = f2bf(clip7(rintf(w1 / sq)));
    if (l == 0) {
      float sc = P.g4[o] / sqrtf(P.v4[o] + EPSV);
      cst4[o] = f32x4{P.s3[0] * sq, sc, P.m4[o], P.b4[o]};
    }
  } else {
    int o = bi - 512;
    if (o < 19) {
      float w0 = P.clsw[o * 128 + l], w1 = P.clsw[o * 128 + 64 + l];
      float mx = wmax64(fmaxf(fabsf(w0), fabsf(w1)));
      float sq = fmaxf(mx / 7.0f, 1e-8f);
      r5[o * 128 + l]      = f2bf(clip7(rintf(w0 / sq)));
      r5[o * 128 + 64 + l] = f2bf(clip7(rintf(w1 / sq)));
      if (l == 0) {
        float A5 = P.s4[0] * sq;
        float bq = rintf(P.clsb[o] / A5) * A5;
        cst5[o] = make_float2(A5, bq);
      }
    } else {
      r5[o * 128 + l] = 0; r5[o * 128 + 64 + l] = 0;
      if (l == 0) cst5[o] = make_float2(0.f, 0.f);
    }
  }
}

// ---------------- dw-conv1 phase A: per-plane streaming, rolling 3-row window ----------------
// block = (b, c): one full 128x256 plane, each input row read ONCE.
// Output u8 NCHW plane; fmaf/qstep order identical to r1..r10 -> bit-identical bytes.
__global__ __launch_bounds__(512) void dwA_kernel(const float* __restrict__ x,
                                                  char* __restrict__ ws,
                                                  const float* __restrict__ s1p) {
  int bid = blockIdx.x;
  int b = bid & 7, c = bid >> 3;              // XCD x owns image b=x
  int tid = threadIdx.x;
  int wq = tid & 63, wv = tid >> 6;
  int w0 = wq << 2;
  int h0 = wv << 4;
  const float* wp = (const float*)(ws + OFF_WQ1) + c * 12;
  float k0 = wp[0], k1 = wp[1], k2 = wp[2], k3 = wp[3], k4 = wp[4],
        k5 = wp[5], k6 = wp[6], k7 = wp[7], k8 = wp[8];
  f32x4 cs = ((const f32x4*)(ws + OFF_CST1))[c];
  float s_act = *s1p;
  const float* plane = x + (((size_t)((b << 7) | c)) << 15);
  unsigned char* oplane = (unsigned char*)(ws + OFF_BUFB) + (((size_t)((b << 7) | c)) << 15);

  f32x4 vm = {0.f, 0.f, 0.f, 0.f};
  if (h0 > 0) vm = *(const f32x4*)(plane + ((h0 - 1) << 8) + w0);
  f32x4 v0 = *(const f32x4*)(plane + (h0 << 8) + w0);
  f32x4 vp = *(const f32x4*)(plane + ((h0 + 1) << 8) + w0);
  float lm = __shfl_up(vm.w, 1), l0 = __shfl_up(v0.w, 1), lp = __shfl_up(vp.w, 1);
  float rm = __shfl_down(vm.x, 1), r0 = __shfl_down(v0.x, 1), rp = __shfl_down(vp.x, 1);
  if (wq == 0)  { lm = 0.f; l0 = 0.f; lp = 0.f; }
  if (wq == 63) { rm = 0.f; r0 = 0.f; rp = 0.f; }

  #pragma unroll 4
  for (int i = 0; i < 16; i++) {
    int h = h0 + i;
    float y0 = 0.f, y1 = 0.f, y2 = 0.f, y3 = 0.f;
    // row -1 (k0,k1,k2) then row 0 (k3,k4,k5) then row +1 (k6,k7,k8) — r1 order
    y0 = fmaf(lm,   k0, y0); y0 = fmaf(vm.x, k1, y0); y0 = fmaf(vm.y, k2, y0);
    y1 = fmaf(vm.x, k0, y1); y1 = fmaf(vm.y, k1, y1); y1 = fmaf(vm.z, k2, y1);
    y2 = fmaf(vm.y, k0, y2); y2 = fmaf(vm.z, k1, y2); y2 = fmaf(vm.w, k2, y2);
    y3 = fmaf(vm.z, k0, y3); y3 = fmaf(vm.w, k1, y3); y3 = fmaf(rm,   k2, y3);

    y0 = fmaf(l0,   k3, y0); y0 = fmaf(v0.x, k4, y0); y0 = fmaf(v0.y, k5, y0);
    y1 = fmaf(v0.x, k3, y1); y1 = fmaf(v0.y, k4, y1); y1 = fmaf(v0.z, k5, y1);
    y2 = fmaf(v0.y, k3, y2); y2 = fmaf(v0.z, k4, y2); y2 = fmaf(v0.w, k5, y2);
    y3 = fmaf(v0.z, k3, y3); y3 = fmaf(v0.w, k4, y3); y3 = fmaf(r0,   k5, y3);

    y0 = fmaf(lp,   k6, y0); y0 = fmaf(vp.x, k7, y0); y0 = fmaf(vp.y, k8, y0);
    y1 = fmaf(vp.x, k6, y1); y1 = fmaf(vp.y, k7, y1); y1 = fmaf(vp.z, k8, y1);
    y2 = fmaf(vp.y, k6, y2); y2 = fmaf(vp.z, k7, y2); y2 = fmaf(vp.w, k8, y2);
    y3 = fmaf(vp.z, k6, y3); y3 = fmaf(vp.w, k7, y3); y3 = fmaf(rp,   k8, y3);

    unsigned int pk = qstep(y0, cs, s_act) | (qstep(y1, cs, s_act) << 8) |
                      (qstep(y2, cs, s_act) << 16) | (qstep(y3, cs, s_act) << 24);
    *(unsigned int*)(oplane + (h << 8) + w0) = pk;

    // shift window; load row h+2 for next iteration
    vm = v0; lm = l0; rm = r0;
    v0 = vp; l0 = lp; r0 = rp;
    f32x4 nv = {0.f, 0.f, 0.f, 0.f};
    if (i < 15 && h + 2 < 128) nv = *(const f32x4*)(plane + ((h + 2) << 8) + w0);
    vp = nv;
    float nl = __shfl_up(nv.w, 1), nr = __shfl_down(nv.x, 1);
    if (wq == 0)  nl = 0.f;
    if (wq == 63) nr = 0.f;
    lp = nl; rp = nr;
  }
}

// ---------------- pw1 from NCHW: staging does the transpose in-register ----------------
__global__ __launch_bounds__(256) void pwn_kernel(const unsigned char* __restrict__ in,
                                                  unsigned char* __restrict__ out,
                                                  const unsigned short* __restrict__ rbf,
                                                  const f32x4* __restrict__ cst,
                                                  const float* __restrict__ sp) {
  __shared__ unsigned char lds[32768];
  int tid = threadIdx.x;
  int p0 = blockIdx.x << 7;
  int b_img = p0 >> 15, loc0 = p0 & 32767;
  {
    int pb = tid & 7, cq = tid >> 3;
    int c4 = cq << 2;
    int kc = cq >> 3, lgr = (cq >> 1) & 3, half = cq & 1;
    const unsigned char* ib = in + (((size_t)(b_img << 7)) << 15) + loc0 + (pb << 4);
    u32x4 t0 = *(const u32x4*)(ib + ((size_t)(c4 + 0) << 15));
    u32x4 t1 = *(const u32x4*)(ib + ((size_t)(c4 + 1) << 15));
    u32x4 t2 = *(const u32x4*)(ib + ((size_t)(c4 + 2) << 15));
    u32x4 t3 = *(const u32x4*)(ib + ((size_t)(c4 + 3) << 15));
    int swz = (pb & 7) << 4;
    #pragma unroll
    for (int s = 0; s < 16; s++) {
      int wrd = s >> 2, sh8 = (s & 3) << 3;
      unsigned int chw = ((t0[wrd] >> sh8) & 0xffu)
                       | (((t1[wrd] >> sh8) & 0xffu) << 8)
                       | (((t2[wrd] >> sh8) & 0xffu) << 16)
                       | (((t3[wrd] >> sh8) & 0xffu) << 24);
      unsigned int lo, hi;
      cvt2(chw, lo, hi);
      int ad = ((((((pb << 2) + kc) << 6) | s | (lgr << 4)) << 4) + (half << 3)) ^ swz;
      *(u32x2*)(lds + ad) = u32x2{lo, hi};
    }
  }
  __syncthreads();
  int l = tid & 63, wv = tid >> 6;
  int ob = wv << 5;                          // wave owns 32 output channels
  bf16x8 af[2][4];
  #pragma unroll
  for (int ot = 0; ot < 2; ot++)
    #pragma unroll
    for (int kc = 0; kc < 4; kc++) {
      int o = ob + (ot << 4) + (l & 15);
      int k = (kc << 5) + ((l >> 4) << 3);
      af[ot][kc] = *(const bf16x8*)(rbf + o * 128 + k);
    }
  f32x4 acc[2][8];
  #pragma unroll
  for (int ot = 0; ot < 2; ot++)
    #pragma unroll
    for (int pt = 0; pt < 8; pt++) acc[ot][pt] = f32x4{0.f, 0.f, 0.f, 0.f};
  #pragma unroll
  for (int kc = 0; kc < 4; kc++) {
    bf16x8 bb[8];
    #pragma unroll
    for (int pt = 0; pt < 8; pt++)
      bb[pt] = *(const bf16x8*)(lds + (((((((pt << 2) + kc) << 6)) + l) << 4) ^ ((pt & 7) << 4)));
    #pragma unroll
    for (int ot = 0; ot < 2; ot++)
      #pragma unroll
      for (int pt = 0; pt < 8; pt++)
        acc[ot][pt] = __builtin_amdgcn_mfma_f32_16x16x32_bf16(af[ot][kc], bb[pt], acc[ot][pt], 0, 0, 0);
  }
  float s_act = *sp;
  #pragma unroll
  for (int ot = 0; ot < 2; ot++) {
    int o0 = ob + (ot << 4) + ((l >> 4) << 2);
    f32x4 c0 = cst[o0], c1 = cst[o0 + 1], c2 = cst[o0 + 2], c3 = cst[o0 + 3];
    #pragma unroll
    for (int pt = 0; pt < 8; pt++) {
      int p = p0 + (pt << 4) + (l & 15);
      f32x4 a = acc[ot][pt];
      unsigned int pk = qstep(a.x, c0, s_act) | (qstep(a.y, c1, s_act) << 8) |
                        (qstep(a.z, c2, s_act) << 16) | (qstep(a.w, c3, s_act) << 24);
      *(unsigned int*)(out + (size_t)p * 128 + o0) = pk;
    }
  }
}

// ---------------- fused dw2 + BN3 + qrelu + pw2 + BN4 + qrelu + classifier ----------------
// k3 never touches global memory: dw2's quantized outputs are written as bf16 pairs
// straight into the pw2 B-fragment LDS layout, with slot[2:0] XOR g (g = hi|((kc&1)<<2))
// applied on BOTH the write and the MFMA read (bank-conflict fix, bijective per (kc,hi)).
__global__ __launch_bounds__(256) void dw2pwcls_kernel(const unsigned char* __restrict__ in,
                                                       float* __restrict__ out,
                                                       const char* __restrict__ ws,
                                                       const unsigned short* __restrict__ rbf,
                                                       const f32x4* __restrict__ cst,
                                                       const float* __restrict__ s3p,
                                                       const float* __restrict__ s4p,
                                                       const unsigned short* __restrict__ r5,
                                                       const float2* __restrict__ cst5) {
  __shared__ unsigned char lds[32768];
  int tid = threadIdx.x;
  int p0 = blockIdx.x << 7;          // 128 consecutive positions, single h row
  // ---- phase 1: dw2 sliding window -> bf16 fragments (swizzled) ----
  {
    int cq = tid & 31, pg = tid >> 5;
    int c4 = cq << 2;
    const float* r3f = (const float*)(ws + OFF_R3F);
    float wk[9][4];
    #pragma unroll
    for (int t = 0; t < 9; t++) {
      wk[t][0] = r3f[t * 128 + c4];     wk[t][1] = r3f[t * 128 + c4 + 1];
      wk[t][2] = r3f[t * 128 + c4 + 2]; wk[t][3] = r3f[t * 128 + c4 + 3];
    }
    const f32x4* cst3 = (const f32x4*)(ws + OFF_CST3);
    f32x4 cs0 = cst3[c4], cs1 = cst3[c4 + 1], cs2 = cst3[c4 + 2], cs3 = cst3[c4 + 3];
    float s_act3 = *s3p;
    int kc = c4 >> 5, hi = (c4 >> 3) & 3, half = (c4 >> 2) & 1;
    int g = hi | ((kc & 1) << 2);
    for (int ps = 0; ps < 4; ps++) {
      int pbase = p0 + (ps << 5) + (pg << 2);   // 4 consecutive positions
      int wbase = pbase & 255, hh = (pbase >> 8) & 127;
      unsigned int xw[3][6];
      #pragma unroll
      for (int r = 0; r < 3; r++) {
        int dh = r - 1;
        bool rowok = (hh + dh >= 0) && (hh + dh <= 127);
        #pragma unroll
        for (int i = 0; i < 6; i++) {
          int wo = wbase + i - 1;
          unsigned int v = 0;
          if (rowok && wo >= 0 && wo <= 255)
            v = *(const unsigned int*)(in + (size_t)(pbase + dh * 256 + (i - 1)) * 128 + c4);
          xw[r][i] = v;
        }
      }
      #pragma unroll
      for (int j = 0; j < 4; j++) {
        float a0 = 0.f, a1 = 0.f, a2 = 0.f, a3 = 0.f;
        #pragma unroll
        for (int r = 0; r < 3; r++) {
          #pragma unroll
          for (int dwi = 0; dwi < 3; dwi++) {
            unsigned int v = xw[r][j + dwi];
            int t = r * 3 + dwi;
            a0 = fmaf((float)(v & 0xffu),         wk[t][0], a0);
            a1 = fmaf((float)((v >> 8) & 0xffu),  wk[t][1], a1);
            a2 = fmaf((float)((v >> 16) & 0xffu), wk[t][2], a2);
            a3 = fmaf((float)(v >> 24),           wk[t][3], a3);
          }
        }
        float k0f = qstepf(a0, cs0, s_act3), k1f = qstepf(a1, cs1, s_act3);
        float k2f = qstepf(a2, cs2, s_act3), k3f = qstepf(a3, cs3, s_act3);
        // bf16(small int float) == cvt2-of-u8 path exactly
        unsigned int wlo = (__builtin_bit_cast(unsigned int, k0f) >> 16) |
                           (__builtin_bit_cast(unsigned int, k1f) & 0xffff0000u);
        unsigned int whi = (__builtin_bit_cast(unsigned int, k2f) >> 16) |
                           (__builtin_bit_cast(unsigned int, k3f) & 0xffff0000u);
        int p_local = (ps << 5) + (pg << 2) + j;
        int pt = p_local >> 4, pl = p_local & 15;
        int slot = (pl ^ g) | (hi << 4);
        int ad = (((((pt << 2) + kc) << 6) | slot) << 4) + (half << 3);
        *(u32x2*)(lds + ad) = u32x2{wlo, whi};
      }
    }
  }
  __syncthreads();
  // ---- phase 2: pw2 MFMA (reads swizzled fragments) ----
  int l = tid & 63, wv = tid >> 6;
  int ob = wv << 5;
  bf16x8 af[2][4];
  #pragma unroll
  for (int ot = 0; ot < 2; ot++)
    #pragma unroll
    for (int kc = 0; kc < 4; kc++) {
      int o = ob + (ot << 4) + (l & 15);
      int k = (kc << 5) + ((l >> 4) << 3);
      af[ot][kc] = *(const bf16x8*)(rbf + o * 128 + k);
    }
  f32x4 acc[2][8];
  #pragma unroll
  for (int ot = 0; ot < 2; ot++)
    #pragma unroll
    for (int pt = 0; pt < 8; pt++) acc[ot][pt] = f32x4{0.f, 0.f, 0.f, 0.f};
  #pragma unroll
  for (int kc = 0; kc < 4; kc++) {
    int gg = (l >> 4) | ((kc & 1) << 2);
    bf16x8 bb[8];
    #pragma unroll
    for (int pt = 0; pt < 8; pt++)
      bb[pt] = *(const bf16x8*)(lds + ((((((pt << 2) + kc) << 6)) | (l ^ gg)) << 4));
    #pragma unroll
    for (int ot = 0; ot < 2; ot++)
      #pragma unroll
      for (int pt = 0; pt < 8; pt++)
        acc[ot][pt] = __builtin_amdgcn_mfma_f32_16x16x32_bf16(af[ot][kc], bb[pt], acc[ot][pt], 0, 0, 0);
  }
  float s_act4 = *s4p;
  __syncthreads();   // all waves done reading k3 fragments; lds reusable for k4
  // ---- phase 3: BN4+qrelu -> k4 bf16 fragments (pwcls scheme, unswizzled) ----
  {
    int hsel = (l >> 4) & 1;
    #pragma unroll
    for (int ot = 0; ot < 2; ot++) {
      int o0 = ob + (ot << 4) + ((l >> 4) << 2);
      f32x4 c0 = cst[o0], c1 = cst[o0 + 1], c2 = cst[o0 + 2], c3 = cst[o0 + 3];
      int hi = (ot << 1) + ((l >> 4) >> 1);
      int lfrag = (l & 15) | (hi << 4);
      #pragma unroll
      for (int pt = 0; pt < 8; pt++) {
        f32x4 a = acc[ot][pt];
        float k0f = qstepf(a.x, c0, s_act4), k1f = qstepf(a.y, c1, s_act4);
        float k2f = qstepf(a.z, c2, s_act4), k3f = qstepf(a.w, c3, s_act4);
        unsigned int w0 = (__builtin_bit_cast(unsigned int, k0f) >> 16) |
                          (__builtin_bit_cast(unsigned int, k1f) & 0xffff0000u);
        unsigned int w1 = (__builtin_bit_cast(unsigned int, k2f) >> 16) |
                          (__builtin_bit_cast(unsigned int, k3f) & 0xffff0000u);
        int ad = (((((pt << 2) + wv) << 6) | lfrag) << 4) + (hsel << 3);
        *(u32x2*)(lds + ad) = u32x2{w0, w1};
      }
    }
  }
  __syncthreads();
  // ---- phase 4: classifier MFMA ----
  int pt0 = wv << 1;
  bf16x8 af5[2][4];
  #pragma unroll
  for (int ot = 0; ot < 2; ot++)
    #pragma unroll
    for (int kc = 0; kc < 4; kc++) {
      int o = (ot << 4) + (l & 15);
      int k = (kc << 5) + ((l >> 4) << 3);
      af5[ot][kc] = *(const bf16x8*)(r5 + o * 128 + k);
    }
  f32x4 a5[2][2] = {{{0,0,0,0},{0,0,0,0}},{{0,0,0,0},{0,0,0,0}}};
  #pragma unroll
  for (int kc = 0; kc < 4; kc++) {
    bf16x8 b0 = *(const bf16x8*)(lds + ((((((pt0    ) << 2) + kc) << 6) + l) << 4));
    bf16x8 b1 = *(const bf16x8*)(lds + ((((((pt0 + 1) << 2) + kc) << 6) + l) << 4));
    #pragma unroll
    for (int ot = 0; ot < 2; ot++) {
      a5[ot][0] = __builtin_amdgcn_mfma_f32_16x16x32_bf16(af5[ot][kc], b0, a5[ot][0], 0, 0, 0);
      a5[ot][1] = __builtin_amdgcn_mfma_f32_16x16x32_bf16(af5[ot][kc], b1, a5[ot][1], 0, 0, 0);
    }
  }
  #pragma unroll
  for (int ptl = 0; ptl < 2; ptl++) {
    int p = p0 + ((pt0 + ptl) << 4) + (l & 15);
    int bb = p >> 15, hw = p & 32767;
    float* ob2 = out + (((size_t)bb * 19) << 15) + hw;
    #pragma unroll
    for (int ot = 0; ot < 2; ot++) {
      int obase = (ot << 4) + ((l >> 4) << 2);
      f32x4 a = a5[ot][ptl];
      #pragma unroll
      for (int i = 0; i < 4; i++) {
        int o = obase + i;
        if (o < 19) {
          float2 c5 = cst5[o];
          ob2[(size_t)o << 15] = fmaf(a[i], c5.x, c5.y);
        }
      }
    }
  }
}

// ---------------- launch ----------------
extern "C" void kernel_launch(void* const* d_in, const int* in_sizes, int n_in,
                              void* d_out, int out_size, void* d_ws, size_t ws_size,
                              hipStream_t stream) {
  (void)in_sizes; (void)n_in; (void)out_size; (void)ws_size;
  char* ws = (char*)d_ws;
  PArgs P;
  P.dw1  = (const float*)d_in[1];
  P.pw1  = (const float*)d_in[2];
  P.dw2  = (const float*)d_in[3];
  P.pw2  = (const float*)d_in[4];
  P.clsw = (const float*)d_in[5];
  P.clsb = (const float*)d_in[6];
  P.g1 = (const float*)d_in[7];  P.b1 = (const float*)d_in[8];
  P.m1 = (const float*)d_in[9];  P.v1 = (const float*)d_in[10];
  P.g2 = (const float*)d_in[11]; P.b2 = (const float*)d_in[12];
  P.m2 = (const float*)d_in[13]; P.v2 = (const float*)d_in[14];
  P.g3 = (const float*)d_in[15]; P.b3 = (const float*)d_in[16];
  P.m3 = (const float*)d_in[17]; P.v3 = (const float*)d_in[18];
  P.g4 = (const float*)d_in[19]; P.b4 = (const float*)d_in[20];
  P.m4 = (const float*)d_in[21]; P.v4 = (const float*)d_in[22];
  P.s1 = (const float*)d_in[23]; P.s2 = (const float*)d_in[24];
  P.s3 = (const float*)d_in[25]; P.s4 = (const float*)d_in[26];

  const float* x = (const float*)d_in[0];
  unsigned char* bufA = (unsigned char*)(ws + OFF_BUFA);
  unsigned char* bufB = (unsigned char*)(ws + OFF_BUFB);

  prep_kernel<<<544, 64, 0, stream>>>(P, ws);
  dwA_kernel<<<1024, 512, 0, stream>>>(x, ws, P.s1);                       // x -> k1 NCHW u8 (B)
  pwn_kernel<<<2048, 256, 0, stream>>>(bufB, bufA,
      (const unsigned short*)(ws + OFF_R2BF), (const f32x4*)(ws + OFF_CST2), P.s2);  // k1 NCHW -> k2 NHWC (A)
  dw2pwcls_kernel<<<2048, 256, 0, stream>>>(bufA, (float*)d_out, ws,
      (const unsigned short*)(ws + OFF_R4BF), (const f32x4*)(ws + OFF_CST4),
      P.s3, P.s4,
      (const unsigned short*)(ws + OFF_R5BF), (const float2*)(ws + OFF_CST5));       // k2 -> out
}

// Round 12
// 127.959 us; speedup vs baseline: 1.9294x; 1.0635x over previous
//
#include <hip/hip_runtime.h>

typedef __attribute__((ext_vector_type(4))) float f32x4;
typedef __attribute__((ext_vector_type(8))) short bf16x8;
typedef __attribute__((ext_vector_type(2))) unsigned int u32x2;
typedef __attribute__((ext_vector_type(4))) unsigned int u32x4;

#define EPSV 1e-5f

// workspace layout (bytes)
#define OFF_BUFA 0u
#define OFF_BUFB 33554432u
#define OFF_T    67108864u
#define OFF_WQ1  (OFF_T + 0u)       // f32 [128][12]  (9 taps used)
#define OFF_R3F  (OFF_T + 6144u)    // f32 [9][128]   integer-valued
#define OFF_CST3 (OFF_T + 10752u)   // f32x4 [128]
#define OFF_CST1 (OFF_T + 12800u)   // f32x4 [128]
#define OFF_R2BF (OFF_T + 14848u)   // bf16 [128][128]
#define OFF_CST2 (OFF_T + 47616u)   // f32x4 [128]
#define OFF_R4BF (OFF_T + 49664u)   // bf16 [128][128]
#define OFF_CST4 (OFF_T + 82432u)   // f32x4 [128]
#define OFF_R5BF (OFF_T + 84480u)   // bf16 [32][128] (rows 19..31 zero)
#define OFF_CST5 (OFF_T + 92672u)   // float2 [32]

struct PArgs {
  const float *dw1, *pw1, *dw2, *pw2, *clsw, *clsb;
  const float *g1, *b1, *m1, *v1;
  const float *g2, *b2, *m2, *v2;
  const float *g3, *b3, *m3, *v3;
  const float *g4, *b4, *m4, *v4;
  const float *s1, *s2, *s3, *s4;
};

__device__ __forceinline__ unsigned short f2bf(float f) {
  return (unsigned short)(__builtin_bit_cast(unsigned int, f) >> 16);
}
__device__ __forceinline__ float clip7(float r) { return fminf(fmaxf(r, -7.f), 7.f); }

// BN-transformed value; expression identical to all previous rounds.
__device__ __forceinline__ float bnval(float a, f32x4 c) {
  return (a * c.x - c.z) * c.y + c.w;
}

// Quantize 4 values: fast path u = t*(1/s) + rint; if any lane lands within
// 3e-5 of a half-integer (fast-path abs error <= ~4e-6 for |u|<=16), the wave
// recomputes with exact division -> emitted k bit-identical to exact path.
__device__ __forceinline__ void qstep4(float t0, float t1, float t2, float t3,
                                       float s, float rs,
                                       float &k0, float &k1, float &k2, float &k3) {
  float u0 = t0 * rs, u1 = t1 * rs, u2 = t2 * rs, u3 = t3 * rs;
  float f0 = rintf(u0), f1 = rintf(u1), f2 = rintf(u2), f3 = rintf(u3);
  float d0 = fabsf(fabsf(u0 - f0) - 0.5f);
  float d1 = fabsf(fabsf(u1 - f1) - 0.5f);
  float d2 = fabsf(fabsf(u2 - f2) - 0.5f);
  float d3 = fabsf(fabsf(u3 - f3) - 0.5f);
  bool near = (d0 < 3e-5f) | (d1 < 3e-5f) | (d2 < 3e-5f) | (d3 < 3e-5f);
  if (__any(near)) {
    f0 = rintf(t0 / s); f1 = rintf(t1 / s);
    f2 = rintf(t2 / s); f3 = rintf(t3 / s);
  }
  k0 = fminf(fmaxf(f0, 0.f), 15.f);
  k1 = fminf(fmaxf(f1, 0.f), 15.f);
  k2 = fminf(fmaxf(f2, 0.f), 15.f);
  k3 = fminf(fmaxf(f3, 0.f), 15.f);
}

// 4 u8 -> 2 dwords of packed bf16
__device__ __forceinline__ void cvt2(unsigned int d, unsigned int &lo, unsigned int &hi) {
  float f0 = (float)(d & 0xffu);
  float f1 = (float)((d >> 8) & 0xffu);
  float f2 = (float)((d >> 16) & 0xffu);
  float f3 = (float)(d >> 24);
  lo = (__builtin_bit_cast(unsigned int, f0) >> 16) | (__builtin_bit_cast(unsigned int, f1) & 0xffff0000u);
  hi = (__builtin_bit_cast(unsigned int, f2) >> 16) | (__builtin_bit_cast(unsigned int, f3) & 0xffff0000u);
}

__device__ __forceinline__ float wmax16(float v) {
  #pragma unroll
  for (int s = 1; s < 16; s <<= 1) v = fmaxf(v, __shfl_xor(v, s));
  return v;
}
__device__ __forceinline__ float wmax64(float v) {
  #pragma unroll
  for (int s = 1; s < 64; s <<= 1) v = fmaxf(v, __shfl_xor(v, s));
  return v;
}

// ---------------- prep: quantize weights, fold BN constants ----------------
__global__ __launch_bounds__(64) void prep_kernel(PArgs P, char* __restrict__ ws) {
  int bi = blockIdx.x, l = threadIdx.x;
  float* wq1 = (float*)(ws + OFF_WQ1);
  float* r3f = (float*)(ws + OFF_R3F);
  f32x4* cst1 = (f32x4*)(ws + OFF_CST1);
  f32x4* cst2 = (f32x4*)(ws + OFF_CST2);
  f32x4* cst3 = (f32x4*)(ws + OFF_CST3);
  f32x4* cst4 = (f32x4*)(ws + OFF_CST4);
  unsigned short* r2 = (unsigned short*)(ws + OFF_R2BF);
  unsigned short* r4 = (unsigned short*)(ws + OFF_R4BF);
  unsigned short* r5 = (unsigned short*)(ws + OFF_R5BF);
  float2* cst5 = (float2*)(ws + OFF_CST5);

  if (bi < 128) {
    int c = bi;
    float w = (l < 9) ? P.dw1[c * 9 + l] : 0.f;
    float mx = wmax16(fabsf(w));
    float sq = fmaxf(mx / 7.0f, 1e-8f);
    if (l < 9) wq1[c * 12 + l] = clip7(rintf(w / sq)) * sq;
    if (l == 0) {
      float sc = P.g1[c] / sqrtf(P.v1[c] + EPSV);
      cst1[c] = f32x4{1.f, sc, P.m1[c], P.b1[c]};
    }
  } else if (bi < 256) {
    int o = bi - 128;
    float w0 = P.pw1[o * 128 + l], w1 = P.pw1[o * 128 + 64 + l];
    float mx = wmax64(fmaxf(fabsf(w0), fabsf(w1)));
    float sq = fmaxf(mx / 7.0f, 1e-8f);
    r2[o * 128 + l]      = f2bf(clip7(rintf(w0 / sq)));
    r2[o * 128 + 64 + l] = f2bf(clip7(rintf(w1 / sq)));
    if (l == 0) {
      float sc = P.g2[o] / sqrtf(P.v2[o] + EPSV);
      cst2[o] = f32x4{P.s1[0] * sq, sc, P.m2[o], P.b2[o]};
    }
  } else if (bi < 384) {
    int c = bi - 256;
    float w = (l < 9) ? P.dw2[c * 9 + l] : 0.f;
    float mx = wmax16(fabsf(w));
    float sq = fmaxf(mx / 7.0f, 1e-8f);
    if (l < 9) r3f[l * 128 + c] = clip7(rintf(w / sq));
    if (l == 0) {
      float sc = P.g3[c] / sqrtf(P.v3[c] + EPSV);
      cst3[c] = f32x4{P.s2[0] * sq, sc, P.m3[c], P.b3[c]};
    }
  } else if (bi < 512) {
    int o = bi - 384;
    float w0 = P.pw2[o * 128 + l], w1 = P.pw2[o * 128 + 64 + l];
    float mx = wmax64(fmaxf(fabsf(w0), fabsf(w1)));
    float sq = fmaxf(mx / 7.0f, 1e-8f);
    r4[o * 128 + l]      = f2bf(clip7(rintf(w0 / sq)));
    r4[o * 128 + 64 + l] = f2bf(clip7(rintf(w1 / sq)));
    if (l == 0) {
      float sc = P.g4[o] / sqrtf(P.v4[o] + EPSV);
      cst4[o] = f32x4{P.s3[0] * sq, sc, P.m4[o], P.b4[o]};
    }
  } else {
    int o = bi - 512;
    if (o < 19) {
      float w0 = P.clsw[o * 128 + l], w1 = P.clsw[o * 128 + 64 + l];
      float mx = wmax64(fmaxf(fabsf(w0), fabsf(w1)));
      float sq = fmaxf(mx / 7.0f, 1e-8f);
      r5[o * 128 + l]      = f2bf(clip7(rintf(w0 / sq)));
      r5[o * 128 + 64 + l] = f2bf(clip7(rintf(w1 / sq)));
      if (l == 0) {
        float A5 = P.s4[0] * sq;
        float bq = rintf(P.clsb[o] / A5) * A5;
        cst5[o] = make_float2(A5, bq);
      }
    } else {
      r5[o * 128 + l] = 0; r5[o * 128 + 64 + l] = 0;
      if (l == 0) cst5[o] = make_float2(0.f, 0.f);
    }
  }
}

// ---------------- dw-conv1 phase A: per-plane streaming, rolling 3-row window ----------------
__global__ __launch_bounds__(512) void dwA_kernel(const float* __restrict__ x,
                                                  char* __restrict__ ws,
                                                  const float* __restrict__ s1p) {
  int bid = blockIdx.x;
  int b = bid & 7, c = bid >> 3;              // XCD x owns image b=x
  int tid = threadIdx.x;
  int wq = tid & 63, wv = tid >> 6;
  int w0 = wq << 2;
  int h0 = wv << 4;
  const float* wp = (const float*)(ws + OFF_WQ1) + c * 12;
  float k0 = wp[0], k1 = wp[1], k2 = wp[2], k3 = wp[3], k4 = wp[4],
        k5 = wp[5], k6 = wp[6], k7 = wp[7], k8 = wp[8];
  f32x4 cs = ((const f32x4*)(ws + OFF_CST1))[c];
  float s_act = *s1p;
  float rs = 1.0f / s_act;
  const float* plane = x + (((size_t)((b << 7) | c)) << 15);
  unsigned char* oplane = (unsigned char*)(ws + OFF_BUFB) + (((size_t)((b << 7) | c)) << 15);

  f32x4 vm = {0.f, 0.f, 0.f, 0.f};
  if (h0 > 0) vm = *(const f32x4*)(plane + ((h0 - 1) << 8) + w0);
  f32x4 v0 = *(const f32x4*)(plane + (h0 << 8) + w0);
  f32x4 vp = *(const f32x4*)(plane + ((h0 + 1) << 8) + w0);
  float lm = __shfl_up(vm.w, 1), l0 = __shfl_up(v0.w, 1), lp = __shfl_up(vp.w, 1);
  float rm = __shfl_down(vm.x, 1), r0 = __shfl_down(v0.x, 1), rp = __shfl_down(vp.x, 1);
  if (wq == 0)  { lm = 0.f; l0 = 0.f; lp = 0.f; }
  if (wq == 63) { rm = 0.f; r0 = 0.f; rp = 0.f; }

  #pragma unroll 4
  for (int i = 0; i < 16; i++) {
    int h = h0 + i;
    float y0 = 0.f, y1 = 0.f, y2 = 0.f, y3 = 0.f;
    // row -1 (k0,k1,k2) then row 0 (k3,k4,k5) then row +1 (k6,k7,k8) — r1 order
    y0 = fmaf(lm,   k0, y0); y0 = fmaf(vm.x, k1, y0); y0 = fmaf(vm.y, k2, y0);
    y1 = fmaf(vm.x, k0, y1); y1 = fmaf(vm.y, k1, y1); y1 = fmaf(vm.z, k2, y1);
    y2 = fmaf(vm.y, k0, y2); y2 = fmaf(vm.z, k1, y2); y2 = fmaf(vm.w, k2, y2);
    y3 = fmaf(vm.z, k0, y3); y3 = fmaf(vm.w, k1, y3); y3 = fmaf(rm,   k2, y3);

    y0 = fmaf(l0,   k3, y0); y0 = fmaf(v0.x, k4, y0); y0 = fmaf(v0.y, k5, y0);
    y1 = fmaf(v0.x, k3, y1); y1 = fmaf(v0.y, k4, y1); y1 = fmaf(v0.z, k5, y1);
    y2 = fmaf(v0.y, k3, y2); y2 = fmaf(v0.z, k4, y2); y2 = fmaf(v0.w, k5, y2);
    y3 = fmaf(v0.z, k3, y3); y3 = fmaf(v0.w, k4, y3); y3 = fmaf(r0,   k5, y3);

    y0 = fmaf(lp,   k6, y0); y0 = fmaf(vp.x, k7, y0); y0 = fmaf(vp.y, k8, y0);
    y1 = fmaf(vp.x, k6, y1); y1 = fmaf(vp.y, k7, y1); y1 = fmaf(vp.z, k8, y1);
    y2 = fmaf(vp.y, k6, y2); y2 = fmaf(vp.z, k7, y2); y2 = fmaf(vp.w, k8, y2);
    y3 = fmaf(vp.z, k6, y3); y3 = fmaf(vp.w, k7, y3); y3 = fmaf(rp,   k8, y3);

    float q0, q1, q2, q3;
    qstep4(bnval(y0, cs), bnval(y1, cs), bnval(y2, cs), bnval(y3, cs),
           s_act, rs, q0, q1, q2, q3);
    unsigned int pk = (unsigned int)q0 | ((unsigned int)q1 << 8) |
                      ((unsigned int)q2 << 16) | ((unsigned int)q3 << 24);
    *(unsigned int*)(oplane + (h << 8) + w0) = pk;

    // shift window; load row h+2 for next iteration
    vm = v0; lm = l0; rm = r0;
    v0 = vp; l0 = lp; r0 = rp;
    f32x4 nv = {0.f, 0.f, 0.f, 0.f};
    if (i < 15 && h + 2 < 128) nv = *(const f32x4*)(plane + ((h + 2) << 8) + w0);
    vp = nv;
    float nl = __shfl_up(nv.w, 1), nr = __shfl_down(nv.x, 1);
    if (wq == 0)  nl = 0.f;
    if (wq == 63) nr = 0.f;
    lp = nl; rp = nr;
  }
}

// ---------------- pw1 from NCHW: staging does the transpose in-register ----------------
__global__ __launch_bounds__(256) void pwn_kernel(const unsigned char* __restrict__ in,
                                                  unsigned char* __restrict__ out,
                                                  const unsigned short* __restrict__ rbf,
                                                  const f32x4* __restrict__ cst,
                                                  const float* __restrict__ sp) {
  __shared__ unsigned char lds[32768];
  int tid = threadIdx.x;
  int p0 = blockIdx.x << 7;
  int b_img = p0 >> 15, loc0 = p0 & 32767;
  {
    int pb = tid & 7, cq = tid >> 3;
    int c4 = cq << 2;
    int kc = cq >> 3, lgr = (cq >> 1) & 3, half = cq & 1;
    const unsigned char* ib = in + (((size_t)(b_img << 7)) << 15) + loc0 + (pb << 4);
    u32x4 t0 = *(const u32x4*)(ib + ((size_t)(c4 + 0) << 15));
    u32x4 t1 = *(const u32x4*)(ib + ((size_t)(c4 + 1) << 15));
    u32x4 t2 = *(const u32x4*)(ib + ((size_t)(c4 + 2) << 15));
    u32x4 t3 = *(const u32x4*)(ib + ((size_t)(c4 + 3) << 15));
    int swz = (pb & 7) << 4;
    #pragma unroll
    for (int s = 0; s < 16; s++) {
      int wrd = s >> 2, sh8 = (s & 3) << 3;
      unsigned int chw = ((t0[wrd] >> sh8) & 0xffu)
                       | (((t1[wrd] >> sh8) & 0xffu) << 8)
                       | (((t2[wrd] >> sh8) & 0xffu) << 16)
                       | (((t3[wrd] >> sh8) & 0xffu) << 24);
      unsigned int lo, hi;
      cvt2(chw, lo, hi);
      int ad = ((((((pb << 2) + kc) << 6) | s | (lgr << 4)) << 4) + (half << 3)) ^ swz;
      *(u32x2*)(lds + ad) = u32x2{lo, hi};
    }
  }
  __syncthreads();
  int l = tid & 63, wv = tid >> 6;
  int ob = wv << 5;                          // wave owns 32 output channels
  bf16x8 af[2][4];
  #pragma unroll
  for (int ot = 0; ot < 2; ot++)
    #pragma unroll
    for (int kc = 0; kc < 4; kc++) {
      int o = ob + (ot << 4) + (l & 15);
      int k = (kc << 5) + ((l >> 4) << 3);
      af[ot][kc] = *(const bf16x8*)(rbf + o * 128 + k);
    }
  f32x4 acc[2][8];
  #pragma unroll
  for (int ot = 0; ot < 2; ot++)
    #pragma unroll
    for (int pt = 0; pt < 8; pt++) acc[ot][pt] = f32x4{0.f, 0.f, 0.f, 0.f};
  #pragma unroll
  for (int kc = 0; kc < 4; kc++) {
    bf16x8 bb[8];
    #pragma unroll
    for (int pt = 0; pt < 8; pt++)
      bb[pt] = *(const bf16x8*)(lds + (((((((pt << 2) + kc) << 6)) + l) << 4) ^ ((pt & 7) << 4)));
    #pragma unroll
    for (int ot = 0; ot < 2; ot++)
      #pragma unroll
      for (int pt = 0; pt < 8; pt++)
        acc[ot][pt] = __builtin_amdgcn_mfma_f32_16x16x32_bf16(af[ot][kc], bb[pt], acc[ot][pt], 0, 0, 0);
  }
  float s_act = *sp;
  float rs = 1.0f / s_act;
  #pragma unroll
  for (int ot = 0; ot < 2; ot++) {
    int o0 = ob + (ot << 4) + ((l >> 4) << 2);
    f32x4 c0 = cst[o0], c1 = cst[o0 + 1], c2 = cst[o0 + 2], c3 = cst[o0 + 3];
    #pragma unroll
    for (int pt = 0; pt < 8; pt++) {
      int p = p0 + (pt << 4) + (l & 15);
      f32x4 a = acc[ot][pt];
      float q0, q1, q2, q3;
      qstep4(bnval(a.x, c0), bnval(a.y, c1), bnval(a.z, c2), bnval(a.w, c3),
             s_act, rs, q0, q1, q2, q3);
      unsigned int pk = (unsigned int)q0 | ((unsigned int)q1 << 8) |
                        ((unsigned int)q2 << 16) | ((unsigned int)q3 << 24);
      *(unsigned int*)(out + (size_t)p * 128 + o0) = pk;
    }
  }
}

// ---------------- fused dw2 + BN3 + qrelu + pw2 + BN4 + qrelu + classifier ----------------
__global__ __launch_bounds__(256) void dw2pwcls_kernel(const unsigned char* __restrict__ in,
                                                       float* __restrict__ out,
                                                       const char* __restrict__ ws,
                                                       const unsigned short* __restrict__ rbf,
                                                       const f32x4* __restrict__ cst,
                                                       const float* __restrict__ s3p,
                                                       const float* __restrict__ s4p,
                                                       const unsigned short* __restrict__ r5,
                                                       const float2* __restrict__ cst5) {
  __shared__ unsigned char lds[32768];
  int tid = threadIdx.x;
  int p0 = blockIdx.x << 7;          // 128 consecutive positions, single h row
  // ---- phase 1: dw2 sliding window -> bf16 fragments (swizzled) ----
  {
    int cq = tid & 31, pg = tid >> 5;
    int c4 = cq << 2;
    const float* r3f = (const float*)(ws + OFF_R3F);
    float wk[9][4];
    #pragma unroll
    for (int t = 0; t < 9; t++) {
      wk[t][0] = r3f[t * 128 + c4];     wk[t][1] = r3f[t * 128 + c4 + 1];
      wk[t][2] = r3f[t * 128 + c4 + 2]; wk[t][3] = r3f[t * 128 + c4 + 3];
    }
    const f32x4* cst3 = (const f32x4*)(ws + OFF_CST3);
    f32x4 cs0 = cst3[c4], cs1 = cst3[c4 + 1], cs2 = cst3[c4 + 2], cs3 = cst3[c4 + 3];
    float s_act3 = *s3p;
    float rs3 = 1.0f / s_act3;
    int kc = c4 >> 5, hi = (c4 >> 3) & 3, half = (c4 >> 2) & 1;
    int g = hi | ((kc & 1) << 2);
    int hh = (p0 >> 8) & 127;          // block-uniform row index
    #pragma unroll 2
    for (int ps = 0; ps < 4; ps++) {
      int pbase = p0 + (ps << 5) + (pg << 2);   // 4 consecutive positions
      int wbase = pbase & 255;
      unsigned int xw[3][6];
      #pragma unroll
      for (int r = 0; r < 3; r++) {
        int gh = hh + r - 1;
        if (gh >= 0 && gh <= 127) {    // uniform branch
          const unsigned char* rp = in + (size_t)(pbase + (r - 1) * 256) * 128 + c4;
          xw[r][0] = (wbase > 0)   ? *(const unsigned int*)(rp - 128) : 0u;
          xw[r][1] = *(const unsigned int*)(rp);
          xw[r][2] = *(const unsigned int*)(rp + 128);
          xw[r][3] = *(const unsigned int*)(rp + 256);
          xw[r][4] = *(const unsigned int*)(rp + 384);
          xw[r][5] = (wbase < 252) ? *(const unsigned int*)(rp + 512) : 0u;
        } else {
          xw[r][0] = 0u; xw[r][1] = 0u; xw[r][2] = 0u;
          xw[r][3] = 0u; xw[r][4] = 0u; xw[r][5] = 0u;
        }
      }
      #pragma unroll
      for (int j = 0; j < 4; j++) {
        float a0 = 0.f, a1 = 0.f, a2 = 0.f, a3 = 0.f;
        #pragma unroll
        for (int r = 0; r < 3; r++) {
          #pragma unroll
          for (int dwi = 0; dwi < 3; dwi++) {
            unsigned int v = xw[r][j + dwi];
            int t = r * 3 + dwi;
            a0 = fmaf((float)(v & 0xffu),         wk[t][0], a0);
            a1 = fmaf((float)((v >> 8) & 0xffu),  wk[t][1], a1);
            a2 = fmaf((float)((v >> 16) & 0xffu), wk[t][2], a2);
            a3 = fmaf((float)(v >> 24),           wk[t][3], a3);
          }
        }
        float k0f, k1f, k2f, k3f;
        qstep4(bnval(a0, cs0), bnval(a1, cs1), bnval(a2, cs2), bnval(a3, cs3),
               s_act3, rs3, k0f, k1f, k2f, k3f);
        // bf16(small int float) == cvt2-of-u8 path exactly
        unsigned int wlo = (__builtin_bit_cast(unsigned int, k0f) >> 16) |
                           (__builtin_bit_cast(unsigned int, k1f) & 0xffff0000u);
        unsigned int whi = (__builtin_bit_cast(unsigned int, k2f) >> 16) |
                           (__builtin_bit_cast(unsigned int, k3f) & 0xffff0000u);
        int p_local = (ps << 5) + (pg << 2) + j;
        int pt = p_local >> 4, pl = p_local & 15;
        int slot = (pl ^ g) | (hi << 4);
        int ad = (((((pt << 2) + kc) << 6) | slot) << 4) + (half << 3);
        *(u32x2*)(lds + ad) = u32x2{wlo, whi};
      }
    }
  }
  __syncthreads();
  // ---- phase 2: pw2 MFMA (reads swizzled fragments) ----
  int l = tid & 63, wv = tid >> 6;
  int ob = wv << 5;
  bf16x8 af[2][4];
  #pragma unroll
  for (int ot = 0; ot < 2; ot++)
    #pragma unroll
    for (int kc = 0; kc < 4; kc++) {
      int o = ob + (ot << 4) + (l & 15);
      int k = (kc << 5) + ((l >> 4) << 3);
      af[ot][kc] = *(const bf16x8*)(rbf + o * 128 + k);
    }
  f32x4 acc[2][8];
  #pragma unroll
  for (int ot = 0; ot < 2; ot++)
    #pragma unroll
    for (int pt = 0; pt < 8; pt++) acc[ot][pt] = f32x4{0.f, 0.f, 0.f, 0.f};
  #pragma unroll
  for (int kc = 0; kc < 4; kc++) {
    int gg = (l >> 4) | ((kc & 1) << 2);
    bf16x8 bb[8];
    #pragma unroll
    for (int pt = 0; pt < 8; pt++)
      bb[pt] = *(const bf16x8*)(lds + ((((((pt << 2) + kc) << 6)) | (l ^ gg)) << 4));
    #pragma unroll
    for (int ot = 0; ot < 2; ot++)
      #pragma unroll
      for (int pt = 0; pt < 8; pt++)
        acc[ot][pt] = __builtin_amdgcn_mfma_f32_16x16x32_bf16(af[ot][kc], bb[pt], acc[ot][pt], 0, 0, 0);
  }
  float s_act4 = *s4p;
  float rs4 = 1.0f / s_act4;
  __syncthreads();   // all waves done reading k3 fragments; lds reusable for k4
  // ---- phase 3: BN4+qrelu -> k4 bf16 fragments (pwcls scheme, unswizzled) ----
  {
    int hsel = (l >> 4) & 1;
    #pragma unroll
    for (int ot = 0; ot < 2; ot++) {
      int o0 = ob + (ot << 4) + ((l >> 4) << 2);
      f32x4 c0 = cst[o0], c1 = cst[o0 + 1], c2 = cst[o0 + 2], c3 = cst[o0 + 3];
      int hi = (ot << 1) + ((l >> 4) >> 1);
      int lfrag = (l & 15) | (hi << 4);
      #pragma unroll
      for (int pt = 0; pt < 8; pt++) {
        f32x4 a = acc[ot][pt];
        float k0f, k1f, k2f, k3f;
        qstep4(bnval(a.x, c0), bnval(a.y, c1), bnval(a.z, c2), bnval(a.w, c3),
               s_act4, rs4, k0f, k1f, k2f, k3f);
        unsigned int w0 = (__builtin_bit_cast(unsigned int, k0f) >> 16) |
                          (__builtin_bit_cast(unsigned int, k1f) & 0xffff0000u);
        unsigned int w1 = (__builtin_bit_cast(unsigned int, k2f) >> 16) |
                          (__builtin_bit_cast(unsigned int, k3f) & 0xffff0000u);
        int ad = (((((pt << 2) + wv) << 6) | lfrag) << 4) + (hsel << 3);
        *(u32x2*)(lds + ad) = u32x2{w0, w1};
      }
    }
  }
  __syncthreads();
  // ---- phase 4: classifier MFMA ----
  int pt0 = wv << 1;
  bf16x8 af5[2][4];
  #pragma unroll
  for (int ot = 0; ot < 2; ot++)
    #pragma unroll
    for (int kc = 0; kc < 4; kc++) {
      int o = (ot << 4) + (l & 15);
      int k = (kc << 5) + ((l >> 4) << 3);
      af5[ot][kc] = *(const bf16x8*)(r5 + o * 128 + k);
    }
  f32x4 a5[2][2] = {{{0,0,0,0},{0,0,0,0}},{{0,0,0,0},{0,0,0,0}}};
  #pragma unroll
  for (int kc = 0; kc < 4; kc++) {
    bf16x8 b0 = *(const bf16x8*)(lds + ((((((pt0    ) << 2) + kc) << 6) + l) << 4));
    bf16x8 b1 = *(const bf16x8*)(lds + ((((((pt0 + 1) << 2) + kc) << 6) + l) << 4));
    #pragma unroll
    for (int ot = 0; ot < 2; ot++) {
      a5[ot][0] = __builtin_amdgcn_mfma_f32_16x16x32_bf16(af5[ot][kc], b0, a5[ot][0], 0, 0, 0);
      a5[ot][1] = __builtin_amdgcn_mfma_f32_16x16x32_bf16(af5[ot][kc], b1, a5[ot][1], 0, 0, 0);
    }
  }
  #pragma unroll
  for (int ptl = 0; ptl < 2; ptl++) {
    int p = p0 + ((pt0 + ptl) << 4) + (l & 15);
    int bb = p >> 15, hw = p & 32767;
    float* ob2 = out + (((size_t)bb * 19) << 15) + hw;
    #pragma unroll
    for (int ot = 0; ot < 2; ot++) {
      int obase = (ot << 4) + ((l >> 4) << 2);
      f32x4 a = a5[ot][ptl];
      #pragma unroll
      for (int i = 0; i < 4; i++) {
        int o = obase + i;
        if (o < 19) {
          float2 c5 = cst5[o];
          ob2[(size_t)o << 15] = fmaf(a[i], c5.x, c5.y);
        }
      }
    }
  }
}

// ---------------- launch ----------------
extern "C" void kernel_launch(void* const* d_in, const int* in_sizes, int n_in,
                              void* d_out, int out_size, void* d_ws, size_t ws_size,
                              hipStream_t stream) {
  (void)in_sizes; (void)n_in; (void)out_size; (void)ws_size;
  char* ws = (char*)d_ws;
  PArgs P;
  P.dw1  = (const float*)d_in[1];
  P.pw1  = (const float*)d_in[2];
  P.dw2  = (const float*)d_in[3];
  P.pw2  = (const float*)d_in[4];
  P.clsw = (const float*)d_in[5];
  P.clsb = (const float*)d_in[6];
  P.g1 = (const float*)d_in[7];  P.b1 = (const float*)d_in[8];
  P.m1 = (const float*)d_in[9];  P.v1 = (const float*)d_in[10];
  P.g2 = (const float*)d_in[11]; P.b2 = (const float*)d_in[12];
  P.m2 = (const float*)d_in[13]; P.v2 = (const float*)d_in[14];
  P.g3 = (const float*)d_in[15]; P.b3 = (const float*)d_in[16];
  P.m3 = (const float*)d_in[17]; P.v3 = (const float*)d_in[18];
  P.g4 = (const float*)d_in[19]; P.b4 = (const float*)d_in[20];
  P.m4 = (const float*)d_in[21]; P.v4 = (const float*)d_in[22];
  P.s1 = (const float*)d_in[23]; P.s2 = (const float*)d_in[24];
  P.s3 = (const float*)d_in[25]; P.s4 = (const float*)d_in[26];

  const float* x = (const float*)d_in[0];
  unsigned char* bufA = (unsigned char*)(ws + OFF_BUFA);
  unsigned char* bufB = (unsigned char*)(ws + OFF_BUFB);

  prep_kernel<<<544, 64, 0, stream>>>(P, ws);
  dwA_kernel<<<1024, 512, 0, stream>>>(x, ws, P.s1);                       // x -> k1 NCHW u8 (B)
  pwn_kernel<<<2048, 256, 0, stream>>>(bufB, bufA,
      (const unsigned short*)(ws + OFF_R2BF), (const f32x4*)(ws + OFF_CST2), P.s2);  // k1 NCHW -> k2 NHWC (A)
  dw2pwcls_kernel<<<2048, 256, 0, stream>>>(bufA, (float*)d_out, ws,
      (const unsigned short*)(ws + OFF_R4BF), (const f32x4*)(ws + OFF_CST4),
      P.s3, P.s4,
      (const unsigned short*)(ws + OFF_R5BF), (const float2*)(ws + OFF_CST5));       // k2 -> out
}

// Round 13
// 127.026 us; speedup vs baseline: 1.9435x; 1.0073x over previous
//
#include <hip/hip_runtime.h>

typedef __attribute__((ext_vector_type(4))) float f32x4;
typedef __attribute__((ext_vector_type(8))) short bf16x8;
typedef __attribute__((ext_vector_type(2))) unsigned int u32x2;
typedef __attribute__((ext_vector_type(4))) unsigned int u32x4;

#define EPSV 1e-5f

// workspace layout (bytes)
#define OFF_BUFA 0u
#define OFF_BUFB 33554432u
#define OFF_T    67108864u
#define OFF_WQ1  (OFF_T + 0u)       // f32 [128][12]  (9 taps used)
#define OFF_R3F  (OFF_T + 6144u)    // f32 [9][128]   integer-valued
#define OFF_CST3 (OFF_T + 10752u)   // f32x4 [128]
#define OFF_CST1 (OFF_T + 12800u)   // f32x4 [128]
#define OFF_R2BF (OFF_T + 14848u)   // bf16 [128][128]
#define OFF_CST2 (OFF_T + 47616u)   // f32x4 [128]
#define OFF_R4BF (OFF_T + 49664u)   // bf16 [128][128]
#define OFF_CST4 (OFF_T + 82432u)   // f32x4 [128]
#define OFF_R5BF (OFF_T + 84480u)   // bf16 [32][128] (rows 19..31 zero)
#define OFF_CST5 (OFF_T + 92672u)   // float2 [32]

struct PArgs {
  const float *dw1, *pw1, *dw2, *pw2, *clsw, *clsb;
  const float *g1, *b1, *m1, *v1;
  const float *g2, *b2, *m2, *v2;
  const float *g3, *b3, *m3, *v3;
  const float *g4, *b4, *m4, *v4;
  const float *s1, *s2, *s3, *s4;
};

__device__ __forceinline__ unsigned short f2bf(float f) {
  return (unsigned short)(__builtin_bit_cast(unsigned int, f) >> 16);
}
__device__ __forceinline__ float clip7(float r) { return fminf(fmaxf(r, -7.f), 7.f); }

// BN-transformed value; expression identical to all previous rounds.
__device__ __forceinline__ float bnval(float a, f32x4 c) {
  return (a * c.x - c.z) * c.y + c.w;
}

// Quantize 4 values: fast path u = t*(1/s) + rint; if any lane lands within
// 3e-5 of a half-integer (fast-path abs error <= ~4e-6 for |u|<=16), the wave
// recomputes with exact division -> emitted k bit-identical to exact path.
__device__ __forceinline__ void qstep4(float t0, float t1, float t2, float t3,
                                       float s, float rs,
                                       float &k0, float &k1, float &k2, float &k3) {
  float u0 = t0 * rs, u1 = t1 * rs, u2 = t2 * rs, u3 = t3 * rs;
  float f0 = rintf(u0), f1 = rintf(u1), f2 = rintf(u2), f3 = rintf(u3);
  float d0 = fabsf(fabsf(u0 - f0) - 0.5f);
  float d1 = fabsf(fabsf(u1 - f1) - 0.5f);
  float d2 = fabsf(fabsf(u2 - f2) - 0.5f);
  float d3 = fabsf(fabsf(u3 - f3) - 0.5f);
  bool near = (d0 < 3e-5f) | (d1 < 3e-5f) | (d2 < 3e-5f) | (d3 < 3e-5f);
  if (__any(near)) {
    f0 = rintf(t0 / s); f1 = rintf(t1 / s);
    f2 = rintf(t2 / s); f3 = rintf(t3 / s);
  }
  k0 = fminf(fmaxf(f0, 0.f), 15.f);
  k1 = fminf(fmaxf(f1, 0.f), 15.f);
  k2 = fminf(fmaxf(f2, 0.f), 15.f);
  k3 = fminf(fmaxf(f3, 0.f), 15.f);
}

// 4 u8 -> 2 dwords of packed bf16
__device__ __forceinline__ void cvt2(unsigned int d, unsigned int &lo, unsigned int &hi) {
  float f0 = (float)(d & 0xffu);
  float f1 = (float)((d >> 8) & 0xffu);
  float f2 = (float)((d >> 16) & 0xffu);
  float f3 = (float)(d >> 24);
  lo = (__builtin_bit_cast(unsigned int, f0) >> 16) | (__builtin_bit_cast(unsigned int, f1) & 0xffff0000u);
  hi = (__builtin_bit_cast(unsigned int, f2) >> 16) | (__builtin_bit_cast(unsigned int, f3) & 0xffff0000u);
}

__device__ __forceinline__ float wmax16(float v) {
  #pragma unroll
  for (int s = 1; s < 16; s <<= 1) v = fmaxf(v, __shfl_xor(v, s));
  return v;
}
__device__ __forceinline__ float wmax64(float v) {
  #pragma unroll
  for (int s = 1; s < 64; s <<= 1) v = fmaxf(v, __shfl_xor(v, s));
  return v;
}

// ---------------- prep: quantize weights, fold BN constants ----------------
__global__ __launch_bounds__(64) void prep_kernel(PArgs P, char* __restrict__ ws) {
  int bi = blockIdx.x, l = threadIdx.x;
  float* wq1 = (float*)(ws + OFF_WQ1);
  float* r3f = (float*)(ws + OFF_R3F);
  f32x4* cst1 = (f32x4*)(ws + OFF_CST1);
  f32x4* cst2 = (f32x4*)(ws + OFF_CST2);
  f32x4* cst3 = (f32x4*)(ws + OFF_CST3);
  f32x4* cst4 = (f32x4*)(ws + OFF_CST4);
  unsigned short* r2 = (unsigned short*)(ws + OFF_R2BF);
  unsigned short* r4 = (unsigned short*)(ws + OFF_R4BF);
  unsigned short* r5 = (unsigned short*)(ws + OFF_R5BF);
  float2* cst5 = (float2*)(ws + OFF_CST5);

  if (bi < 128) {
    int c = bi;
    float w = (l < 9) ? P.dw1[c * 9 + l] : 0.f;
    float mx = wmax16(fabsf(w));
    float sq = fmaxf(mx / 7.0f, 1e-8f);
    if (l < 9) wq1[c * 12 + l] = clip7(rintf(w / sq)) * sq;
    if (l == 0) {
      float sc = P.g1[c] / sqrtf(P.v1[c] + EPSV);
      cst1[c] = f32x4{1.f, sc, P.m1[c], P.b1[c]};
    }
  } else if (bi < 256) {
    int o = bi - 128;
    float w0 = P.pw1[o * 128 + l], w1 = P.pw1[o * 128 + 64 + l];
    float mx = wmax64(fmaxf(fabsf(w0), fabsf(w1)));
    float sq = fmaxf(mx / 7.0f, 1e-8f);
    r2[o * 128 + l]      = f2bf(clip7(rintf(w0 / sq)));
    r2[o * 128 + 64 + l] = f2bf(clip7(rintf(w1 / sq)));
    if (l == 0) {
      float sc = P.g2[o] / sqrtf(P.v2[o] + EPSV);
      cst2[o] = f32x4{P.s1[0] * sq, sc, P.m2[o], P.b2[o]};
    }
  } else if (bi < 384) {
    int c = bi - 256;
    float w = (l < 9) ? P.dw2[c * 9 + l] : 0.f;
    float mx = wmax16(fabsf(w));
    float sq = fmaxf(mx / 7.0f, 1e-8f);
    if (l < 9) r3f[l * 128 + c] = clip7(rintf(w / sq));
    if (l == 0) {
      float sc = P.g3[c] / sqrtf(P.v3[c] + EPSV);
      cst3[c] = f32x4{P.s2[0] * sq, sc, P.m3[c], P.b3[c]};
    }
  } else if (bi < 512) {
    int o = bi - 384;
    float w0 = P.pw2[o * 128 + l], w1 = P.pw2[o * 128 + 64 + l];
    float mx = wmax64(fmaxf(fabsf(w0), fabsf(w1)));
    float sq = fmaxf(mx / 7.0f, 1e-8f);
    r4[o * 128 + l]      = f2bf(clip7(rintf(w0 / sq)));
    r4[o * 128 + 64 + l] = f2bf(clip7(rintf(w1 / sq)));
    if (l == 0) {
      float sc = P.g4[o] / sqrtf(P.v4[o] + EPSV);
      cst4[o] = f32x4{P.s3[0] * sq, sc, P.m4[o], P.b4[o]};
    }
  } else {
    int o = bi - 512;
    if (o < 19) {
      float w0 = P.clsw[o * 128 + l], w1 = P.clsw[o * 128 + 64 + l];
      float mx = wmax64(fmaxf(fabsf(w0), fabsf(w1)));
      float sq = fmaxf(mx / 7.0f, 1e-8f);
      r5[o * 128 + l]      = f2bf(clip7(rintf(w0 / sq)));
      r5[o * 128 + 64 + l] = f2bf(clip7(rintf(w1 / sq)));
      if (l == 0) {
        float A5 = P.s4[0] * sq;
        float bq = rintf(P.clsb[o] / A5) * A5;
        cst5[o] = make_float2(A5, bq);
      }
    } else {
      r5[o * 128 + l] = 0; r5[o * 128 + 64 + l] = 0;
      if (l == 0) cst5[o] = make_float2(0.f, 0.f);
    }
  }
}

// ---------------- dw-conv1 phase A: per-plane streaming, rolling 3-row window ----------------
__global__ __launch_bounds__(512) void dwA_kernel(const float* __restrict__ x,
                                                  char* __restrict__ ws,
                                                  const float* __restrict__ s1p) {
  int bid = blockIdx.x;
  int b = bid & 7, c = bid >> 3;              // XCD x owns image b=x
  int tid = threadIdx.x;
  int wq = tid & 63, wv = tid >> 6;
  int w0 = wq << 2;
  int h0 = wv << 4;
  const float* wp = (const float*)(ws + OFF_WQ1) + c * 12;
  float k0 = wp[0], k1 = wp[1], k2 = wp[2], k3 = wp[3], k4 = wp[4],
        k5 = wp[5], k6 = wp[6], k7 = wp[7], k8 = wp[8];
  f32x4 cs = ((const f32x4*)(ws + OFF_CST1))[c];
  float s_act = *s1p;
  float rs = 1.0f / s_act;
  const float* plane = x + (((size_t)((b << 7) | c)) << 15);
  unsigned char* oplane = (unsigned char*)(ws + OFF_BUFB) + (((size_t)((b << 7) | c)) << 15);

  f32x4 vm = {0.f, 0.f, 0.f, 0.f};
  if (h0 > 0) vm = *(const f32x4*)(plane + ((h0 - 1) << 8) + w0);
  f32x4 v0 = *(const f32x4*)(plane + (h0 << 8) + w0);
  f32x4 vp = *(const f32x4*)(plane + ((h0 + 1) << 8) + w0);
  float lm = __shfl_up(vm.w, 1), l0 = __shfl_up(v0.w, 1), lp = __shfl_up(vp.w, 1);
  float rm = __shfl_down(vm.x, 1), r0 = __shfl_down(v0.x, 1), rp = __shfl_down(vp.x, 1);
  if (wq == 0)  { lm = 0.f; l0 = 0.f; lp = 0.f; }
  if (wq == 63) { rm = 0.f; r0 = 0.f; rp = 0.f; }

  #pragma unroll 4
  for (int i = 0; i < 16; i++) {
    int h = h0 + i;
    float y0 = 0.f, y1 = 0.f, y2 = 0.f, y3 = 0.f;
    // row -1 (k0,k1,k2) then row 0 (k3,k4,k5) then row +1 (k6,k7,k8) — r1 order
    y0 = fmaf(lm,   k0, y0); y0 = fmaf(vm.x, k1, y0); y0 = fmaf(vm.y, k2, y0);
    y1 = fmaf(vm.x, k0, y1); y1 = fmaf(vm.y, k1, y1); y1 = fmaf(vm.z, k2, y1);
    y2 = fmaf(vm.y, k0, y2); y2 = fmaf(vm.z, k1, y2); y2 = fmaf(vm.w, k2, y2);
    y3 = fmaf(vm.z, k0, y3); y3 = fmaf(vm.w, k1, y3); y3 = fmaf(rm,   k2, y3);

    y0 = fmaf(l0,   k3, y0); y0 = fmaf(v0.x, k4, y0); y0 = fmaf(v0.y, k5, y0);
    y1 = fmaf(v0.x, k3, y1); y1 = fmaf(v0.y, k4, y1); y1 = fmaf(v0.z, k5, y1);
    y2 = fmaf(v0.y, k3, y2); y2 = fmaf(v0.z, k4, y2); y2 = fmaf(v0.w, k5, y2);
    y3 = fmaf(v0.z, k3, y3); y3 = fmaf(v0.w, k4, y3); y3 = fmaf(r0,   k5, y3);

    y0 = fmaf(lp,   k6, y0); y0 = fmaf(vp.x, k7, y0); y0 = fmaf(vp.y, k8, y0);
    y1 = fmaf(vp.x, k6, y1); y1 = fmaf(vp.y, k7, y1); y1 = fmaf(vp.z, k8, y1);
    y2 = fmaf(vp.y, k6, y2); y2 = fmaf(vp.z, k7, y2); y2 = fmaf(vp.w, k8, y2);
    y3 = fmaf(vp.z, k6, y3); y3 = fmaf(vp.w, k7, y3); y3 = fmaf(rp,   k8, y3);

    float q0, q1, q2, q3;
    qstep4(bnval(y0, cs), bnval(y1, cs), bnval(y2, cs), bnval(y3, cs),
           s_act, rs, q0, q1, q2, q3);
    unsigned int pk = (unsigned int)q0 | ((unsigned int)q1 << 8) |
                      ((unsigned int)q2 << 16) | ((unsigned int)q3 << 24);
    *(unsigned int*)(oplane + (h << 8) + w0) = pk;

    // shift window; load row h+2 for next iteration
    vm = v0; lm = l0; rm = r0;
    v0 = vp; l0 = lp; r0 = rp;
    f32x4 nv = {0.f, 0.f, 0.f, 0.f};
    if (i < 15 && h + 2 < 128) nv = *(const f32x4*)(plane + ((h + 2) << 8) + w0);
    vp = nv;
    float nl = __shfl_up(nv.w, 1), nr = __shfl_down(nv.x, 1);
    if (wq == 0)  nl = 0.f;
    if (wq == 63) nr = 0.f;
    lp = nl; rp = nr;
  }
}

// ---------------- pw1 from NCHW: staging does the transpose in-register ----------------
// XCD-swizzled grid: XCD x processes image x (k1 written by dwA on the same XCD).
__global__ __launch_bounds__(256) void pwn_kernel(const unsigned char* __restrict__ in,
                                                  unsigned char* __restrict__ out,
                                                  const unsigned short* __restrict__ rbf,
                                                  const f32x4* __restrict__ cst,
                                                  const float* __restrict__ sp) {
  __shared__ unsigned char lds[32768];
  int tid = threadIdx.x;
  int bid = blockIdx.x;
  int sbid = ((bid & 7) << 8) | (bid >> 3);   // XCD x -> image x, rows sequential
  int p0 = sbid << 7;
  int b_img = p0 >> 15, loc0 = p0 & 32767;
  {
    int pb = tid & 7, cq = tid >> 3;
    int c4 = cq << 2;
    int kc = cq >> 3, lgr = (cq >> 1) & 3, half = cq & 1;
    const unsigned char* ib = in + (((size_t)(b_img << 7)) << 15) + loc0 + (pb << 4);
    u32x4 t0 = *(const u32x4*)(ib + ((size_t)(c4 + 0) << 15));
    u32x4 t1 = *(const u32x4*)(ib + ((size_t)(c4 + 1) << 15));
    u32x4 t2 = *(const u32x4*)(ib + ((size_t)(c4 + 2) << 15));
    u32x4 t3 = *(const u32x4*)(ib + ((size_t)(c4 + 3) << 15));
    int swz = (pb & 7) << 4;
    #pragma unroll
    for (int s = 0; s < 16; s++) {
      int wrd = s >> 2, sh8 = (s & 3) << 3;
      unsigned int chw = ((t0[wrd] >> sh8) & 0xffu)
                       | (((t1[wrd] >> sh8) & 0xffu) << 8)
                       | (((t2[wrd] >> sh8) & 0xffu) << 16)
                       | (((t3[wrd] >> sh8) & 0xffu) << 24);
      unsigned int lo, hi;
      cvt2(chw, lo, hi);
      int ad = ((((((pb << 2) + kc) << 6) | s | (lgr << 4)) << 4) + (half << 3)) ^ swz;
      *(u32x2*)(lds + ad) = u32x2{lo, hi};
    }
  }
  __syncthreads();
  int l = tid & 63, wv = tid >> 6;
  int ob = wv << 5;                          // wave owns 32 output channels
  bf16x8 af[2][4];
  #pragma unroll
  for (int ot = 0; ot < 2; ot++)
    #pragma unroll
    for (int kc = 0; kc < 4; kc++) {
      int o = ob + (ot << 4) + (l & 15);
      int k = (kc << 5) + ((l >> 4) << 3);
      af[ot][kc] = *(const bf16x8*)(rbf + o * 128 + k);
    }
  f32x4 acc[2][8];
  #pragma unroll
  for (int ot = 0; ot < 2; ot++)
    #pragma unroll
    for (int pt = 0; pt < 8; pt++) acc[ot][pt] = f32x4{0.f, 0.f, 0.f, 0.f};
  #pragma unroll
  for (int kc = 0; kc < 4; kc++) {
    bf16x8 bb[8];
    #pragma unroll
    for (int pt = 0; pt < 8; pt++)
      bb[pt] = *(const bf16x8*)(lds + (((((((pt << 2) + kc) << 6)) + l) << 4) ^ ((pt & 7) << 4)));
    #pragma unroll
    for (int ot = 0; ot < 2; ot++)
      #pragma unroll
      for (int pt = 0; pt < 8; pt++)
        acc[ot][pt] = __builtin_amdgcn_mfma_f32_16x16x32_bf16(af[ot][kc], bb[pt], acc[ot][pt], 0, 0, 0);
  }
  float s_act = *sp;
  float rs = 1.0f / s_act;
  #pragma unroll
  for (int ot = 0; ot < 2; ot++) {
    int o0 = ob + (ot << 4) + ((l >> 4) << 2);
    f32x4 c0 = cst[o0], c1 = cst[o0 + 1], c2 = cst[o0 + 2], c3 = cst[o0 + 3];
    #pragma unroll
    for (int pt = 0; pt < 8; pt++) {
      int p = p0 + (pt << 4) + (l & 15);
      f32x4 a = acc[ot][pt];
      float q0, q1, q2, q3;
      qstep4(bnval(a.x, c0), bnval(a.y, c1), bnval(a.z, c2), bnval(a.w, c3),
             s_act, rs, q0, q1, q2, q3);
      unsigned int pk = (unsigned int)q0 | ((unsigned int)q1 << 8) |
                        ((unsigned int)q2 << 16) | ((unsigned int)q3 << 24);
      *(unsigned int*)(out + (size_t)p * 128 + o0) = pk;
    }
  }
}

// ---------------- fused dw2 + BN3 + qrelu + pw2 + BN4 + qrelu + classifier ----------------
// XCD-swizzled grid: halo rows + pwn's k2 stay in the owning XCD's L2.
// LDS 64KB: k3 fragments [0,32K), k4 fragments [32K,64K) -> no phase2->3 barrier.
__global__ __launch_bounds__(256) void dw2pwcls_kernel(const unsigned char* __restrict__ in,
                                                       float* __restrict__ out,
                                                       const char* __restrict__ ws,
                                                       const unsigned short* __restrict__ rbf,
                                                       const f32x4* __restrict__ cst,
                                                       const float* __restrict__ s3p,
                                                       const float* __restrict__ s4p,
                                                       const unsigned short* __restrict__ r5,
                                                       const float2* __restrict__ cst5) {
  __shared__ unsigned char lds[65536];
  int tid = threadIdx.x;
  int bid = blockIdx.x;
  int sbid = ((bid & 7) << 8) | (bid >> 3);   // XCD x -> image x, rows sequential
  int p0 = sbid << 7;                         // 128 consecutive positions, single h row
  // ---- phase 1: dw2 sliding window -> bf16 fragments (swizzled) ----
  {
    int cq = tid & 31, pg = tid >> 5;
    int c4 = cq << 2;
    const float* r3f = (const float*)(ws + OFF_R3F);
    float wk[9][4];
    #pragma unroll
    for (int t = 0; t < 9; t++) {
      wk[t][0] = r3f[t * 128 + c4];     wk[t][1] = r3f[t * 128 + c4 + 1];
      wk[t][2] = r3f[t * 128 + c4 + 2]; wk[t][3] = r3f[t * 128 + c4 + 3];
    }
    const f32x4* cst3 = (const f32x4*)(ws + OFF_CST3);
    f32x4 cs0 = cst3[c4], cs1 = cst3[c4 + 1], cs2 = cst3[c4 + 2], cs3 = cst3[c4 + 3];
    float s_act3 = *s3p;
    float rs3 = 1.0f / s_act3;
    int kc = c4 >> 5, hi = (c4 >> 3) & 3, half = (c4 >> 2) & 1;
    int g = hi | ((kc & 1) << 2);
    int hh = (p0 >> 8) & 127;          // block-uniform row index
    #pragma unroll 2
    for (int ps = 0; ps < 4; ps++) {
      int pbase = p0 + (ps << 5) + (pg << 2);   // 4 consecutive positions
      int wbase = pbase & 255;
      unsigned int xw[3][6];
      #pragma unroll
      for (int r = 0; r < 3; r++) {
        int gh = hh + r - 1;
        if (gh >= 0 && gh <= 127) {    // uniform branch
          const unsigned char* rp = in + (size_t)(pbase + (r - 1) * 256) * 128 + c4;
          xw[r][0] = (wbase > 0)   ? *(const unsigned int*)(rp - 128) : 0u;
          xw[r][1] = *(const unsigned int*)(rp);
          xw[r][2] = *(const unsigned int*)(rp + 128);
          xw[r][3] = *(const unsigned int*)(rp + 256);
          xw[r][4] = *(const unsigned int*)(rp + 384);
          xw[r][5] = (wbase < 252) ? *(const unsigned int*)(rp + 512) : 0u;
        } else {
          xw[r][0] = 0u; xw[r][1] = 0u; xw[r][2] = 0u;
          xw[r][3] = 0u; xw[r][4] = 0u; xw[r][5] = 0u;
        }
      }
      #pragma unroll
      for (int j = 0; j < 4; j++) {
        float a0 = 0.f, a1 = 0.f, a2 = 0.f, a3 = 0.f;
        #pragma unroll
        for (int r = 0; r < 3; r++) {
          #pragma unroll
          for (int dwi = 0; dwi < 3; dwi++) {
            unsigned int v = xw[r][j + dwi];
            int t = r * 3 + dwi;
            a0 = fmaf((float)(v & 0xffu),         wk[t][0], a0);
            a1 = fmaf((float)((v >> 8) & 0xffu),  wk[t][1], a1);
            a2 = fmaf((float)((v >> 16) & 0xffu), wk[t][2], a2);
            a3 = fmaf((float)(v >> 24),           wk[t][3], a3);
          }
        }
        float k0f, k1f, k2f, k3f;
        qstep4(bnval(a0, cs0), bnval(a1, cs1), bnval(a2, cs2), bnval(a3, cs3),
               s_act3, rs3, k0f, k1f, k2f, k3f);
        // bf16(small int float) == cvt2-of-u8 path exactly
        unsigned int wlo = (__builtin_bit_cast(unsigned int, k0f) >> 16) |
                           (__builtin_bit_cast(unsigned int, k1f) & 0xffff0000u);
        unsigned int whi = (__builtin_bit_cast(unsigned int, k2f) >> 16) |
                           (__builtin_bit_cast(unsigned int, k3f) & 0xffff0000u);
        int p_local = (ps << 5) + (pg << 2) + j;
        int pt = p_local >> 4, pl = p_local & 15;
        int slot = (pl ^ g) | (hi << 4);
        int ad = (((((pt << 2) + kc) << 6) | slot) << 4) + (half << 3);
        *(u32x2*)(lds + ad) = u32x2{wlo, whi};
      }
    }
  }
  __syncthreads();
  // ---- phase 2: pw2 MFMA (reads swizzled fragments) ----
  int l = tid & 63, wv = tid >> 6;
  int ob = wv << 5;
  bf16x8 af[2][4];
  #pragma unroll
  for (int ot = 0; ot < 2; ot++)
    #pragma unroll
    for (int kc = 0; kc < 4; kc++) {
      int o = ob + (ot << 4) + (l & 15);
      int k = (kc << 5) + ((l >> 4) << 3);
      af[ot][kc] = *(const bf16x8*)(rbf + o * 128 + k);
    }
  f32x4 acc[2][8];
  #pragma unroll
  for (int ot = 0; ot < 2; ot++)
    #pragma unroll
    for (int pt = 0; pt < 8; pt++) acc[ot][pt] = f32x4{0.f, 0.f, 0.f, 0.f};
  #pragma unroll
  for (int kc = 0; kc < 4; kc++) {
    int gg = (l >> 4) | ((kc & 1) << 2);
    bf16x8 bb[8];
    #pragma unroll
    for (int pt = 0; pt < 8; pt++)
      bb[pt] = *(const bf16x8*)(lds + ((((((pt << 2) + kc) << 6)) | (l ^ gg)) << 4));
    #pragma unroll
    for (int ot = 0; ot < 2; ot++)
      #pragma unroll
      for (int pt = 0; pt < 8; pt++)
        acc[ot][pt] = __builtin_amdgcn_mfma_f32_16x16x32_bf16(af[ot][kc], bb[pt], acc[ot][pt], 0, 0, 0);
  }
  float s_act4 = *s4p;
  float rs4 = 1.0f / s_act4;
  // ---- phase 3: BN4+qrelu -> k4 bf16 fragments at +32K (no barrier needed:
  // k4 region is disjoint from the k3 region other waves may still be reading) ----
  {
    int hsel = (l >> 4) & 1;
    #pragma unroll
    for (int ot = 0; ot < 2; ot++) {
      int o0 = ob + (ot << 4) + ((l >> 4) << 2);
      f32x4 c0 = cst[o0], c1 = cst[o0 + 1], c2 = cst[o0 + 2], c3 = cst[o0 + 3];
      int hi = (ot << 1) + ((l >> 4) >> 1);
      int lfrag = (l & 15) | (hi << 4);
      #pragma unroll
      for (int pt = 0; pt < 8; pt++) {
        f32x4 a = acc[ot][pt];
        float k0f, k1f, k2f, k3f;
        qstep4(bnval(a.x, c0), bnval(a.y, c1), bnval(a.z, c2), bnval(a.w, c3),
               s_act4, rs4, k0f, k1f, k2f, k3f);
        unsigned int w0 = (__builtin_bit_cast(unsigned int, k0f) >> 16) |
                          (__builtin_bit_cast(unsigned int, k1f) & 0xffff0000u);
        unsigned int w1 = (__builtin_bit_cast(unsigned int, k2f) >> 16) |
                          (__builtin_bit_cast(unsigned int, k3f) & 0xffff0000u);
        int ad = 32768 + ((((((pt << 2) + wv) << 6) | lfrag) << 4) + (hsel << 3));
        *(u32x2*)(lds + ad) = u32x2{w0, w1};
      }
    }
  }
  __syncthreads();
  // ---- phase 4: classifier MFMA (k4 fragments at +32K) ----
  int pt0 = wv << 1;
  bf16x8 af5[2][4];
  #pragma unroll
  for (int ot = 0; ot < 2; ot++)
    #pragma unroll
    for (int kc = 0; kc < 4; kc++) {
      int o = (ot << 4) + (l & 15);
      int k = (kc << 5) + ((l >> 4) << 3);
      af5[ot][kc] = *(const bf16x8*)(r5 + o * 128 + k);
    }
  f32x4 a5[2][2] = {{{0,0,0,0},{0,0,0,0}},{{0,0,0,0},{0,0,0,0}}};
  #pragma unroll
  for (int kc = 0; kc < 4; kc++) {
    bf16x8 b0 = *(const bf16x8*)(lds + 32768 + ((((((pt0    ) << 2) + kc) << 6) + l) << 4));
    bf16x8 b1 = *(const bf16x8*)(lds + 32768 + ((((((pt0 + 1) << 2) + kc) << 6) + l) << 4));
    #pragma unroll
    for (int ot = 0; ot < 2; ot++) {
      a5[ot][0] = __builtin_amdgcn_mfma_f32_16x16x32_bf16(af5[ot][kc], b0, a5[ot][0], 0, 0, 0);
      a5[ot][1] = __builtin_amdgcn_mfma_f32_16x16x32_bf16(af5[ot][kc], b1, a5[ot][1], 0, 0, 0);
    }
  }
  #pragma unroll
  for (int ptl = 0; ptl < 2; ptl++) {
    int p = p0 + ((pt0 + ptl) << 4) + (l & 15);
    int bb = p >> 15, hw = p & 32767;
    float* ob2 = out + (((size_t)bb * 19) << 15) + hw;
    #pragma unroll
    for (int ot = 0; ot < 2; ot++) {
      int obase = (ot << 4) + ((l >> 4) << 2);
      f32x4 a = a5[ot][ptl];
      #pragma unroll
      for (int i = 0; i < 4; i++) {
        int o = obase + i;
        if (o < 19) {
          float2 c5 = cst5[o];
          ob2[(size_t)o << 15] = fmaf(a[i], c5.x, c5.y);
        }
      }
    }
  }
}

// ---------------- launch ----------------
extern "C" void kernel_launch(void* const* d_in, const int* in_sizes, int n_in,
                              void* d_out, int out_size, void* d_ws, size_t ws_size,
                              hipStream_t stream) {
  (void)in_sizes; (void)n_in; (void)out_size; (void)ws_size;
  char* ws = (char*)d_ws;
  PArgs P;
  P.dw1  = (const float*)d_in[1];
  P.pw1  = (const float*)d_in[2];
  P.dw2  = (const float*)d_in[3];
  P.pw2  = (const float*)d_in[4];
  P.clsw = (const float*)d_in[5];
  P.clsb = (const float*)d_in[6];
  P.g1 = (const float*)d_in[7];  P.b1 = (const float*)d_in[8];
  P.m1 = (const float*)d_in[9];  P.v1 = (const float*)d_in[10];
  P.g2 = (const float*)d_in[11]; P.b2 = (const float*)d_in[12];
  P.m2 = (const float*)d_in[13]; P.v2 = (const float*)d_in[14];
  P.g3 = (const float*)d_in[15]; P.b3 = (const float*)d_in[16];
  P.m3 = (const float*)d_in[17]; P.v3 = (const float*)d_in[18];
  P.g4 = (const float*)d_in[19]; P.b4 = (const float*)d_in[20];
  P.m4 = (const float*)d_in[21]; P.v4 = (const float*)d_in[22];
  P.s1 = (const float*)d_in[23]; P.s2 = (const float*)d_in[24];
  P.s3 = (const float*)d_in[25]; P.s4 = (const float*)d_in[26];

  const float* x = (const float*)d_in[0];
  unsigned char* bufA = (unsigned char*)(ws + OFF_BUFA);
  unsigned char* bufB = (unsigned char*)(ws + OFF_BUFB);

  prep_kernel<<<544, 64, 0, stream>>>(P, ws);
  dwA_kernel<<<1024, 512, 0, stream>>>(x, ws, P.s1);                       // x -> k1 NCHW u8 (B)
  pwn_kernel<<<2048, 256, 0, stream>>>(bufB, bufA,
      (const unsigned short*)(ws + OFF_R2BF), (const f32x4*)(ws + OFF_CST2), P.s2);  // k1 NCHW -> k2 NHWC (A)
  dw2pwcls_kernel<<<2048, 256, 0, stream>>>(bufA, (float*)d_out, ws,
      (const unsigned short*)(ws + OFF_R4BF), (const f32x4*)(ws + OFF_CST4),
      P.s3, P.s4,
      (const unsigned short*)(ws + OFF_R5BF), (const float2*)(ws + OFF_CST5));       // k2 -> out
}